// Round 6
// baseline (4139.468 us; speedup 1.0000x reference)
//
#include <hip/hip_runtime.h>
#include <math.h>

#define L_    9216
#define WIN   144
#define NWIN  64
#define KJ    432

typedef __bf16 bf16x8 __attribute__((ext_vector_type(8)));
typedef unsigned short u16x8 __attribute__((ext_vector_type(8)));
typedef float f32x4 __attribute__((ext_vector_type(4)));

__device__ __forceinline__ unsigned short f2bf(float f) {
    unsigned int u = __builtin_bit_cast(unsigned int, f);
    u = (u + 0x7FFFu + ((u >> 16) & 1u)) >> 16;
    return (unsigned short)u;
}

// ---------------- weight pre-transpose for conv3x3 ----------------
__global__ void k_wprep(const float* __restrict__ wm, float* __restrict__ wtr) {
    int s = blockIdx.x * 256 + threadIdx.x;       // 147456 total
    if (s < 147456) {
        int cq = s & 63, r = s >> 6;              // r = c*9+kk
        wtr[s] = wm[(size_t)cq * 2304 + r];
    }
}

// ---------------- conv3x3 v5: split-K x2 -> partial sums ----------------
// grid 1536 ((n*96+h)*2+half), block 128 (16 cg x 8 wg); thread tile 12w x 4cq.
// half selects channels [half*128, half*128+128); 32 iters of 4 ch.
__global__ __launch_bounds__(128, 3) void k_conv3x3(const float* __restrict__ x,
                                                    const float* __restrict__ wtr,
                                                    float* __restrict__ parts) {
    __shared__ __align__(16) float sx[2][4][3][104];  // col = idx-1
    __shared__ __align__(16) float sw[2][4][9][64];
    const int bid = blockIdx.x;
    const int half = bid & 1;
    const int h = (bid >> 1) % 96, n = bid / 192;
    const int chb = half * 128;
    const int t = threadIdx.x;
    const int cg = t & 15, wg = t >> 4;
    const int w0 = wg * 12, cq0 = cg * 4;
    const float* xb = x + (size_t)n * 256 * 9216;

    // x staging slots: 288 f4 = 4ch x 3r x 24q ; slots {t, t+128, t+256 if <288}
    const int xch0 = t / 72, xr0i = (t / 24) % 3, xq0 = t % 24;
    const int xhh0 = h + xr0i - 1;
    const bool xv0 = (xhh0 >= 0) && (xhh0 < 96);
    const int xoff0 = xch0 * 9216 + (xv0 ? xhh0 : 0) * 96 + xq0 * 4;
    const int s1 = t + 128;
    const int xch1 = s1 / 72, xr1i = (s1 / 24) % 3, xq1 = s1 % 24;
    const int xhh1 = h + xr1i - 1;
    const bool xv1 = (xhh1 >= 0) && (xhh1 < 96);
    const int xoff1 = xch1 * 9216 + (xv1 ? xhh1 : 0) * 96 + xq1 * 4;
    const int s2 = t + 256;
    const bool xhas2 = s2 < 288;
    const int xch2 = xhas2 ? s2 / 72 : 0, xr2i = (s2 / 24) % 3, xq2 = s2 % 24;
    const int xhh2 = h + xr2i - 1;
    const bool xv2 = xhas2 && (xhh2 >= 0) && (xhh2 < 96);
    const int xoff2 = xch2 * 9216 + (xv2 ? xhh2 : 0) * 96 + xq2 * 4;
    // w staging slots: 576 f4; slots {t,+128,+256,+384,+512 if <576}
    const int wch0 = t / 144,          wkk0 = (t % 144) / 16,          wq0 = t % 16;
    const int wch1 = (t + 128) / 144,  wkk1 = ((t + 128) % 144) / 16,  wq1 = (t + 128) % 16;
    const int wch2 = (t + 256) / 144,  wkk2 = ((t + 256) % 144) / 16,  wq2 = (t + 256) % 16;
    const int wch3 = (t + 384) / 144,  wkk3 = ((t + 384) % 144) / 16,  wq3 = (t + 384) % 16;
    const bool whas4 = (t + 512) < 576;
    const int wch4 = whas4 ? (t + 512) / 144 : 0, wkk4 = ((t + 512) % 144) / 16, wq4 = (t + 512) % 16;

    float acc[12][4];
#pragma unroll
    for (int j = 0; j < 12; ++j)
#pragma unroll
        for (int q = 0; q < 4; ++q) acc[j][q] = 0.f;

    float4 xg0, xg1, xg2, wg0, wg1, wg2, wg3, wg4;
    const float4 fz = {0.f, 0.f, 0.f, 0.f};
#define C3_ISSUE(cb)                                                              \
    do {                                                                          \
        const float* xc = xb + (size_t)(cb) * 9216;                               \
        xg0 = xv0 ? *(const float4*)(xc + xoff0) : fz;                            \
        xg1 = xv1 ? *(const float4*)(xc + xoff1) : fz;                            \
        xg2 = xv2 ? *(const float4*)(xc + xoff2) : fz;                            \
        const float* wc = wtr + (size_t)(cb) * 576;                               \
        wg0 = *(const float4*)(wc + (wch0 * 9 + wkk0) * 64 + wq0 * 4);            \
        wg1 = *(const float4*)(wc + (wch1 * 9 + wkk1) * 64 + wq1 * 4);            \
        wg2 = *(const float4*)(wc + (wch2 * 9 + wkk2) * 64 + wq2 * 4);            \
        wg3 = *(const float4*)(wc + (wch3 * 9 + wkk3) * 64 + wq3 * 4);            \
        wg4 = whas4 ? *(const float4*)(wc + (wch4 * 9 + wkk4) * 64 + wq4 * 4) : fz; \
    } while (0)
#define C3_COMMIT(buf)                                                            \
    do {                                                                          \
        float* d0 = &sx[buf][xch0][xr0i][xq0 * 4 + 1];                            \
        d0[0] = xg0.x; d0[1] = xg0.y; d0[2] = xg0.z; d0[3] = xg0.w;               \
        float* d1 = &sx[buf][xch1][xr1i][xq1 * 4 + 1];                            \
        d1[0] = xg1.x; d1[1] = xg1.y; d1[2] = xg1.z; d1[3] = xg1.w;               \
        if (xhas2) {                                                              \
            float* d2 = &sx[buf][xch2][xr2i][xq2 * 4 + 1];                        \
            d2[0] = xg2.x; d2[1] = xg2.y; d2[2] = xg2.z; d2[3] = xg2.w;           \
        }                                                                         \
        *(float4*)&sw[buf][wch0][wkk0][wq0 * 4] = wg0;                            \
        *(float4*)&sw[buf][wch1][wkk1][wq1 * 4] = wg1;                            \
        *(float4*)&sw[buf][wch2][wkk2][wq2 * 4] = wg2;                            \
        *(float4*)&sw[buf][wch3][wkk3][wq3 * 4] = wg3;                            \
        if (whas4) *(float4*)&sw[buf][wch4][wkk4][wq4 * 4] = wg4;                 \
    } while (0)

    // zero edge columns (idx 0 and 97..103), BOTH buffers: 192 slots
    for (int s = t; s < 192; s += 128) {
        int b = s / 96, rem = s % 96;
        int ch = rem / 24, rr = (rem / 8) % 3, e = rem % 8;
        int idx = (e == 0) ? 0 : 96 + e;
        sx[b][ch][rr][idx] = 0.f;
    }
    C3_ISSUE(chb);
    C3_COMMIT(0);
    __syncthreads();

    for (int it = 0; it < 32; ++it) {
        const int cur = it & 1;
        if (it < 31) C3_ISSUE(chb + (it + 1) * 4);
#pragma unroll
        for (int ch = 0; ch < 4; ++ch) {
#pragma unroll
            for (int dh = 0; dh < 3; ++dh) {
                float4 wv0 = *(const float4*)&sw[cur][ch][dh * 3 + 0][cq0];
                float4 wv1 = *(const float4*)&sw[cur][ch][dh * 3 + 1][cq0];
                float4 wv2 = *(const float4*)&sw[cur][ch][dh * 3 + 2][cq0];
                float xr[16];
#pragma unroll
                for (int q = 0; q < 4; ++q) {
                    float4 v = *(const float4*)&sx[cur][ch][dh][w0 + q * 4];
                    xr[q * 4 + 0] = v.x; xr[q * 4 + 1] = v.y;
                    xr[q * 4 + 2] = v.z; xr[q * 4 + 3] = v.w;
                }
#pragma unroll
                for (int kw = 0; kw < 3; ++kw) {
                    const float4 wk = (kw == 0) ? wv0 : (kw == 1) ? wv1 : wv2;
#pragma unroll
                    for (int j = 0; j < 12; ++j) {
                        acc[j][0] += xr[j + kw] * wk.x;
                        acc[j][1] += xr[j + kw] * wk.y;
                        acc[j][2] += xr[j + kw] * wk.z;
                        acc[j][3] += xr[j + kw] * wk.w;
                    }
                }
            }
        }
        if (it < 31) C3_COMMIT(cur ^ 1);
        __syncthreads();
    }
#undef C3_ISSUE
#undef C3_COMMIT

    float* pb = parts + (size_t)half * 4718592;
#pragma unroll
    for (int j = 0; j < 12; ++j) {
        float4 o = {acc[j][0], acc[j][1], acc[j][2], acc[j][3]};
        *(float4*)&pb[((size_t)n * L_ + (size_t)h * 96 + w0 + j) * 64 + cq0] = o;
    }
}

// ---------------- combine split-K partials + bias -> xe ----------------
__global__ __launch_bounds__(256) void k_c3sum(const float* __restrict__ parts,
                                               const float* __restrict__ bm,
                                               float* __restrict__ xe) {
    size_t i = (size_t)blockIdx.x * 256 + threadIdx.x;   // f4 index; grid 4608
    float4 a = ((const float4*)parts)[i];
    float4 b = ((const float4*)parts)[i + 1179648];
    float4 bi = ((const float4*)bm)[i & 15];
    float4 o = {a.x + b.x + bi.x, a.y + b.y + bi.y, a.z + b.z + bi.z, a.w + b.w + bi.w};
    ((float4*)xe)[i] = o;
}

// ---------------- conv1x1 via bf16 MFMA: ye[8,9216,256] fp32 ----------------
// grid 4608 (n*576 + lt*4 + cot), block 256 (4 waves).
// Computes T[co][l] = sum_c wa_bf16[co][c] * x_bf16[c][l] (fp32 accum),
// then LDS-detranspose -> ye[l][co] + bias. A/B/C mappings mirror k_pv_mfma.
__global__ __launch_bounds__(256) void k_conv1x1(const float* __restrict__ x,
                                                 const float* __restrict__ wa,
                                                 const float* __restrict__ ba,
                                                 float* __restrict__ ye) {
    __shared__ __align__(16) unsigned short pA[64 * 40];  // [co][k], pad 40
    __shared__ __align__(16) unsigned short pB[32 * 68];  // [k][l],  pad 68
    __shared__ __align__(16) float det[64 * 67];          // [co][l], pad 67
    const int bid = blockIdx.x;
    const int n = bid / 576, rem = bid % 576;
    const int l0 = (rem >> 2) * 64, co0 = (rem & 3) * 64;
    const int t = threadIdx.x, lane = t & 63, nq = t >> 6;

    f32x4 acc[4];
#pragma unroll
    for (int nt = 0; nt < 4; ++nt) { f32x4 z = {0.f, 0.f, 0.f, 0.f}; acc[nt] = z; }

    const int aOff = (nq * 16 + (lane & 15)) * 40 + (lane >> 4) * 8;
    const int bK = (lane >> 4) * 8, bL = lane & 15;

    for (int kc = 0; kc < 8; ++kc) {
        const int c0 = kc * 32;
        __syncthreads();
        // stage A: wa[co0..+64][c0..+32] -> bf16, 512 f4 slots
        for (int s = t; s < 512; s += 256) {
            int co = s >> 3, q = s & 7;
            float4 v = *(const float4*)&wa[(size_t)(co0 + co) * 256 + c0 + q * 4];
            ushort4 b = {f2bf(v.x), f2bf(v.y), f2bf(v.z), f2bf(v.w)};
            *(ushort4*)&pA[co * 40 + q * 4] = b;
        }
        // stage B: x[n][c0..+32][l0..+64] -> bf16, 512 f4 slots
        for (int s = t; s < 512; s += 256) {
            int c = s >> 4, l4 = s & 15;
            float4 v = *(const float4*)&x[((size_t)n * 256 + c0 + c) * L_ + l0 + l4 * 4];
            ushort4 b = {f2bf(v.x), f2bf(v.y), f2bf(v.z), f2bf(v.w)};
            *(ushort4*)&pB[c * 68 + l4 * 4] = b;
        }
        __syncthreads();
        u16x8 au = *(const u16x8*)&pA[aOff];
        bf16x8 af = __builtin_bit_cast(bf16x8, au);
#pragma unroll
        for (int nt = 0; nt < 4; ++nt) {
            u16x8 bu;
#pragma unroll
            for (int j = 0; j < 8; ++j) bu[j] = pB[(bK + j) * 68 + nt * 16 + bL];
            bf16x8 bf = __builtin_bit_cast(bf16x8, bu);
            acc[nt] = __builtin_amdgcn_mfma_f32_16x16x32_bf16(af, bf, acc[nt], 0, 0, 0);
        }
    }
    // detranspose via LDS: det[co][l] then coalesced ye[l][co]
    __syncthreads();
#pragma unroll
    for (int nt = 0; nt < 4; ++nt)
#pragma unroll
        for (int r = 0; r < 4; ++r)
            det[(nq * 16 + (lane >> 4) * 4 + r) * 67 + nt * 16 + (lane & 15)] = acc[nt][r];
    __syncthreads();
    for (int s = t; s < 1024; s += 256) {
        int l = s >> 4, c4 = s & 15;
        float4 bi = *(const float4*)&ba[co0 + c4 * 4];
        float4 o = {det[(c4 * 4 + 0) * 67 + l] + bi.x,
                    det[(c4 * 4 + 1) * 67 + l] + bi.y,
                    det[(c4 * 4 + 2) * 67 + l] + bi.z,
                    det[(c4 * 4 + 3) * 67 + l] + bi.w};
        *(float4*)&ye[((size_t)n * L_ + l0 + l) * 256 + co0 + c4 * 4] = o;
    }
}

// ---------------- kmeans assign (fp64 dot; norm is argmax-invariant) ----------------
__global__ __launch_bounds__(256) void k_assign(const float* __restrict__ xe,
                                                const float* __restrict__ means,
                                                int* __restrict__ codes_i,
                                                float* __restrict__ codes_f) {
    __shared__ float sm[128 * 64];
    for (int s = threadIdx.x; s < 8192; s += 256) sm[s] = means[s];
    __syncthreads();
    const int g = blockIdx.x * 256 + threadIdx.x;
    const float* row = xe + (size_t)g * 64;
    float v[64];
#pragma unroll
    for (int c4 = 0; c4 < 16; c4++) {
        float4 t4 = *(const float4*)(row + c4 * 4);
        v[c4 * 4 + 0] = t4.x; v[c4 * 4 + 1] = t4.y; v[c4 * 4 + 2] = t4.z; v[c4 * 4 + 3] = t4.w;
    }
    int best = 0;
    double bd = -1e300;
    for (int cl = 0; cl < 128; cl++) {
        double d = 0.0;
#pragma unroll
        for (int c4 = 0; c4 < 16; c4++) {
            float4 m4 = *(const float4*)(sm + cl * 64 + c4 * 4);
            d += (double)v[c4 * 4 + 0] * (double)m4.x + (double)v[c4 * 4 + 1] * (double)m4.y +
                 (double)v[c4 * 4 + 2] * (double)m4.z + (double)v[c4 * 4 + 3] * (double)m4.w;
        }
        if (d > bd) { bd = d; best = cl; }
    }
    codes_i[g] = best;
    codes_f[g] = (float)best;
}

// ---------------- stable counting sort ----------------
__global__ void k_hist(const int* __restrict__ codes_i, int* __restrict__ hist) {
    __shared__ int h[128];
    if (threadIdx.x < 128) h[threadIdx.x] = 0;
    __syncthreads();
    int n = blockIdx.x / 36, ch = blockIdx.x % 36;
    int c = codes_i[n * L_ + ch * 256 + threadIdx.x];
    atomicAdd(&h[c], 1);
    __syncthreads();
    if (threadIdx.x < 128) hist[(n * 36 + ch) * 128 + threadIdx.x] = h[threadIdx.x];
}

__global__ void k_scan(const int* __restrict__ hist, int* __restrict__ basebuf) {
    __shared__ int tot[128];
    __shared__ int binstart[128];
    int n = blockIdx.x, c = threadIdx.x;
    int run = 0;
    int local[36];
    for (int ch = 0; ch < 36; ch++) { local[ch] = run; run += hist[(n * 36 + ch) * 128 + c]; }
    tot[c] = run;
    __syncthreads();
    if (c == 0) {
        int s = 0;
        for (int b = 0; b < 128; b++) { binstart[b] = s; s += tot[b]; }
    }
    __syncthreads();
    int bs0 = binstart[c];
    for (int ch = 0; ch < 36; ch++) basebuf[(n * 36 + ch) * 128 + c] = bs0 + local[ch];
}

__global__ void k_rank(const int* __restrict__ codes_i, const int* __restrict__ basebuf,
                       int* __restrict__ idxb, int* __restrict__ undo) {
    __shared__ int sc[256];
    __shared__ int sb[128];
    int n = blockIdx.x / 36, ch = blockIdx.x % 36;
    int i = threadIdx.x;
    int l = ch * 256 + i;
    int c = codes_i[n * L_ + l];
    sc[i] = c;
    if (i < 128) sb[i] = basebuf[(n * 36 + ch) * 128 + i];
    __syncthreads();
    int r = 0;
    for (int j = 0; j < i; j++) r += (sc[j] == c);
    int pos = sb[c] + r;
    idxb[n * L_ + pos] = l;
    undo[n * L_ + l] = pos;
}

// ---------------- QK: raw logits -> score region ----------------
__global__ __launch_bounds__(128) void k_qk(const float* __restrict__ xe,
                                            const int* __restrict__ idxb,
                                            float* __restrict__ raw) {
    __shared__ float sq[72 * 68];
    __shared__ float sk[10368];
    __shared__ int sidx[432];
    const int bid = blockIdx.x;
    const int n = bid >> 7, k = (bid >> 1) & 63, ih = bid & 1;
    const int t = threadIdx.x;
    const int ti = t >> 4, tj = t & 15;

    for (int s = t; s < 432; s += 128) {
        int wb = s / 144, jj = s % 144;
        int wk = (wb == 0) ? k : (wb == 1) ? ((k + 63) & 63) : ((k + 1) & 63);
        sidx[s] = idxb[n * L_ + wk * WIN + jj];
    }
    __syncthreads();
    for (int s = t; s < 72 * 16; s += 128) {
        int rr = s >> 4, q4 = s & 15;
        int l = sidx[ih * 72 + rr];
        *(float4*)(sq + rr * 68 + q4 * 4) = *(const float4*)(xe + ((size_t)n * L_ + l) * 64 + q4 * 4);
    }
    float* outbase = raw + (size_t)(n * NWIN + k) * WIN * KJ + (size_t)ih * 72 * KJ;

    for (int wb = 0; wb < 3; wb++) {
        __syncthreads();
        for (int s = t; s < 144 * 16; s += 128) {
            int rr = s >> 4, q4 = s & 15;
            int l = sidx[wb * 144 + rr];
            float4 v = *(const float4*)(xe + ((size_t)n * L_ + l) * 64 + q4 * 4);
            float ss = v.x * v.x + v.y * v.y + v.z * v.z + v.w * v.w;
            ss += __shfl_xor(ss, 1); ss += __shfl_xor(ss, 2);
            ss += __shfl_xor(ss, 4); ss += __shfl_xor(ss, 8);
            float inv = 1.0f / fmaxf(sqrtf(ss), 5e-5f);
            v.x *= inv; v.y *= inv; v.z *= inv; v.w *= inv;
            *(float4*)(sk + rr * 68 + q4 * 4) = v;
        }
        __syncthreads();
        float acc[9][9];
#pragma unroll
        for (int a = 0; a < 9; a++)
#pragma unroll
            for (int b = 0; b < 9; b++) acc[a][b] = 0.f;
        for (int c4 = 0; c4 < 16; c4++) {
            float4 qv[9], kv[9];
#pragma unroll
            for (int a = 0; a < 9; a++) qv[a] = *(const float4*)(sq + (ti * 9 + a) * 68 + c4 * 4);
#pragma unroll
            for (int b = 0; b < 9; b++) kv[b] = *(const float4*)(sk + (tj * 9 + b) * 68 + c4 * 4);
#pragma unroll
            for (int a = 0; a < 9; a++)
#pragma unroll
                for (int b = 0; b < 9; b++)
                    acc[a][b] += qv[a].x * kv[b].x + qv[a].y * kv[b].y +
                                 qv[a].z * kv[b].z + qv[a].w * kv[b].w;
        }
        __syncthreads();
#pragma unroll
        for (int a = 0; a < 9; a++)
#pragma unroll
            for (int b = 0; b < 9; b++)
                sk[(ti * 9 + a) * 144 + tj * 9 + b] = acc[a][b];
        __syncthreads();
        for (int s = t; s < 72 * 36; s += 128) {
            int i = s / 36, q = s % 36;
            *(float4*)(outbase + (size_t)i * KJ + wb * 144 + q * 4) =
                *(const float4*)(sk + i * 144 + q * 4);
        }
    }
}

// ---------------- row softmax in place + bs ----------------
__global__ __launch_bounds__(256) void k_softmax(float* __restrict__ score, float* __restrict__ bs) {
    const int row = blockIdx.x * 4 + (threadIdx.x >> 6);
    const int lane = threadIdx.x & 63;
    float* p = score + (size_t)row * KJ;
    float v[7];
    float m = -1e30f;
#pragma unroll
    for (int it = 0; it < 7; it++) {
        int j = lane + it * 64;
        v[it] = (j < KJ) ? p[j] : -1e30f;
        m = fmaxf(m, v[it]);
    }
#pragma unroll
    for (int o = 32; o >= 1; o >>= 1) m = fmaxf(m, __shfl_xor(m, o));
    float s = 0.f;
#pragma unroll
    for (int it = 0; it < 7; it++) {
        v[it] = __expf(v[it] - m);
        s += (lane + it * 64 < KJ) ? v[it] : 0.f;
    }
#pragma unroll
    for (int o = 32; o >= 1; o >>= 1) s += __shfl_xor(s, o);
    float inv = 1.f / s;
#pragma unroll
    for (int it = 0; it < 7; it++) {
        int j = lane + it * 64;
        if (j < KJ) p[j] = v[it] * inv;
    }
    if (lane == 0) bs[row] = m + logf(s);
}

// ---------------- PV via bf16 MFMA: ret_sorted = score @ Y3 ----------------
__global__ __launch_bounds__(256) void k_pv_mfma(const float* __restrict__ ye,
                                                 const int* __restrict__ idxb,
                                                 const float* __restrict__ score,
                                                 float* __restrict__ ret) {
    __shared__ __align__(16) unsigned short pA[144 * 72];   // P[i][kk], stride 72
    __shared__ __align__(16) unsigned short pB[64 * 258];   // Y[kk][co], stride 258
    __shared__ int sidx[432];
    const int bid = blockIdx.x;
    const int n = bid >> 6, k = bid & 63;
    const int t = threadIdx.x, lane = t & 63, nq = t >> 6;

    for (int s = t; s < 432; s += 256) {
        int wb = s / 144, jj = s % 144;
        int wk = (wb == 0) ? k : (wb == 1) ? ((k + 63) & 63) : ((k + 1) & 63);
        sidx[s] = idxb[n * L_ + wk * WIN + jj];
    }

    f32x4 acc[9][4];
#pragma unroll
    for (int mt = 0; mt < 9; ++mt)
#pragma unroll
        for (int nt = 0; nt < 4; ++nt) {
            f32x4 z = {0.f, 0.f, 0.f, 0.f};
            acc[mt][nt] = z;
        }

    const float* srow = score + (size_t)(n * NWIN + k) * WIN * KJ;
    const float* yb = ye + (size_t)n * L_ * 256;
    const int aBase = (lane & 15) * 72 + (lane >> 4) * 8;
    const int bBase = (lane >> 4) * 8 * 258 + nq * 64 + (lane & 15);

    for (int kc = 0; kc < 7; ++kc) {
        __syncthreads();
        // stage P chunk [144 x 64] fp32 -> bf16
        for (int s = t; s < 2304; s += 256) {
            int i = s >> 4, c4 = s & 15;
            int kcol = kc * 64 + c4 * 4;
            float4 v = {0.f, 0.f, 0.f, 0.f};
            if (kcol < KJ) v = *(const float4*)(srow + (size_t)i * KJ + kcol);
            ushort4 b = {f2bf(v.x), f2bf(v.y), f2bf(v.z), f2bf(v.w)};
            *(ushort4*)&pA[i * 72 + c4 * 4] = b;
        }
        // stage Y chunk [64 x 256] gathered rows -> bf16
        for (int s = t; s < 4096; s += 256) {
            int j = s >> 6, c4g = s & 63;
            int kk = kc * 64 + j;
            float4 v = {0.f, 0.f, 0.f, 0.f};
            if (kk < KJ) v = *(const float4*)(yb + (size_t)sidx[kk] * 256 + c4g * 4);
            ushort2 b0 = {f2bf(v.x), f2bf(v.y)};
            ushort2 b1 = {f2bf(v.z), f2bf(v.w)};
            *(ushort2*)&pB[j * 258 + c4g * 4] = b0;
            *(ushort2*)&pB[j * 258 + c4g * 4 + 2] = b1;
        }
        __syncthreads();
#pragma unroll
        for (int ks = 0; ks < 2; ++ks) {
            bf16x8 af[9];
#pragma unroll
            for (int mt = 0; mt < 9; ++mt)
                af[mt] = *(const bf16x8*)&pA[aBase + mt * 1152 + ks * 32];
#pragma unroll
            for (int nt = 0; nt < 4; ++nt) {
                const int e = bBase + ks * 32 * 258 + nt * 16;
                u16x8 bu;
#pragma unroll
                for (int j = 0; j < 8; ++j) bu[j] = pB[e + j * 258];
                bf16x8 bf = __builtin_bit_cast(bf16x8, bu);
#pragma unroll
                for (int mt = 0; mt < 9; ++mt)
                    acc[mt][nt] = __builtin_amdgcn_mfma_f32_16x16x32_bf16(af[mt], bf, acc[mt][nt], 0, 0, 0);
            }
        }
    }
    float* rbase = ret + ((size_t)n * L_ + (size_t)k * WIN) * 256;
    const int rowb = (lane >> 4) * 4;
    const int colb = nq * 64 + (lane & 15);
#pragma unroll
    for (int mt = 0; mt < 9; ++mt)
#pragma unroll
        for (int nt = 0; nt < 4; ++nt)
#pragma unroll
            for (int r = 0; r < 4; ++r)
                rbase[(size_t)(mt * 16 + rowb + r) * 256 + colb + nt * 16] = acc[mt][nt][r];
}

// ---------------- final scatter: out = x + 0.1 * ret[undo] ----------------
__global__ __launch_bounds__(256) void k_out(const float* __restrict__ x,
                                             const float* __restrict__ ret,
                                             const int* __restrict__ undo,
                                             float* __restrict__ out) {
    __shared__ float sr[32 * 257];
    const int n = blockIdx.x / 288, lt = blockIdx.x % 288;
    const int lbase = lt * 32;
    const int t = threadIdx.x;
    for (int s = t; s < 32 * 64; s += 256) {
        int lr = s >> 6, q = s & 63;
        int p = undo[n * L_ + lbase + lr];
        *(float4*)(sr + lr * 257 + q * 4) = *(const float4*)(ret + ((size_t)n * L_ + p) * 256 + q * 4);
    }
    __syncthreads();
    const int lr = t & 31, cog = t >> 5;
    for (int cc = 0; cc < 32; cc++) {
        int co = cog * 32 + cc;
        size_t gi = ((size_t)(n * 256 + co)) * L_ + lbase + lr;
        out[gi] = x[gi] + 0.1f * sr[lr * 257 + co];
    }
}

extern "C" void kernel_launch(void* const* d_in, const int* in_sizes, int n_in,
                              void* d_out, int out_size, void* d_ws, size_t ws_size,
                              hipStream_t stream) {
    (void)in_sizes; (void)n_in; (void)out_size; (void)ws_size;
    const float* x     = (const float*)d_in[0];
    const float* means = (const float*)d_in[1];
    const float* wm    = (const float*)d_in[2];
    const float* bm    = (const float*)d_in[3];
    const float* wa    = (const float*)d_in[4];
    const float* ba    = (const float*)d_in[5];

    float* out   = (float*)d_out;
    float* score = out + (size_t)8 * 256 * L_;
    float* bs    = score + (size_t)8 * NWIN * WIN * KJ;
    float* codesf = bs + (size_t)8 * L_;

    float* xe  = (float*)d_ws;
    float* ye  = xe + (size_t)8 * L_ * 64;
    float* ret = ye + (size_t)8 * L_ * 256;
    float* wtr = ret + (size_t)8 * L_ * 256;
    int* codes_i = (int*)(wtr + 147456);
    int* idxb    = codes_i + 8 * L_;
    int* undo    = idxb + 8 * L_;
    int* hist    = undo + 8 * L_;
    int* basebuf = hist + 8 * 36 * 128;

    float* parts = ret;   // conv3x3 partials live in ret region until c3sum

    k_wprep  <<<576, 256, 0, stream>>>(wm, wtr);
    k_conv3x3<<<1536, 128, 0, stream>>>(x, wtr, parts);
    k_c3sum  <<<4608, 256, 0, stream>>>(parts, bm, xe);
    k_conv1x1<<<4608, 256, 0, stream>>>(x, wa, ba, ye);
    k_assign <<<288, 256, 0, stream>>>(xe, means, codes_i, codesf);
    k_hist   <<<288, 256, 0, stream>>>(codes_i, hist);
    k_scan   <<<8, 128, 0, stream>>>(hist, basebuf);
    k_rank   <<<288, 256, 0, stream>>>(codes_i, basebuf, idxb, undo);
    k_qk     <<<1024, 128, 0, stream>>>(xe, idxb, score);
    k_softmax<<<18432, 256, 0, stream>>>(score, bs);
    k_pv_mfma<<<512, 256, 0, stream>>>(ye, idxb, score, ret);
    k_out    <<<2304, 256, 0, stream>>>(x, ret, undo, out);
}

// Round 7
// 915.782 us; speedup vs baseline: 4.5201x; 4.5201x over previous
//
#include <hip/hip_runtime.h>
#include <math.h>

#define L_    9216
#define WIN   144
#define NWIN  64
#define KJ    432

typedef __bf16 bf16x8 __attribute__((ext_vector_type(8)));
typedef unsigned short u16x8 __attribute__((ext_vector_type(8)));
typedef float f32x4 __attribute__((ext_vector_type(4)));

__device__ __forceinline__ unsigned short f2bf(float f) {
    unsigned int u = __builtin_bit_cast(unsigned int, f);
    u = (u + 0x7FFFu + ((u >> 16) & 1u)) >> 16;
    return (unsigned short)u;
}

// ---------------- weight pre-transpose for conv3x3 ----------------
__global__ void k_wprep(const float* __restrict__ wm, float* __restrict__ wtr) {
    int s = blockIdx.x * 256 + threadIdx.x;       // 147456 total
    if (s < 147456) {
        int cq = s & 63, r = s >> 6;              // r = c*9+kk
        wtr[s] = wm[(size_t)cq * 2304 + r];
    }
}

// ---------------- conv3x3 v3 (reverted, known 498us): x -> xe[8,9216,64] ----------------
// grid 768 (n*96+h), block 256 (8 wg x 32 cg); thread tile 12w x 2cq.
// 4 channels/iter, 64 iters, double-buffered LDS, float4 staging, 1 barrier/iter.
__global__ __launch_bounds__(256) void k_conv3x3(const float* __restrict__ x,
                                                 const float* __restrict__ wtr,
                                                 const float* __restrict__ bm,
                                                 float* __restrict__ xe) {
    __shared__ __align__(16) float sx[2][4][3][104];  // [buf][ch][row][idx], col = idx-1
    __shared__ __align__(16) float sw[2][4][9][64];   // [buf][ch][tap][cq]
    const int n = blockIdx.x / 96, h = blockIdx.x % 96;
    const int t = threadIdx.x;
    const int wg = t >> 5, cg = t & 31;
    const int w0 = wg * 12, cq0 = cg * 2;
    const float* xb = x + (size_t)n * 256 * 9216;

    // --- x staging descriptors: s in {t, t+256(<288)}; s -> ch=s/72, r=(s/24)%3, q=s%24
    const int ch0 = t / 72, r0 = (t / 24) % 3, q0 = t % 24;
    const int hh0 = h + r0 - 1;
    const bool v0 = (hh0 >= 0) && (hh0 < 96);
    const int off0 = ch0 * 9216 + (v0 ? hh0 : 0) * 96 + q0 * 4;
    const int s1 = t + 256;
    const bool has1 = (s1 < 288);
    const int ch1 = has1 ? s1 / 72 : 0, r1 = (s1 / 24) % 3, q1 = s1 % 24;
    const int hh1 = h + r1 - 1;
    const bool v1 = has1 && (hh1 >= 0) && (hh1 < 96);
    const int off1 = ch1 * 9216 + (v1 ? hh1 : 0) * 96 + q1 * 4;
    // --- w staging: s in {t, t+256, t+512(<576)}; s -> ch=s/144, kk=(s%144)/16, q4=s%16
    const int wch0 = t / 144, wkk0 = (t % 144) / 16, wq0 = t % 16;
    const int wch1 = (t + 256) / 144, wkk1 = ((t + 256) % 144) / 16, wq1 = (t + 256) % 16;
    const bool whas2 = (t + 512) < 576;
    const int wch2 = whas2 ? (t + 512) / 144 : 0, wkk2 = ((t + 512) % 144) / 16, wq2 = (t + 512) % 16;

    float acc[12][2];
#pragma unroll
    for (int j = 0; j < 12; ++j) { acc[j][0] = 0.f; acc[j][1] = 0.f; }

    float4 xr0, xr1, wr0, wr1, wr2;
#define C3_ISSUE(cb)                                                              \
    do {                                                                          \
        const float* xc = xb + (size_t)(cb) * 9216;                               \
        xr0 = v0 ? *(const float4*)(xc + off0) : float4{0.f, 0.f, 0.f, 0.f};      \
        xr1 = v1 ? *(const float4*)(xc + off1) : float4{0.f, 0.f, 0.f, 0.f};      \
        const float* wc = wtr + (size_t)(cb) * 576;                               \
        wr0 = *(const float4*)(wc + (wch0 * 9 + wkk0) * 64 + wq0 * 4);            \
        wr1 = *(const float4*)(wc + (wch1 * 9 + wkk1) * 64 + wq1 * 4);            \
        wr2 = whas2 ? *(const float4*)(wc + (wch2 * 9 + wkk2) * 64 + wq2 * 4)     \
                    : float4{0.f, 0.f, 0.f, 0.f};                                 \
    } while (0)
#define C3_COMMIT(buf)                                                            \
    do {                                                                          \
        float* d0 = &sx[buf][ch0][r0][q0 * 4 + 1];                                \
        d0[0] = xr0.x; d0[1] = xr0.y; d0[2] = xr0.z; d0[3] = xr0.w;               \
        if (has1) {                                                               \
            float* d1 = &sx[buf][ch1][r1][q1 * 4 + 1];                            \
            d1[0] = xr1.x; d1[1] = xr1.y; d1[2] = xr1.z; d1[3] = xr1.w;           \
        }                                                                         \
        *(float4*)&sw[buf][wch0][wkk0][wq0 * 4] = wr0;                            \
        *(float4*)&sw[buf][wch1][wkk1][wq1 * 4] = wr1;                            \
        if (whas2) *(float4*)&sw[buf][wch2][wkk2][wq2 * 4] = wr2;                 \
    } while (0)

    // zero edge columns (idx 0 and 97..103) once, both buffers
    if (t < 192) {
        int b = t / 96, ch = (t / 24) % 4, r = (t / 8) % 3, e = t % 8;
        int idx = (e == 0) ? 0 : 96 + e;
        sx[b][ch][r][idx] = 0.f;
    }
    C3_ISSUE(0);
    C3_COMMIT(0);
    __syncthreads();

    for (int it = 0; it < 64; ++it) {
        const int cur = it & 1;
        if (it < 63) C3_ISSUE((it + 1) * 4);
#pragma unroll
        for (int ch = 0; ch < 4; ++ch) {
            float2 wv[9];
#pragma unroll
            for (int tap = 0; tap < 9; ++tap)
                wv[tap] = *(const float2*)&sw[cur][ch][tap][cq0];
#pragma unroll
            for (int dh = 0; dh < 3; ++dh) {
                float xr[16];
#pragma unroll
                for (int q = 0; q < 4; ++q) {
                    float4 v = *(const float4*)&sx[cur][ch][dh][w0 + q * 4];
                    xr[q * 4 + 0] = v.x; xr[q * 4 + 1] = v.y;
                    xr[q * 4 + 2] = v.z; xr[q * 4 + 3] = v.w;
                }
#pragma unroll
                for (int kw = 0; kw < 3; ++kw) {
                    const float2 wk = wv[dh * 3 + kw];
#pragma unroll
                    for (int j = 0; j < 12; ++j) {
                        acc[j][0] += xr[j + kw] * wk.x;
                        acc[j][1] += xr[j + kw] * wk.y;
                    }
                }
            }
        }
        if (it < 63) C3_COMMIT(cur ^ 1);
        __syncthreads();
    }
#undef C3_ISSUE
#undef C3_COMMIT

    const float b0 = bm[cq0], b1 = bm[cq0 + 1];
#pragma unroll
    for (int j = 0; j < 12; ++j) {
        float2 o = {acc[j][0] + b0, acc[j][1] + b1};
        *(float2*)&xe[((size_t)n * L_ + (size_t)h * 96 + w0 + j) * 64 + cq0] = o;
    }
}

// ---------------- conv1x1 via bf16 MFMA: ye[8,9216,256] fp32 ----------------
// grid 4608 (n*576 + lt*4 + cot), block 256 (4 waves).
__global__ __launch_bounds__(256) void k_conv1x1(const float* __restrict__ x,
                                                 const float* __restrict__ wa,
                                                 const float* __restrict__ ba,
                                                 float* __restrict__ ye) {
    __shared__ __align__(16) unsigned short pA[64 * 40];  // [co][k], pad 40
    __shared__ __align__(16) unsigned short pB[32 * 68];  // [k][l],  pad 68
    __shared__ __align__(16) float det[64 * 67];          // [co][l], pad 67
    const int bid = blockIdx.x;
    const int n = bid / 576, rem = bid % 576;
    const int l0 = (rem >> 2) * 64, co0 = (rem & 3) * 64;
    const int t = threadIdx.x, lane = t & 63, nq = t >> 6;

    f32x4 acc[4];
#pragma unroll
    for (int nt = 0; nt < 4; ++nt) { f32x4 z = {0.f, 0.f, 0.f, 0.f}; acc[nt] = z; }

    const int aOff = (nq * 16 + (lane & 15)) * 40 + (lane >> 4) * 8;
    const int bK = (lane >> 4) * 8, bL = lane & 15;

    for (int kc = 0; kc < 8; ++kc) {
        const int c0 = kc * 32;
        __syncthreads();
        for (int s = t; s < 512; s += 256) {
            int co = s >> 3, q = s & 7;
            float4 v = *(const float4*)&wa[(size_t)(co0 + co) * 256 + c0 + q * 4];
            ushort4 b = {f2bf(v.x), f2bf(v.y), f2bf(v.z), f2bf(v.w)};
            *(ushort4*)&pA[co * 40 + q * 4] = b;
        }
        for (int s = t; s < 512; s += 256) {
            int c = s >> 4, l4 = s & 15;
            float4 v = *(const float4*)&x[((size_t)n * 256 + c0 + c) * L_ + l0 + l4 * 4];
            ushort4 b = {f2bf(v.x), f2bf(v.y), f2bf(v.z), f2bf(v.w)};
            *(ushort4*)&pB[c * 68 + l4 * 4] = b;
        }
        __syncthreads();
        u16x8 au = *(const u16x8*)&pA[aOff];
        bf16x8 af = __builtin_bit_cast(bf16x8, au);
#pragma unroll
        for (int nt = 0; nt < 4; ++nt) {
            u16x8 bu;
#pragma unroll
            for (int j = 0; j < 8; ++j) bu[j] = pB[(bK + j) * 68 + nt * 16 + bL];
            bf16x8 bf = __builtin_bit_cast(bf16x8, bu);
            acc[nt] = __builtin_amdgcn_mfma_f32_16x16x32_bf16(af, bf, acc[nt], 0, 0, 0);
        }
    }
    __syncthreads();
#pragma unroll
    for (int nt = 0; nt < 4; ++nt)
#pragma unroll
        for (int r = 0; r < 4; ++r)
            det[(nq * 16 + (lane >> 4) * 4 + r) * 67 + nt * 16 + (lane & 15)] = acc[nt][r];
    __syncthreads();
    for (int s = t; s < 1024; s += 256) {
        int l = s >> 4, c4 = s & 15;
        float4 bi = *(const float4*)&ba[co0 + c4 * 4];
        float4 o = {det[(c4 * 4 + 0) * 67 + l] + bi.x,
                    det[(c4 * 4 + 1) * 67 + l] + bi.y,
                    det[(c4 * 4 + 2) * 67 + l] + bi.z,
                    det[(c4 * 4 + 3) * 67 + l] + bi.w};
        *(float4*)&ye[((size_t)n * L_ + l0 + l) * 256 + co0 + c4 * 4] = o;
    }
}

// ---------------- kmeans assign (fp64 dot; norm is argmax-invariant) ----------------
__global__ __launch_bounds__(256) void k_assign(const float* __restrict__ xe,
                                                const float* __restrict__ means,
                                                int* __restrict__ codes_i,
                                                float* __restrict__ codes_f) {
    __shared__ float sm[128 * 64];
    for (int s = threadIdx.x; s < 8192; s += 256) sm[s] = means[s];
    __syncthreads();
    const int g = blockIdx.x * 256 + threadIdx.x;
    const float* row = xe + (size_t)g * 64;
    float v[64];
#pragma unroll
    for (int c4 = 0; c4 < 16; c4++) {
        float4 t4 = *(const float4*)(row + c4 * 4);
        v[c4 * 4 + 0] = t4.x; v[c4 * 4 + 1] = t4.y; v[c4 * 4 + 2] = t4.z; v[c4 * 4 + 3] = t4.w;
    }
    int best = 0;
    double bd = -1e300;
    for (int cl = 0; cl < 128; cl++) {
        double d = 0.0;
#pragma unroll
        for (int c4 = 0; c4 < 16; c4++) {
            float4 m4 = *(const float4*)(sm + cl * 64 + c4 * 4);
            d += (double)v[c4 * 4 + 0] * (double)m4.x + (double)v[c4 * 4 + 1] * (double)m4.y +
                 (double)v[c4 * 4 + 2] * (double)m4.z + (double)v[c4 * 4 + 3] * (double)m4.w;
        }
        if (d > bd) { bd = d; best = cl; }
    }
    codes_i[g] = best;
    codes_f[g] = (float)best;
}

// ---------------- stable counting sort ----------------
__global__ void k_hist(const int* __restrict__ codes_i, int* __restrict__ hist) {
    __shared__ int h[128];
    if (threadIdx.x < 128) h[threadIdx.x] = 0;
    __syncthreads();
    int n = blockIdx.x / 36, ch = blockIdx.x % 36;
    int c = codes_i[n * L_ + ch * 256 + threadIdx.x];
    atomicAdd(&h[c], 1);
    __syncthreads();
    if (threadIdx.x < 128) hist[(n * 36 + ch) * 128 + threadIdx.x] = h[threadIdx.x];
}

__global__ void k_scan(const int* __restrict__ hist, int* __restrict__ basebuf) {
    __shared__ int tot[128];
    __shared__ int binstart[128];
    int n = blockIdx.x, c = threadIdx.x;
    int run = 0;
    int local[36];
    for (int ch = 0; ch < 36; ch++) { local[ch] = run; run += hist[(n * 36 + ch) * 128 + c]; }
    tot[c] = run;
    __syncthreads();
    if (c == 0) {
        int s = 0;
        for (int b = 0; b < 128; b++) { binstart[b] = s; s += tot[b]; }
    }
    __syncthreads();
    int bs0 = binstart[c];
    for (int ch = 0; ch < 36; ch++) basebuf[(n * 36 + ch) * 128 + c] = bs0 + local[ch];
}

__global__ void k_rank(const int* __restrict__ codes_i, const int* __restrict__ basebuf,
                       int* __restrict__ idxb, int* __restrict__ undo) {
    __shared__ int sc[256];
    __shared__ int sb[128];
    int n = blockIdx.x / 36, ch = blockIdx.x % 36;
    int i = threadIdx.x;
    int l = ch * 256 + i;
    int c = codes_i[n * L_ + l];
    sc[i] = c;
    if (i < 128) sb[i] = basebuf[(n * 36 + ch) * 128 + i];
    __syncthreads();
    int r = 0;
    for (int j = 0; j < i; j++) r += (sc[j] == c);
    int pos = sb[c] + r;
    idxb[n * L_ + pos] = l;
    undo[n * L_ + l] = pos;
}

// ---------------- QK via bf16 MFMA: raw[i,j] = (xn_i . xn_j) * s_i ----------------
// grid 512 (n*64+k), block 256 (4 waves). M=144 (9 mt), N=432 (27 nt), K=64.
// Single normalized key buffer; Q-unnorm recovered by row scale s_i = max(|q_i|,eps).
__global__ __launch_bounds__(256) void k_qk_mfma(const float* __restrict__ xe,
                                                 const int* __restrict__ idxb,
                                                 float* __restrict__ raw) {
    __shared__ __align__(16) unsigned short kb[432 * 72];  // normalized rows bf16 [row][e]
    __shared__ float snorm[144];
    __shared__ int sidx[432];
    const int bid = blockIdx.x;
    const int n = bid >> 6, k = bid & 63;
    const int t = threadIdx.x, lane = t & 63, nq = t >> 6;

    for (int s = t; s < 432; s += 256) {
        int wb = s / 144, jj = s % 144;
        int wk = (wb == 0) ? k : (wb == 1) ? ((k + 63) & 63) : ((k + 1) & 63);
        sidx[s] = idxb[n * L_ + wk * WIN + jj];
    }
    __syncthreads();
    // stage + normalize: 432 rows x 16 f4 slots; 16 threads per row
    for (int s = t; s < 6912; s += 256) {
        int row = s >> 4, q4 = s & 15;
        float4 v = *(const float4*)(xe + ((size_t)n * L_ + sidx[row]) * 64 + q4 * 4);
        float ss = v.x * v.x + v.y * v.y + v.z * v.z + v.w * v.w;
        ss += __shfl_xor(ss, 1); ss += __shfl_xor(ss, 2);
        ss += __shfl_xor(ss, 4); ss += __shfl_xor(ss, 8);
        float nr = fmaxf(sqrtf(ss), 5e-5f);
        float inv = 1.0f / nr;
        ushort4 b = {f2bf(v.x * inv), f2bf(v.y * inv), f2bf(v.z * inv), f2bf(v.w * inv)};
        *(ushort4*)&kb[row * 72 + q4 * 4] = b;
        if (q4 == 0 && row < 144) snorm[row] = nr;
    }
    __syncthreads();
    // A frags resident: 9 mt x 2 ks (rows = q = wb0 keys, normalized; scaled after MFMA)
    const int arow = lane & 15, aks = (lane >> 4) * 8;
    bf16x8 af[9][2];
#pragma unroll
    for (int mt = 0; mt < 9; ++mt) {
        af[mt][0] = *(const bf16x8*)&kb[(mt * 16 + arow) * 72 + aks];
        af[mt][1] = *(const bf16x8*)&kb[(mt * 16 + arow) * 72 + 32 + aks];
    }
    float sc[9][4];
#pragma unroll
    for (int mt = 0; mt < 9; ++mt)
#pragma unroll
        for (int r = 0; r < 4; ++r)
            sc[mt][r] = snorm[mt * 16 + (lane >> 4) * 4 + r];
    float* rbase = raw + (size_t)(n * NWIN + k) * WIN * KJ;
    for (int nt = nq; nt < 27; nt += 4) {
        const int col = nt * 16 + (lane & 15);
        bf16x8 b0 = *(const bf16x8*)&kb[col * 72 + aks];
        bf16x8 b1 = *(const bf16x8*)&kb[col * 72 + 32 + aks];
#pragma unroll
        for (int mt = 0; mt < 9; ++mt) {
            f32x4 acc = {0.f, 0.f, 0.f, 0.f};
            acc = __builtin_amdgcn_mfma_f32_16x16x32_bf16(af[mt][0], b0, acc, 0, 0, 0);
            acc = __builtin_amdgcn_mfma_f32_16x16x32_bf16(af[mt][1], b1, acc, 0, 0, 0);
#pragma unroll
            for (int r = 0; r < 4; ++r)
                rbase[(size_t)(mt * 16 + (lane >> 4) * 4 + r) * KJ + nt * 16 + (lane & 15)] =
                    acc[r] * sc[mt][r];
        }
    }
}

// ---------------- row softmax in place + bs ----------------
__global__ __launch_bounds__(256) void k_softmax(float* __restrict__ score, float* __restrict__ bs) {
    const int row = blockIdx.x * 4 + (threadIdx.x >> 6);
    const int lane = threadIdx.x & 63;
    float* p = score + (size_t)row * KJ;
    float v[7];
    float m = -1e30f;
#pragma unroll
    for (int it = 0; it < 7; it++) {
        int j = lane + it * 64;
        v[it] = (j < KJ) ? p[j] : -1e30f;
        m = fmaxf(m, v[it]);
    }
#pragma unroll
    for (int o = 32; o >= 1; o >>= 1) m = fmaxf(m, __shfl_xor(m, o));
    float s = 0.f;
#pragma unroll
    for (int it = 0; it < 7; it++) {
        v[it] = __expf(v[it] - m);
        s += (lane + it * 64 < KJ) ? v[it] : 0.f;
    }
#pragma unroll
    for (int o = 32; o >= 1; o >>= 1) s += __shfl_xor(s, o);
    float inv = 1.f / s;
#pragma unroll
    for (int it = 0; it < 7; it++) {
        int j = lane + it * 64;
        if (j < KJ) p[j] = v[it] * inv;
    }
    if (lane == 0) bs[row] = m + logf(s);
}

// ---------------- PV via bf16 MFMA: ret_sorted = score @ Y3 ----------------
__global__ __launch_bounds__(256) void k_pv_mfma(const float* __restrict__ ye,
                                                 const int* __restrict__ idxb,
                                                 const float* __restrict__ score,
                                                 float* __restrict__ ret) {
    __shared__ __align__(16) unsigned short pA[144 * 72];   // P[i][kk], stride 72
    __shared__ __align__(16) unsigned short pB[64 * 258];   // Y[kk][co], stride 258
    __shared__ int sidx[432];
    const int bid = blockIdx.x;
    const int n = bid >> 6, k = bid & 63;
    const int t = threadIdx.x, lane = t & 63, nq = t >> 6;

    for (int s = t; s < 432; s += 256) {
        int wb = s / 144, jj = s % 144;
        int wk = (wb == 0) ? k : (wb == 1) ? ((k + 63) & 63) : ((k + 1) & 63);
        sidx[s] = idxb[n * L_ + wk * WIN + jj];
    }

    f32x4 acc[9][4];
#pragma unroll
    for (int mt = 0; mt < 9; ++mt)
#pragma unroll
        for (int nt = 0; nt < 4; ++nt) {
            f32x4 z = {0.f, 0.f, 0.f, 0.f};
            acc[mt][nt] = z;
        }

    const float* srow = score + (size_t)(n * NWIN + k) * WIN * KJ;
    const float* yb = ye + (size_t)n * L_ * 256;
    const int aBase = (lane & 15) * 72 + (lane >> 4) * 8;
    const int bBase = (lane >> 4) * 8 * 258 + nq * 64 + (lane & 15);

    for (int kc = 0; kc < 7; ++kc) {
        __syncthreads();
        for (int s = t; s < 2304; s += 256) {
            int i = s >> 4, c4 = s & 15;
            int kcol = kc * 64 + c4 * 4;
            float4 v = {0.f, 0.f, 0.f, 0.f};
            if (kcol < KJ) v = *(const float4*)(srow + (size_t)i * KJ + kcol);
            ushort4 b = {f2bf(v.x), f2bf(v.y), f2bf(v.z), f2bf(v.w)};
            *(ushort4*)&pA[i * 72 + c4 * 4] = b;
        }
        for (int s = t; s < 4096; s += 256) {
            int j = s >> 6, c4g = s & 63;
            int kk = kc * 64 + j;
            float4 v = {0.f, 0.f, 0.f, 0.f};
            if (kk < KJ) v = *(const float4*)(yb + (size_t)sidx[kk] * 256 + c4g * 4);
            ushort2 b0 = {f2bf(v.x), f2bf(v.y)};
            ushort2 b1 = {f2bf(v.z), f2bf(v.w)};
            *(ushort2*)&pB[j * 258 + c4g * 4] = b0;
            *(ushort2*)&pB[j * 258 + c4g * 4 + 2] = b1;
        }
        __syncthreads();
#pragma unroll
        for (int ks = 0; ks < 2; ++ks) {
            bf16x8 af[9];
#pragma unroll
            for (int mt = 0; mt < 9; ++mt)
                af[mt] = *(const bf16x8*)&pA[aBase + mt * 1152 + ks * 32];
#pragma unroll
            for (int nt = 0; nt < 4; ++nt) {
                const int e = bBase + ks * 32 * 258 + nt * 16;
                u16x8 bu;
#pragma unroll
                for (int j = 0; j < 8; ++j) bu[j] = pB[e + j * 258];
                bf16x8 bf = __builtin_bit_cast(bf16x8, bu);
#pragma unroll
                for (int mt = 0; mt < 9; ++mt)
                    acc[mt][nt] = __builtin_amdgcn_mfma_f32_16x16x32_bf16(af[mt], bf, acc[mt][nt], 0, 0, 0);
            }
        }
    }
    float* rbase = ret + ((size_t)n * L_ + (size_t)k * WIN) * 256;
    const int rowb = (lane >> 4) * 4;
    const int colb = nq * 64 + (lane & 15);
#pragma unroll
    for (int mt = 0; mt < 9; ++mt)
#pragma unroll
        for (int nt = 0; nt < 4; ++nt)
#pragma unroll
            for (int r = 0; r < 4; ++r)
                rbase[(size_t)(mt * 16 + rowb + r) * 256 + colb + nt * 16] = acc[mt][nt][r];
}

// ---------------- final scatter: out = x + 0.1 * ret[undo] ----------------
__global__ __launch_bounds__(256) void k_out(const float* __restrict__ x,
                                             const float* __restrict__ ret,
                                             const int* __restrict__ undo,
                                             float* __restrict__ out) {
    __shared__ float sr[32 * 257];
    const int n = blockIdx.x / 288, lt = blockIdx.x % 288;
    const int lbase = lt * 32;
    const int t = threadIdx.x;
    for (int s = t; s < 32 * 64; s += 256) {
        int lr = s >> 6, q = s & 63;
        int p = undo[n * L_ + lbase + lr];
        *(float4*)(sr + lr * 257 + q * 4) = *(const float4*)(ret + ((size_t)n * L_ + p) * 256 + q * 4);
    }
    __syncthreads();
    const int lr = t & 31, cog = t >> 5;
    for (int cc = 0; cc < 32; cc++) {
        int co = cog * 32 + cc;
        size_t gi = ((size_t)(n * 256 + co)) * L_ + lbase + lr;
        out[gi] = x[gi] + 0.1f * sr[lr * 257 + co];
    }
}

extern "C" void kernel_launch(void* const* d_in, const int* in_sizes, int n_in,
                              void* d_out, int out_size, void* d_ws, size_t ws_size,
                              hipStream_t stream) {
    (void)in_sizes; (void)n_in; (void)out_size; (void)ws_size;
    const float* x     = (const float*)d_in[0];
    const float* means = (const float*)d_in[1];
    const float* wm    = (const float*)d_in[2];
    const float* bm    = (const float*)d_in[3];
    const float* wa    = (const float*)d_in[4];
    const float* ba    = (const float*)d_in[5];

    float* out   = (float*)d_out;
    float* score = out + (size_t)8 * 256 * L_;
    float* bs    = score + (size_t)8 * NWIN * WIN * KJ;
    float* codesf = bs + (size_t)8 * L_;

    float* xe  = (float*)d_ws;
    float* ye  = xe + (size_t)8 * L_ * 64;
    float* ret = ye + (size_t)8 * L_ * 256;
    float* wtr = ret + (size_t)8 * L_ * 256;
    int* codes_i = (int*)(wtr + 147456);
    int* idxb    = codes_i + 8 * L_;
    int* undo    = idxb + 8 * L_;
    int* hist    = undo + 8 * L_;
    int* basebuf = hist + 8 * 36 * 128;

    k_wprep  <<<576, 256, 0, stream>>>(wm, wtr);
    k_conv3x3<<<768, 256, 0, stream>>>(x, wtr, bm, xe);
    k_conv1x1<<<4608, 256, 0, stream>>>(x, wa, ba, ye);
    k_assign <<<288, 256, 0, stream>>>(xe, means, codes_i, codesf);
    k_hist   <<<288, 256, 0, stream>>>(codes_i, hist);
    k_scan   <<<8, 128, 0, stream>>>(hist, basebuf);
    k_rank   <<<288, 256, 0, stream>>>(codes_i, basebuf, idxb, undo);
    k_qk_mfma<<<512, 256, 0, stream>>>(xe, idxb, score);
    k_softmax<<<18432, 256, 0, stream>>>(score, bs);
    k_pv_mfma<<<512, 256, 0, stream>>>(ye, idxb, score, ret);
    k_out    <<<2304, 256, 0, stream>>>(x, ret, undo, out);
}

// Round 8
// 908.901 us; speedup vs baseline: 4.5544x; 1.0076x over previous
//
#include <hip/hip_runtime.h>
#include <math.h>

#define L_    9216
#define WIN   144
#define NWIN  64
#define KJ    432

typedef __bf16 bf16x8 __attribute__((ext_vector_type(8)));
typedef unsigned short u16x8 __attribute__((ext_vector_type(8)));
typedef float f32x4 __attribute__((ext_vector_type(4)));

__device__ __forceinline__ unsigned short f2bf(float f) {
    unsigned int u = __builtin_bit_cast(unsigned int, f);
    u = (u + 0x7FFFu + ((u >> 16) & 1u)) >> 16;
    return (unsigned short)u;
}

// ---------------- weight pre-transpose for conv3x3 ----------------
__global__ void k_wprep(const float* __restrict__ wm, float* __restrict__ wtr) {
    int s = blockIdx.x * 256 + threadIdx.x;       // 147456 total
    if (s < 147456) {
        int cq = s & 63, r = s >> 6;              // r = c*9+kk
        wtr[s] = wm[(size_t)cq * 2304 + r];
    }
}

// ---------------- conv3x3 v6: x[8,256,96,96] -> xe[8,9216,64] ----------------
// grid 768 (n*96+h), block 128 (16 cg x 8 wg); thread tile 12w x 4cq.
// 4 ch/iter, double-buffered LDS, DIRECT global->LDS staging (no reg relay,
// keeps VGPR low: v1 precedent = 72 VGPR with same acc footprint).
__global__ __launch_bounds__(128) void k_conv3x3(const float* __restrict__ x,
                                                 const float* __restrict__ wtr,
                                                 const float* __restrict__ bm,
                                                 float* __restrict__ xe) {
    __shared__ __align__(16) float sx[2][4][3][104];  // col = idx-1
    __shared__ __align__(16) float sw[2][4][9][64];
    const int n = blockIdx.x / 96, h = blockIdx.x % 96;
    const int t = threadIdx.x;
    const int cg = t & 15, wg = t >> 4;
    const int w0 = wg * 12, cq0 = cg * 4;
    const float* xb = x + (size_t)n * 256 * 9216;
    const float4 fz = {0.f, 0.f, 0.f, 0.f};

    // zero edge columns (idx 0 and 97..103), BOTH buffers: 192 slots
    for (int s = t; s < 192; s += 128) {
        int b = s / 96, rem = s % 96;
        int ch = rem / 24, rr = (rem / 8) % 3, e = rem % 8;
        int idx = (e == 0) ? 0 : 96 + e;
        sx[b][ch][rr][idx] = 0.f;
    }

#define C3_STAGE(buf, cb)                                                         \
    do {                                                                          \
        for (int s = t; s < 288; s += 128) {                                      \
            int ch = s / 72, r = (s / 24) % 3, q = s % 24;                        \
            int hh = h + r - 1;                                                   \
            bool vld = (hh >= 0) && (hh < 96);                                    \
            float4 v = vld ? *(const float4*)(xb + (size_t)((cb) + ch) * 9216 +   \
                                              hh * 96 + q * 4)                    \
                           : fz;                                                  \
            float* d = &sx[buf][ch][r][q * 4 + 1];                                \
            d[0] = v.x; d[1] = v.y; d[2] = v.z; d[3] = v.w;                       \
        }                                                                         \
        for (int s = t; s < 576; s += 128) {                                      \
            int ch = s / 144, kk = (s % 144) >> 4, q = s & 15;                    \
            float4 v = *(const float4*)(wtr + (size_t)((cb) + ch) * 576 +         \
                                        kk * 64 + q * 4);                         \
            *(float4*)&sw[buf][ch][kk][q * 4] = v;                                \
        }                                                                         \
    } while (0)

    float acc[12][4];
#pragma unroll
    for (int j = 0; j < 12; ++j)
#pragma unroll
        for (int q = 0; q < 4; ++q) acc[j][q] = 0.f;

    C3_STAGE(0, 0);
    __syncthreads();

    for (int it = 0; it < 64; ++it) {
        const int cur = it & 1;
        if (it < 63) C3_STAGE(cur ^ 1, (it + 1) * 4);
#pragma unroll
        for (int ch = 0; ch < 4; ++ch) {
#pragma unroll
            for (int dh = 0; dh < 3; ++dh) {
                float4 wv0 = *(const float4*)&sw[cur][ch][dh * 3 + 0][cq0];
                float4 wv1 = *(const float4*)&sw[cur][ch][dh * 3 + 1][cq0];
                float4 wv2 = *(const float4*)&sw[cur][ch][dh * 3 + 2][cq0];
                float xr[16];
#pragma unroll
                for (int q = 0; q < 4; ++q) {
                    float4 v = *(const float4*)&sx[cur][ch][dh][w0 + q * 4];
                    xr[q * 4 + 0] = v.x; xr[q * 4 + 1] = v.y;
                    xr[q * 4 + 2] = v.z; xr[q * 4 + 3] = v.w;
                }
#pragma unroll
                for (int j = 0; j < 12; ++j) {
                    acc[j][0] += xr[j + 0] * wv0.x;
                    acc[j][1] += xr[j + 0] * wv0.y;
                    acc[j][2] += xr[j + 0] * wv0.z;
                    acc[j][3] += xr[j + 0] * wv0.w;
                }
#pragma unroll
                for (int j = 0; j < 12; ++j) {
                    acc[j][0] += xr[j + 1] * wv1.x;
                    acc[j][1] += xr[j + 1] * wv1.y;
                    acc[j][2] += xr[j + 1] * wv1.z;
                    acc[j][3] += xr[j + 1] * wv1.w;
                }
#pragma unroll
                for (int j = 0; j < 12; ++j) {
                    acc[j][0] += xr[j + 2] * wv2.x;
                    acc[j][1] += xr[j + 2] * wv2.y;
                    acc[j][2] += xr[j + 2] * wv2.z;
                    acc[j][3] += xr[j + 2] * wv2.w;
                }
            }
        }
        __syncthreads();
    }
#undef C3_STAGE

    const float4 bi = *(const float4*)(bm + cq0);
#pragma unroll
    for (int j = 0; j < 12; ++j) {
        float4 o = {acc[j][0] + bi.x, acc[j][1] + bi.y, acc[j][2] + bi.z, acc[j][3] + bi.w};
        *(float4*)&xe[((size_t)n * L_ + (size_t)h * 96 + w0 + j) * 64 + cq0] = o;
    }
}

// ---------------- conv1x1 via bf16 MFMA: ye[8,9216,256] fp32 ----------------
__global__ __launch_bounds__(256) void k_conv1x1(const float* __restrict__ x,
                                                 const float* __restrict__ wa,
                                                 const float* __restrict__ ba,
                                                 float* __restrict__ ye) {
    __shared__ __align__(16) unsigned short pA[64 * 40];  // [co][k], pad 40
    __shared__ __align__(16) unsigned short pB[32 * 68];  // [k][l],  pad 68
    __shared__ __align__(16) float det[64 * 67];          // [co][l], pad 67
    const int bid = blockIdx.x;
    const int n = bid / 576, rem = bid % 576;
    const int l0 = (rem >> 2) * 64, co0 = (rem & 3) * 64;
    const int t = threadIdx.x, lane = t & 63, nq = t >> 6;

    f32x4 acc[4];
#pragma unroll
    for (int nt = 0; nt < 4; ++nt) { f32x4 z = {0.f, 0.f, 0.f, 0.f}; acc[nt] = z; }

    const int aOff = (nq * 16 + (lane & 15)) * 40 + (lane >> 4) * 8;
    const int bK = (lane >> 4) * 8, bL = lane & 15;

    for (int kc = 0; kc < 8; ++kc) {
        const int c0 = kc * 32;
        __syncthreads();
        for (int s = t; s < 512; s += 256) {
            int co = s >> 3, q = s & 7;
            float4 v = *(const float4*)&wa[(size_t)(co0 + co) * 256 + c0 + q * 4];
            ushort4 b = {f2bf(v.x), f2bf(v.y), f2bf(v.z), f2bf(v.w)};
            *(ushort4*)&pA[co * 40 + q * 4] = b;
        }
        for (int s = t; s < 512; s += 256) {
            int c = s >> 4, l4 = s & 15;
            float4 v = *(const float4*)&x[((size_t)n * 256 + c0 + c) * L_ + l0 + l4 * 4];
            ushort4 b = {f2bf(v.x), f2bf(v.y), f2bf(v.z), f2bf(v.w)};
            *(ushort4*)&pB[c * 68 + l4 * 4] = b;
        }
        __syncthreads();
        u16x8 au = *(const u16x8*)&pA[aOff];
        bf16x8 af = __builtin_bit_cast(bf16x8, au);
#pragma unroll
        for (int nt = 0; nt < 4; ++nt) {
            u16x8 bu;
#pragma unroll
            for (int j = 0; j < 8; ++j) bu[j] = pB[(bK + j) * 68 + nt * 16 + bL];
            bf16x8 bf = __builtin_bit_cast(bf16x8, bu);
            acc[nt] = __builtin_amdgcn_mfma_f32_16x16x32_bf16(af, bf, acc[nt], 0, 0, 0);
        }
    }
    __syncthreads();
#pragma unroll
    for (int nt = 0; nt < 4; ++nt)
#pragma unroll
        for (int r = 0; r < 4; ++r)
            det[(nq * 16 + (lane >> 4) * 4 + r) * 67 + nt * 16 + (lane & 15)] = acc[nt][r];
    __syncthreads();
    for (int s = t; s < 1024; s += 256) {
        int l = s >> 4, c4 = s & 15;
        float4 bi = *(const float4*)&ba[co0 + c4 * 4];
        float4 o = {det[(c4 * 4 + 0) * 67 + l] + bi.x,
                    det[(c4 * 4 + 1) * 67 + l] + bi.y,
                    det[(c4 * 4 + 2) * 67 + l] + bi.z,
                    det[(c4 * 4 + 3) * 67 + l] + bi.w};
        *(float4*)&ye[((size_t)n * L_ + l0 + l) * 256 + co0 + c4 * 4] = o;
    }
}

// ---------------- kmeans assign (fp64 dot; norm is argmax-invariant) ----------------
__global__ __launch_bounds__(256) void k_assign(const float* __restrict__ xe,
                                                const float* __restrict__ means,
                                                int* __restrict__ codes_i,
                                                float* __restrict__ codes_f) {
    __shared__ float sm[128 * 64];
    for (int s = threadIdx.x; s < 8192; s += 256) sm[s] = means[s];
    __syncthreads();
    const int g = blockIdx.x * 256 + threadIdx.x;
    const float* row = xe + (size_t)g * 64;
    float v[64];
#pragma unroll
    for (int c4 = 0; c4 < 16; c4++) {
        float4 t4 = *(const float4*)(row + c4 * 4);
        v[c4 * 4 + 0] = t4.x; v[c4 * 4 + 1] = t4.y; v[c4 * 4 + 2] = t4.z; v[c4 * 4 + 3] = t4.w;
    }
    int best = 0;
    double bd = -1e300;
    for (int cl = 0; cl < 128; cl++) {
        double d = 0.0;
#pragma unroll
        for (int c4 = 0; c4 < 16; c4++) {
            float4 m4 = *(const float4*)(sm + cl * 64 + c4 * 4);
            d += (double)v[c4 * 4 + 0] * (double)m4.x + (double)v[c4 * 4 + 1] * (double)m4.y +
                 (double)v[c4 * 4 + 2] * (double)m4.z + (double)v[c4 * 4 + 3] * (double)m4.w;
        }
        if (d > bd) { bd = d; best = cl; }
    }
    codes_i[g] = best;
    codes_f[g] = (float)best;
}

// ---------------- stable counting sort ----------------
__global__ void k_hist(const int* __restrict__ codes_i, int* __restrict__ hist) {
    __shared__ int h[128];
    if (threadIdx.x < 128) h[threadIdx.x] = 0;
    __syncthreads();
    int n = blockIdx.x / 36, ch = blockIdx.x % 36;
    int c = codes_i[n * L_ + ch * 256 + threadIdx.x];
    atomicAdd(&h[c], 1);
    __syncthreads();
    if (threadIdx.x < 128) hist[(n * 36 + ch) * 128 + threadIdx.x] = h[threadIdx.x];
}

__global__ void k_scan(const int* __restrict__ hist, int* __restrict__ basebuf) {
    __shared__ int tot[128];
    __shared__ int binstart[128];
    int n = blockIdx.x, c = threadIdx.x;
    int run = 0;
    int local[36];
    for (int ch = 0; ch < 36; ch++) { local[ch] = run; run += hist[(n * 36 + ch) * 128 + c]; }
    tot[c] = run;
    __syncthreads();
    if (c == 0) {
        int s = 0;
        for (int b = 0; b < 128; b++) { binstart[b] = s; s += tot[b]; }
    }
    __syncthreads();
    int bs0 = binstart[c];
    for (int ch = 0; ch < 36; ch++) basebuf[(n * 36 + ch) * 128 + c] = bs0 + local[ch];
}

__global__ void k_rank(const int* __restrict__ codes_i, const int* __restrict__ basebuf,
                       int* __restrict__ idxb, int* __restrict__ undo) {
    __shared__ int sc[256];
    __shared__ int sb[128];
    int n = blockIdx.x / 36, ch = blockIdx.x % 36;
    int i = threadIdx.x;
    int l = ch * 256 + i;
    int c = codes_i[n * L_ + l];
    sc[i] = c;
    if (i < 128) sb[i] = basebuf[(n * 36 + ch) * 128 + i];
    __syncthreads();
    int r = 0;
    for (int j = 0; j < i; j++) r += (sc[j] == c);
    int pos = sb[c] + r;
    idxb[n * L_ + pos] = l;
    undo[n * L_ + l] = pos;
}

// ---------------- QK via bf16 MFMA: raw[i,j] = (xn_i . xn_j) * s_i ----------------
__global__ __launch_bounds__(256) void k_qk_mfma(const float* __restrict__ xe,
                                                 const int* __restrict__ idxb,
                                                 float* __restrict__ raw) {
    __shared__ __align__(16) unsigned short kb[432 * 72];
    __shared__ float snorm[144];
    __shared__ int sidx[432];
    const int bid = blockIdx.x;
    const int n = bid >> 6, k = bid & 63;
    const int t = threadIdx.x, lane = t & 63, nq = t >> 6;

    for (int s = t; s < 432; s += 256) {
        int wb = s / 144, jj = s % 144;
        int wk = (wb == 0) ? k : (wb == 1) ? ((k + 63) & 63) : ((k + 1) & 63);
        sidx[s] = idxb[n * L_ + wk * WIN + jj];
    }
    __syncthreads();
    for (int s = t; s < 6912; s += 256) {
        int row = s >> 4, q4 = s & 15;
        float4 v = *(const float4*)(xe + ((size_t)n * L_ + sidx[row]) * 64 + q4 * 4);
        float ss = v.x * v.x + v.y * v.y + v.z * v.z + v.w * v.w;
        ss += __shfl_xor(ss, 1); ss += __shfl_xor(ss, 2);
        ss += __shfl_xor(ss, 4); ss += __shfl_xor(ss, 8);
        float nr = fmaxf(sqrtf(ss), 5e-5f);
        float inv = 1.0f / nr;
        ushort4 b = {f2bf(v.x * inv), f2bf(v.y * inv), f2bf(v.z * inv), f2bf(v.w * inv)};
        *(ushort4*)&kb[row * 72 + q4 * 4] = b;
        if (q4 == 0 && row < 144) snorm[row] = nr;
    }
    __syncthreads();
    const int arow = lane & 15, aks = (lane >> 4) * 8;
    bf16x8 af[9][2];
#pragma unroll
    for (int mt = 0; mt < 9; ++mt) {
        af[mt][0] = *(const bf16x8*)&kb[(mt * 16 + arow) * 72 + aks];
        af[mt][1] = *(const bf16x8*)&kb[(mt * 16 + arow) * 72 + 32 + aks];
    }
    float sc[9][4];
#pragma unroll
    for (int mt = 0; mt < 9; ++mt)
#pragma unroll
        for (int r = 0; r < 4; ++r)
            sc[mt][r] = snorm[mt * 16 + (lane >> 4) * 4 + r];
    float* rbase = raw + (size_t)(n * NWIN + k) * WIN * KJ;
    for (int nt = nq; nt < 27; nt += 4) {
        const int col = nt * 16 + (lane & 15);
        bf16x8 b0 = *(const bf16x8*)&kb[col * 72 + aks];
        bf16x8 b1 = *(const bf16x8*)&kb[col * 72 + 32 + aks];
#pragma unroll
        for (int mt = 0; mt < 9; ++mt) {
            f32x4 acc = {0.f, 0.f, 0.f, 0.f};
            acc = __builtin_amdgcn_mfma_f32_16x16x32_bf16(af[mt][0], b0, acc, 0, 0, 0);
            acc = __builtin_amdgcn_mfma_f32_16x16x32_bf16(af[mt][1], b1, acc, 0, 0, 0);
#pragma unroll
            for (int r = 0; r < 4; ++r)
                rbase[(size_t)(mt * 16 + (lane >> 4) * 4 + r) * KJ + nt * 16 + (lane & 15)] =
                    acc[r] * sc[mt][r];
        }
    }
}

// ---------------- PV + fused softmax: probs->score, bs, ret = P @ Y3 ----------------
// Reads raw logits from score region, computes per-row (m, 1/s), writes f32 probs
// back to score (the required output) during pA staging, bf16 P into LDS for MFMA.
__global__ __launch_bounds__(256) void k_pv_sm(const float* __restrict__ ye,
                                               const int* __restrict__ idxb,
                                               float* __restrict__ score,
                                               float* __restrict__ bs,
                                               float* __restrict__ ret) {
    __shared__ __align__(16) unsigned short pA[144 * 72];   // P[i][kk], stride 72
    __shared__ __align__(16) unsigned short pB[64 * 258];   // Y[kk][co], stride 258
    __shared__ int sidx[432];
    __shared__ float smax[144], sinv[144];
    const int bid = blockIdx.x;
    const int n = bid >> 6, k = bid & 63;
    const int t = threadIdx.x, lane = t & 63, nq = t >> 6;

    for (int s = t; s < 432; s += 256) {
        int wb = s / 144, jj = s % 144;
        int wk = (wb == 0) ? k : (wb == 1) ? ((k + 63) & 63) : ((k + 1) & 63);
        sidx[s] = idxb[n * L_ + wk * WIN + jj];
    }

    float* srow = score + (size_t)(n * NWIN + k) * WIN * KJ;
    // ---- stats pass: wave nq handles rows nq*36 .. nq*36+35 ----
    for (int rr = 0; rr < 36; ++rr) {
        const int row = nq * 36 + rr;
        float v[7];
        float m = -1e30f;
#pragma unroll
        for (int it = 0; it < 7; ++it) {
            int j = lane + it * 64;
            v[it] = (j < KJ) ? srow[(size_t)row * KJ + j] : -1e30f;
            m = fmaxf(m, v[it]);
        }
#pragma unroll
        for (int o = 32; o >= 1; o >>= 1) m = fmaxf(m, __shfl_xor(m, o));
        float s = 0.f;
#pragma unroll
        for (int it = 0; it < 7; ++it)
            s += (lane + it * 64 < KJ) ? __expf(v[it] - m) : 0.f;
#pragma unroll
        for (int o = 32; o >= 1; o >>= 1) s += __shfl_xor(s, o);
        if (lane == 0) {
            smax[row] = m;
            sinv[row] = 1.f / s;
            bs[(size_t)(n * NWIN + k) * WIN + row] = m + logf(s);
        }
    }

    f32x4 acc[9][4];
#pragma unroll
    for (int mt = 0; mt < 9; ++mt)
#pragma unroll
        for (int nt = 0; nt < 4; ++nt) {
            f32x4 z = {0.f, 0.f, 0.f, 0.f};
            acc[mt][nt] = z;
        }

    const float* yb = ye + (size_t)n * L_ * 256;
    const int aBase = (lane & 15) * 72 + (lane >> 4) * 8;
    const int bBase = (lane >> 4) * 8 * 258 + nq * 64 + (lane & 15);

    for (int kc = 0; kc < 7; ++kc) {
        __syncthreads();
        // stage P chunk: raw -> prob (f32 to score out) -> bf16 to pA
        for (int s = t; s < 2304; s += 256) {
            int i = s >> 4, c4 = s & 15;
            int kcol = kc * 64 + c4 * 4;
            ushort4 b = {0, 0, 0, 0};
            if (kcol < KJ) {
                float4 v = *(const float4*)(srow + (size_t)i * KJ + kcol);
                float m = smax[i], iv = sinv[i];
                float4 p = {__expf(v.x - m) * iv, __expf(v.y - m) * iv,
                            __expf(v.z - m) * iv, __expf(v.w - m) * iv};
                *(float4*)(srow + (size_t)i * KJ + kcol) = p;
                b.x = f2bf(p.x); b.y = f2bf(p.y); b.z = f2bf(p.z); b.w = f2bf(p.w);
            }
            *(ushort4*)&pA[i * 72 + c4 * 4] = b;
        }
        // stage Y chunk [64 x 256] gathered rows -> bf16
        for (int s = t; s < 4096; s += 256) {
            int j = s >> 6, c4g = s & 63;
            int kk = kc * 64 + j;
            float4 v = {0.f, 0.f, 0.f, 0.f};
            if (kk < KJ) v = *(const float4*)(yb + (size_t)sidx[kk] * 256 + c4g * 4);
            ushort2 b0 = {f2bf(v.x), f2bf(v.y)};
            ushort2 b1 = {f2bf(v.z), f2bf(v.w)};
            *(ushort2*)&pB[j * 258 + c4g * 4] = b0;
            *(ushort2*)&pB[j * 258 + c4g * 4 + 2] = b1;
        }
        __syncthreads();
#pragma unroll
        for (int ks = 0; ks < 2; ++ks) {
            bf16x8 af[9];
#pragma unroll
            for (int mt = 0; mt < 9; ++mt)
                af[mt] = *(const bf16x8*)&pA[aBase + mt * 1152 + ks * 32];
#pragma unroll
            for (int nt = 0; nt < 4; ++nt) {
                const int e = bBase + ks * 32 * 258 + nt * 16;
                u16x8 bu;
#pragma unroll
                for (int j = 0; j < 8; ++j) bu[j] = pB[e + j * 258];
                bf16x8 bf = __builtin_bit_cast(bf16x8, bu);
#pragma unroll
                for (int mt = 0; mt < 9; ++mt)
                    acc[mt][nt] = __builtin_amdgcn_mfma_f32_16x16x32_bf16(af[mt], bf, acc[mt][nt], 0, 0, 0);
            }
        }
    }
    float* rbase = ret + ((size_t)n * L_ + (size_t)k * WIN) * 256;
    const int rowb = (lane >> 4) * 4;
    const int colb = nq * 64 + (lane & 15);
#pragma unroll
    for (int mt = 0; mt < 9; ++mt)
#pragma unroll
        for (int nt = 0; nt < 4; ++nt)
#pragma unroll
            for (int r = 0; r < 4; ++r)
                rbase[(size_t)(mt * 16 + rowb + r) * 256 + colb + nt * 16] = acc[mt][nt][r];
}

// ---------------- final scatter: out = x + 0.1 * ret[undo] ----------------
__global__ __launch_bounds__(256) void k_out(const float* __restrict__ x,
                                             const float* __restrict__ ret,
                                             const int* __restrict__ undo,
                                             float* __restrict__ out) {
    __shared__ float sr[32 * 257];
    const int n = blockIdx.x / 288, lt = blockIdx.x % 288;
    const int lbase = lt * 32;
    const int t = threadIdx.x;
    for (int s = t; s < 32 * 64; s += 256) {
        int lr = s >> 6, q = s & 63;
        int p = undo[n * L_ + lbase + lr];
        *(float4*)(sr + lr * 257 + q * 4) = *(const float4*)(ret + ((size_t)n * L_ + p) * 256 + q * 4);
    }
    __syncthreads();
    const int lr = t & 31, cog = t >> 5;
    for (int cc = 0; cc < 32; cc++) {
        int co = cog * 32 + cc;
        size_t gi = ((size_t)(n * 256 + co)) * L_ + lbase + lr;
        out[gi] = x[gi] + 0.1f * sr[lr * 257 + co];
    }
}

extern "C" void kernel_launch(void* const* d_in, const int* in_sizes, int n_in,
                              void* d_out, int out_size, void* d_ws, size_t ws_size,
                              hipStream_t stream) {
    (void)in_sizes; (void)n_in; (void)out_size; (void)ws_size;
    const float* x     = (const float*)d_in[0];
    const float* means = (const float*)d_in[1];
    const float* wm    = (const float*)d_in[2];
    const float* bm    = (const float*)d_in[3];
    const float* wa    = (const float*)d_in[4];
    const float* ba    = (const float*)d_in[5];

    float* out   = (float*)d_out;
    float* score = out + (size_t)8 * 256 * L_;
    float* bs    = score + (size_t)8 * NWIN * WIN * KJ;
    float* codesf = bs + (size_t)8 * L_;

    float* xe  = (float*)d_ws;
    float* ye  = xe + (size_t)8 * L_ * 64;
    float* ret = ye + (size_t)8 * L_ * 256;
    float* wtr = ret + (size_t)8 * L_ * 256;
    int* codes_i = (int*)(wtr + 147456);
    int* idxb    = codes_i + 8 * L_;
    int* undo    = idxb + 8 * L_;
    int* hist    = undo + 8 * L_;
    int* basebuf = hist + 8 * 36 * 128;

    k_wprep  <<<576, 256, 0, stream>>>(wm, wtr);
    k_conv3x3<<<768, 128, 0, stream>>>(x, wtr, bm, xe);
    k_conv1x1<<<4608, 256, 0, stream>>>(x, wa, ba, ye);
    k_assign <<<288, 256, 0, stream>>>(xe, means, codes_i, codesf);
    k_hist   <<<288, 256, 0, stream>>>(codes_i, hist);
    k_scan   <<<8, 128, 0, stream>>>(hist, basebuf);
    k_rank   <<<288, 256, 0, stream>>>(codes_i, basebuf, idxb, undo);
    k_qk_mfma<<<512, 256, 0, stream>>>(xe, idxb, score);
    k_pv_sm  <<<512, 256, 0, stream>>>(ye, idxb, score, bs, ret);
    k_out    <<<2304, 256, 0, stream>>>(x, ret, undo, out);
}

// Round 9
// 903.941 us; speedup vs baseline: 4.5794x; 1.0055x over previous
//
#include <hip/hip_runtime.h>
#include <math.h>

#define L_    9216
#define WIN   144
#define NWIN  64
#define KJ    432

typedef __bf16 bf16x8 __attribute__((ext_vector_type(8)));
typedef unsigned short u16x8 __attribute__((ext_vector_type(8)));
typedef float f32x4 __attribute__((ext_vector_type(4)));

__device__ __forceinline__ unsigned short f2bf(float f) {
    unsigned int u = __builtin_bit_cast(unsigned int, f);
    u = (u + 0x7FFFu + ((u >> 16) & 1u)) >> 16;
    return (unsigned short)u;
}

// ---------------- weight pre-transpose for conv3x3 ----------------
__global__ void k_wprep(const float* __restrict__ wm, float* __restrict__ wtr) {
    int s = blockIdx.x * 256 + threadIdx.x;       // 147456 total
    if (s < 147456) {
        int cq = s & 63, r = s >> 6;              // r = c*9+kk
        wtr[s] = wm[(size_t)cq * 2304 + r];
    }
}

// ---------------- conv3x3 v7: split-K x2, v6 direct staging ----------------
// grid 1536 ((n*96+h)*2+half), block 128 (16 cg x 8 wg); thread tile 12w x 4cq.
// half = channels [half*128, half*128+128), 32 iters of 4 ch. Partials out.
// NO launch_bounds cap (v5 lesson: reg cap below tile working set => spill).
__global__ __launch_bounds__(128) void k_conv3x3(const float* __restrict__ x,
                                                 const float* __restrict__ wtr,
                                                 float* __restrict__ parts) {
    __shared__ __align__(16) float sx[2][4][3][104];  // col = idx-1
    __shared__ __align__(16) float sw[2][4][9][64];
    const int bid = blockIdx.x;
    const int half = bid & 1;
    const int h = (bid >> 1) % 96, n = bid / 192;
    const int chb = half * 128;
    const int t = threadIdx.x;
    const int cg = t & 15, wg = t >> 4;
    const int w0 = wg * 12, cq0 = cg * 4;
    const float* xb = x + (size_t)n * 256 * 9216;
    const float4 fz = {0.f, 0.f, 0.f, 0.f};

    // zero edge columns (idx 0 and 97..103), BOTH buffers: 192 slots
    for (int s = t; s < 192; s += 128) {
        int b = s / 96, rem = s % 96;
        int ch = rem / 24, rr = (rem / 8) % 3, e = rem % 8;
        int idx = (e == 0) ? 0 : 96 + e;
        sx[b][ch][rr][idx] = 0.f;
    }

#define C3_STAGE(buf, cb)                                                         \
    do {                                                                          \
        for (int s = t; s < 288; s += 128) {                                      \
            int ch = s / 72, r = (s / 24) % 3, q = s % 24;                        \
            int hh = h + r - 1;                                                   \
            bool vld = (hh >= 0) && (hh < 96);                                    \
            float4 v = vld ? *(const float4*)(xb + (size_t)((cb) + ch) * 9216 +   \
                                              hh * 96 + q * 4)                    \
                           : fz;                                                  \
            float* d = &sx[buf][ch][r][q * 4 + 1];                                \
            d[0] = v.x; d[1] = v.y; d[2] = v.z; d[3] = v.w;                       \
        }                                                                         \
        for (int s = t; s < 576; s += 128) {                                      \
            int ch = s / 144, kk = (s % 144) >> 4, q = s & 15;                    \
            float4 v = *(const float4*)(wtr + (size_t)((cb) + ch) * 576 +         \
                                        kk * 64 + q * 4);                         \
            *(float4*)&sw[buf][ch][kk][q * 4] = v;                                \
        }                                                                         \
    } while (0)

    float acc[12][4];
#pragma unroll
    for (int j = 0; j < 12; ++j)
#pragma unroll
        for (int q = 0; q < 4; ++q) acc[j][q] = 0.f;

    C3_STAGE(0, chb);
    __syncthreads();

    for (int it = 0; it < 32; ++it) {
        const int cur = it & 1;
        if (it < 31) C3_STAGE(cur ^ 1, chb + (it + 1) * 4);
#pragma unroll
        for (int ch = 0; ch < 4; ++ch) {
#pragma unroll
            for (int dh = 0; dh < 3; ++dh) {
                float4 wv0 = *(const float4*)&sw[cur][ch][dh * 3 + 0][cq0];
                float4 wv1 = *(const float4*)&sw[cur][ch][dh * 3 + 1][cq0];
                float4 wv2 = *(const float4*)&sw[cur][ch][dh * 3 + 2][cq0];
                float xr[16];
#pragma unroll
                for (int q = 0; q < 4; ++q) {
                    float4 v = *(const float4*)&sx[cur][ch][dh][w0 + q * 4];
                    xr[q * 4 + 0] = v.x; xr[q * 4 + 1] = v.y;
                    xr[q * 4 + 2] = v.z; xr[q * 4 + 3] = v.w;
                }
#pragma unroll
                for (int j = 0; j < 12; ++j) {
                    acc[j][0] += xr[j + 0] * wv0.x;
                    acc[j][1] += xr[j + 0] * wv0.y;
                    acc[j][2] += xr[j + 0] * wv0.z;
                    acc[j][3] += xr[j + 0] * wv0.w;
                }
#pragma unroll
                for (int j = 0; j < 12; ++j) {
                    acc[j][0] += xr[j + 1] * wv1.x;
                    acc[j][1] += xr[j + 1] * wv1.y;
                    acc[j][2] += xr[j + 1] * wv1.z;
                    acc[j][3] += xr[j + 1] * wv1.w;
                }
#pragma unroll
                for (int j = 0; j < 12; ++j) {
                    acc[j][0] += xr[j + 2] * wv2.x;
                    acc[j][1] += xr[j + 2] * wv2.y;
                    acc[j][2] += xr[j + 2] * wv2.z;
                    acc[j][3] += xr[j + 2] * wv2.w;
                }
            }
        }
        __syncthreads();
    }
#undef C3_STAGE

    float* pb = parts + (size_t)half * 4718592;
#pragma unroll
    for (int j = 0; j < 12; ++j) {
        float4 o = {acc[j][0], acc[j][1], acc[j][2], acc[j][3]};
        *(float4*)&pb[((size_t)n * L_ + (size_t)h * 96 + w0 + j) * 64 + cq0] = o;
    }
}

// ---------------- combine split-K partials + bias -> xe ----------------
__global__ __launch_bounds__(256) void k_c3sum(const float* __restrict__ parts,
                                               const float* __restrict__ bm,
                                               float* __restrict__ xe) {
    size_t i = (size_t)blockIdx.x * 256 + threadIdx.x;   // f4 index; grid 4608
    float4 a = ((const float4*)parts)[i];
    float4 b = ((const float4*)parts)[i + 1179648];
    float4 bi = ((const float4*)bm)[i & 15];
    float4 o = {a.x + b.x + bi.x, a.y + b.y + bi.y, a.z + b.z + bi.z, a.w + b.w + bi.w};
    ((float4*)xe)[i] = o;
}

// ---------------- conv1x1 via bf16 MFMA: ye[8,9216,256] fp32 ----------------
__global__ __launch_bounds__(256) void k_conv1x1(const float* __restrict__ x,
                                                 const float* __restrict__ wa,
                                                 const float* __restrict__ ba,
                                                 float* __restrict__ ye) {
    __shared__ __align__(16) unsigned short pA[64 * 40];  // [co][k], pad 40
    __shared__ __align__(16) unsigned short pB[32 * 68];  // [k][l],  pad 68
    __shared__ __align__(16) float det[64 * 67];          // [co][l], pad 67
    const int bid = blockIdx.x;
    const int n = bid / 576, rem = bid % 576;
    const int l0 = (rem >> 2) * 64, co0 = (rem & 3) * 64;
    const int t = threadIdx.x, lane = t & 63, nq = t >> 6;

    f32x4 acc[4];
#pragma unroll
    for (int nt = 0; nt < 4; ++nt) { f32x4 z = {0.f, 0.f, 0.f, 0.f}; acc[nt] = z; }

    const int aOff = (nq * 16 + (lane & 15)) * 40 + (lane >> 4) * 8;
    const int bK = (lane >> 4) * 8, bL = lane & 15;

    for (int kc = 0; kc < 8; ++kc) {
        const int c0 = kc * 32;
        __syncthreads();
        for (int s = t; s < 512; s += 256) {
            int co = s >> 3, q = s & 7;
            float4 v = *(const float4*)&wa[(size_t)(co0 + co) * 256 + c0 + q * 4];
            ushort4 b = {f2bf(v.x), f2bf(v.y), f2bf(v.z), f2bf(v.w)};
            *(ushort4*)&pA[co * 40 + q * 4] = b;
        }
        for (int s = t; s < 512; s += 256) {
            int c = s >> 4, l4 = s & 15;
            float4 v = *(const float4*)&x[((size_t)n * 256 + c0 + c) * L_ + l0 + l4 * 4];
            ushort4 b = {f2bf(v.x), f2bf(v.y), f2bf(v.z), f2bf(v.w)};
            *(ushort4*)&pB[c * 68 + l4 * 4] = b;
        }
        __syncthreads();
        u16x8 au = *(const u16x8*)&pA[aOff];
        bf16x8 af = __builtin_bit_cast(bf16x8, au);
#pragma unroll
        for (int nt = 0; nt < 4; ++nt) {
            u16x8 bu;
#pragma unroll
            for (int j = 0; j < 8; ++j) bu[j] = pB[(bK + j) * 68 + nt * 16 + bL];
            bf16x8 bf = __builtin_bit_cast(bf16x8, bu);
            acc[nt] = __builtin_amdgcn_mfma_f32_16x16x32_bf16(af, bf, acc[nt], 0, 0, 0);
        }
    }
    __syncthreads();
#pragma unroll
    for (int nt = 0; nt < 4; ++nt)
#pragma unroll
        for (int r = 0; r < 4; ++r)
            det[(nq * 16 + (lane >> 4) * 4 + r) * 67 + nt * 16 + (lane & 15)] = acc[nt][r];
    __syncthreads();
    for (int s = t; s < 1024; s += 256) {
        int l = s >> 4, c4 = s & 15;
        float4 bi = *(const float4*)&ba[co0 + c4 * 4];
        float4 o = {det[(c4 * 4 + 0) * 67 + l] + bi.x,
                    det[(c4 * 4 + 1) * 67 + l] + bi.y,
                    det[(c4 * 4 + 2) * 67 + l] + bi.z,
                    det[(c4 * 4 + 3) * 67 + l] + bi.w};
        *(float4*)&ye[((size_t)n * L_ + l0 + l) * 256 + co0 + c4 * 4] = o;
    }
}

// ---------------- kmeans assign (fp64 dot; norm is argmax-invariant) ----------------
__global__ __launch_bounds__(256) void k_assign(const float* __restrict__ xe,
                                                const float* __restrict__ means,
                                                int* __restrict__ codes_i,
                                                float* __restrict__ codes_f) {
    __shared__ float sm[128 * 64];
    for (int s = threadIdx.x; s < 8192; s += 256) sm[s] = means[s];
    __syncthreads();
    const int g = blockIdx.x * 256 + threadIdx.x;
    const float* row = xe + (size_t)g * 64;
    float v[64];
#pragma unroll
    for (int c4 = 0; c4 < 16; c4++) {
        float4 t4 = *(const float4*)(row + c4 * 4);
        v[c4 * 4 + 0] = t4.x; v[c4 * 4 + 1] = t4.y; v[c4 * 4 + 2] = t4.z; v[c4 * 4 + 3] = t4.w;
    }
    int best = 0;
    double bd = -1e300;
    for (int cl = 0; cl < 128; cl++) {
        double d = 0.0;
#pragma unroll
        for (int c4 = 0; c4 < 16; c4++) {
            float4 m4 = *(const float4*)(sm + cl * 64 + c4 * 4);
            d += (double)v[c4 * 4 + 0] * (double)m4.x + (double)v[c4 * 4 + 1] * (double)m4.y +
                 (double)v[c4 * 4 + 2] * (double)m4.z + (double)v[c4 * 4 + 3] * (double)m4.w;
        }
        if (d > bd) { bd = d; best = cl; }
    }
    codes_i[g] = best;
    codes_f[g] = (float)best;
}

// ---------------- stable counting sort ----------------
__global__ void k_hist(const int* __restrict__ codes_i, int* __restrict__ hist) {
    __shared__ int h[128];
    if (threadIdx.x < 128) h[threadIdx.x] = 0;
    __syncthreads();
    int n = blockIdx.x / 36, ch = blockIdx.x % 36;
    int c = codes_i[n * L_ + ch * 256 + threadIdx.x];
    atomicAdd(&h[c], 1);
    __syncthreads();
    if (threadIdx.x < 128) hist[(n * 36 + ch) * 128 + threadIdx.x] = h[threadIdx.x];
}

__global__ void k_scan(const int* __restrict__ hist, int* __restrict__ basebuf) {
    __shared__ int tot[128];
    __shared__ int binstart[128];
    int n = blockIdx.x, c = threadIdx.x;
    int run = 0;
    int local[36];
    for (int ch = 0; ch < 36; ch++) { local[ch] = run; run += hist[(n * 36 + ch) * 128 + c]; }
    tot[c] = run;
    __syncthreads();
    if (c == 0) {
        int s = 0;
        for (int b = 0; b < 128; b++) { binstart[b] = s; s += tot[b]; }
    }
    __syncthreads();
    int bs0 = binstart[c];
    for (int ch = 0; ch < 36; ch++) basebuf[(n * 36 + ch) * 128 + c] = bs0 + local[ch];
}

__global__ void k_rank(const int* __restrict__ codes_i, const int* __restrict__ basebuf,
                       int* __restrict__ idxb, int* __restrict__ undo) {
    __shared__ int sc[256];
    __shared__ int sb[128];
    int n = blockIdx.x / 36, ch = blockIdx.x % 36;
    int i = threadIdx.x;
    int l = ch * 256 + i;
    int c = codes_i[n * L_ + l];
    sc[i] = c;
    if (i < 128) sb[i] = basebuf[(n * 36 + ch) * 128 + i];
    __syncthreads();
    int r = 0;
    for (int j = 0; j < i; j++) r += (sc[j] == c);
    int pos = sb[c] + r;
    idxb[n * L_ + pos] = l;
    undo[n * L_ + l] = pos;
}

// ---------------- QK via bf16 MFMA: raw[i,j] = (xn_i . xn_j) * s_i ----------------
__global__ __launch_bounds__(256) void k_qk_mfma(const float* __restrict__ xe,
                                                 const int* __restrict__ idxb,
                                                 float* __restrict__ raw) {
    __shared__ __align__(16) unsigned short kb[432 * 72];
    __shared__ float snorm[144];
    __shared__ int sidx[432];
    const int bid = blockIdx.x;
    const int n = bid >> 6, k = bid & 63;
    const int t = threadIdx.x, lane = t & 63, nq = t >> 6;

    for (int s = t; s < 432; s += 256) {
        int wb = s / 144, jj = s % 144;
        int wk = (wb == 0) ? k : (wb == 1) ? ((k + 63) & 63) : ((k + 1) & 63);
        sidx[s] = idxb[n * L_ + wk * WIN + jj];
    }
    __syncthreads();
    for (int s = t; s < 6912; s += 256) {
        int row = s >> 4, q4 = s & 15;
        float4 v = *(const float4*)(xe + ((size_t)n * L_ + sidx[row]) * 64 + q4 * 4);
        float ss = v.x * v.x + v.y * v.y + v.z * v.z + v.w * v.w;
        ss += __shfl_xor(ss, 1); ss += __shfl_xor(ss, 2);
        ss += __shfl_xor(ss, 4); ss += __shfl_xor(ss, 8);
        float nr = fmaxf(sqrtf(ss), 5e-5f);
        float inv = 1.0f / nr;
        ushort4 b = {f2bf(v.x * inv), f2bf(v.y * inv), f2bf(v.z * inv), f2bf(v.w * inv)};
        *(ushort4*)&kb[row * 72 + q4 * 4] = b;
        if (q4 == 0 && row < 144) snorm[row] = nr;
    }
    __syncthreads();
    const int arow = lane & 15, aks = (lane >> 4) * 8;
    bf16x8 af[9][2];
#pragma unroll
    for (int mt = 0; mt < 9; ++mt) {
        af[mt][0] = *(const bf16x8*)&kb[(mt * 16 + arow) * 72 + aks];
        af[mt][1] = *(const bf16x8*)&kb[(mt * 16 + arow) * 72 + 32 + aks];
    }
    float sc[9][4];
#pragma unroll
    for (int mt = 0; mt < 9; ++mt)
#pragma unroll
        for (int r = 0; r < 4; ++r)
            sc[mt][r] = snorm[mt * 16 + (lane >> 4) * 4 + r];
    float* rbase = raw + (size_t)(n * NWIN + k) * WIN * KJ;
    for (int nt = nq; nt < 27; nt += 4) {
        const int col = nt * 16 + (lane & 15);
        bf16x8 b0 = *(const bf16x8*)&kb[col * 72 + aks];
        bf16x8 b1 = *(const bf16x8*)&kb[col * 72 + 32 + aks];
#pragma unroll
        for (int mt = 0; mt < 9; ++mt) {
            f32x4 acc = {0.f, 0.f, 0.f, 0.f};
            acc = __builtin_amdgcn_mfma_f32_16x16x32_bf16(af[mt][0], b0, acc, 0, 0, 0);
            acc = __builtin_amdgcn_mfma_f32_16x16x32_bf16(af[mt][1], b1, acc, 0, 0, 0);
#pragma unroll
            for (int r = 0; r < 4; ++r)
                rbase[(size_t)(mt * 16 + (lane >> 4) * 4 + r) * KJ + nt * 16 + (lane & 15)] =
                    acc[r] * sc[mt][r];
        }
    }
}

// ---------------- PV + fused softmax: probs->score, bs, ret = P @ Y3 ----------------
__global__ __launch_bounds__(256) void k_pv_sm(const float* __restrict__ ye,
                                               const int* __restrict__ idxb,
                                               float* __restrict__ score,
                                               float* __restrict__ bs,
                                               float* __restrict__ ret) {
    __shared__ __align__(16) unsigned short pA[144 * 72];   // P[i][kk], stride 72
    __shared__ __align__(16) unsigned short pB[64 * 258];   // Y[kk][co], stride 258
    __shared__ int sidx[432];
    __shared__ float smax[144], sinv[144];
    const int bid = blockIdx.x;
    const int n = bid >> 6, k = bid & 63;
    const int t = threadIdx.x, lane = t & 63, nq = t >> 6;

    for (int s = t; s < 432; s += 256) {
        int wb = s / 144, jj = s % 144;
        int wk = (wb == 0) ? k : (wb == 1) ? ((k + 63) & 63) : ((k + 1) & 63);
        sidx[s] = idxb[n * L_ + wk * WIN + jj];
    }

    float* srow = score + (size_t)(n * NWIN + k) * WIN * KJ;
    for (int rr = 0; rr < 36; ++rr) {
        const int row = nq * 36 + rr;
        float v[7];
        float m = -1e30f;
#pragma unroll
        for (int it = 0; it < 7; ++it) {
            int j = lane + it * 64;
            v[it] = (j < KJ) ? srow[(size_t)row * KJ + j] : -1e30f;
            m = fmaxf(m, v[it]);
        }
#pragma unroll
        for (int o = 32; o >= 1; o >>= 1) m = fmaxf(m, __shfl_xor(m, o));
        float s = 0.f;
#pragma unroll
        for (int it = 0; it < 7; ++it)
            s += (lane + it * 64 < KJ) ? __expf(v[it] - m) : 0.f;
#pragma unroll
        for (int o = 32; o >= 1; o >>= 1) s += __shfl_xor(s, o);
        if (lane == 0) {
            smax[row] = m;
            sinv[row] = 1.f / s;
            bs[(size_t)(n * NWIN + k) * WIN + row] = m + logf(s);
        }
    }

    f32x4 acc[9][4];
#pragma unroll
    for (int mt = 0; mt < 9; ++mt)
#pragma unroll
        for (int nt = 0; nt < 4; ++nt) {
            f32x4 z = {0.f, 0.f, 0.f, 0.f};
            acc[mt][nt] = z;
        }

    const float* yb = ye + (size_t)n * L_ * 256;
    const int aBase = (lane & 15) * 72 + (lane >> 4) * 8;
    const int bBase = (lane >> 4) * 8 * 258 + nq * 64 + (lane & 15);

    for (int kc = 0; kc < 7; ++kc) {
        __syncthreads();
        for (int s = t; s < 2304; s += 256) {
            int i = s >> 4, c4 = s & 15;
            int kcol = kc * 64 + c4 * 4;
            ushort4 b = {0, 0, 0, 0};
            if (kcol < KJ) {
                float4 v = *(const float4*)(srow + (size_t)i * KJ + kcol);
                float m = smax[i], iv = sinv[i];
                float4 p = {__expf(v.x - m) * iv, __expf(v.y - m) * iv,
                            __expf(v.z - m) * iv, __expf(v.w - m) * iv};
                *(float4*)(srow + (size_t)i * KJ + kcol) = p;
                b.x = f2bf(p.x); b.y = f2bf(p.y); b.z = f2bf(p.z); b.w = f2bf(p.w);
            }
            *(ushort4*)&pA[i * 72 + c4 * 4] = b;
        }
        for (int s = t; s < 4096; s += 256) {
            int j = s >> 6, c4g = s & 63;
            int kk = kc * 64 + j;
            float4 v = {0.f, 0.f, 0.f, 0.f};
            if (kk < KJ) v = *(const float4*)(yb + (size_t)sidx[kk] * 256 + c4g * 4);
            ushort2 b0 = {f2bf(v.x), f2bf(v.y)};
            ushort2 b1 = {f2bf(v.z), f2bf(v.w)};
            *(ushort2*)&pB[j * 258 + c4g * 4] = b0;
            *(ushort2*)&pB[j * 258 + c4g * 4 + 2] = b1;
        }
        __syncthreads();
#pragma unroll
        for (int ks = 0; ks < 2; ++ks) {
            bf16x8 af[9];
#pragma unroll
            for (int mt = 0; mt < 9; ++mt)
                af[mt] = *(const bf16x8*)&pA[aBase + mt * 1152 + ks * 32];
#pragma unroll
            for (int nt = 0; nt < 4; ++nt) {
                const int e = bBase + ks * 32 * 258 + nt * 16;
                u16x8 bu;
#pragma unroll
                for (int j = 0; j < 8; ++j) bu[j] = pB[e + j * 258];
                bf16x8 bf = __builtin_bit_cast(bf16x8, bu);
#pragma unroll
                for (int mt = 0; mt < 9; ++mt)
                    acc[mt][nt] = __builtin_amdgcn_mfma_f32_16x16x32_bf16(af[mt], bf, acc[mt][nt], 0, 0, 0);
            }
        }
    }
    float* rbase = ret + ((size_t)n * L_ + (size_t)k * WIN) * 256;
    const int rowb = (lane >> 4) * 4;
    const int colb = nq * 64 + (lane & 15);
#pragma unroll
    for (int mt = 0; mt < 9; ++mt)
#pragma unroll
        for (int nt = 0; nt < 4; ++nt)
#pragma unroll
            for (int r = 0; r < 4; ++r)
                rbase[(size_t)(mt * 16 + rowb + r) * 256 + colb + nt * 16] = acc[mt][nt][r];
}

// ---------------- final scatter: out = x + 0.1 * ret[undo] ----------------
__global__ __launch_bounds__(256) void k_out(const float* __restrict__ x,
                                             const float* __restrict__ ret,
                                             const int* __restrict__ undo,
                                             float* __restrict__ out) {
    __shared__ float sr[32 * 257];
    const int n = blockIdx.x / 288, lt = blockIdx.x % 288;
    const int lbase = lt * 32;
    const int t = threadIdx.x;
    for (int s = t; s < 32 * 64; s += 256) {
        int lr = s >> 6, q = s & 63;
        int p = undo[n * L_ + lbase + lr];
        *(float4*)(sr + lr * 257 + q * 4) = *(const float4*)(ret + ((size_t)n * L_ + p) * 256 + q * 4);
    }
    __syncthreads();
    const int lr = t & 31, cog = t >> 5;
    for (int cc = 0; cc < 32; cc++) {
        int co = cog * 32 + cc;
        size_t gi = ((size_t)(n * 256 + co)) * L_ + lbase + lr;
        out[gi] = x[gi] + 0.1f * sr[lr * 257 + co];
    }
}

extern "C" void kernel_launch(void* const* d_in, const int* in_sizes, int n_in,
                              void* d_out, int out_size, void* d_ws, size_t ws_size,
                              hipStream_t stream) {
    (void)in_sizes; (void)n_in; (void)out_size; (void)ws_size;
    const float* x     = (const float*)d_in[0];
    const float* means = (const float*)d_in[1];
    const float* wm    = (const float*)d_in[2];
    const float* bm    = (const float*)d_in[3];
    const float* wa    = (const float*)d_in[4];
    const float* ba    = (const float*)d_in[5];

    float* out   = (float*)d_out;
    float* score = out + (size_t)8 * 256 * L_;
    float* bs    = score + (size_t)8 * NWIN * WIN * KJ;
    float* codesf = bs + (size_t)8 * L_;

    float* xe  = (float*)d_ws;
    float* ye  = xe + (size_t)8 * L_ * 64;
    float* ret = ye + (size_t)8 * L_ * 256;
    float* wtr = ret + (size_t)8 * L_ * 256;
    int* codes_i = (int*)(wtr + 147456);
    int* idxb    = codes_i + 8 * L_;
    int* undo    = idxb + 8 * L_;
    int* hist    = undo + 8 * L_;
    int* basebuf = hist + 8 * 36 * 128;

    float* parts = ret;   // conv3x3 partials live in ret region until c3sum

    k_wprep  <<<576, 256, 0, stream>>>(wm, wtr);
    k_conv3x3<<<1536, 128, 0, stream>>>(x, wtr, parts);
    k_c3sum  <<<4608, 256, 0, stream>>>(parts, bm, xe);
    k_conv1x1<<<4608, 256, 0, stream>>>(x, wa, ba, ye);
    k_assign <<<288, 256, 0, stream>>>(xe, means, codes_i, codesf);
    k_hist   <<<288, 256, 0, stream>>>(codes_i, hist);
    k_scan   <<<8, 128, 0, stream>>>(hist, basebuf);
    k_rank   <<<288, 256, 0, stream>>>(codes_i, basebuf, idxb, undo);
    k_qk_mfma<<<512, 256, 0, stream>>>(xe, idxb, score);
    k_pv_sm  <<<512, 256, 0, stream>>>(ye, idxb, score, bs, ret);
    k_out    <<<2304, 256, 0, stream>>>(x, ret, undo, out);
}

// Round 10
// 884.363 us; speedup vs baseline: 4.6807x; 1.0221x over previous
//
#include <hip/hip_runtime.h>
#include <math.h>

#define L_    9216
#define WIN   144
#define NWIN  64
#define KJ    432

typedef __bf16 bf16x8 __attribute__((ext_vector_type(8)));
typedef unsigned short u16x8 __attribute__((ext_vector_type(8)));
typedef float f32x4 __attribute__((ext_vector_type(4)));

__device__ __forceinline__ unsigned short f2bf(float f) {
    unsigned int u = __builtin_bit_cast(unsigned int, f);
    u = (u + 0x7FFFu + ((u >> 16) & 1u)) >> 16;
    return (unsigned short)u;
}

// ---------------- weight pre-transpose for conv3x3 ----------------
__global__ void k_wprep(const float* __restrict__ wm, float* __restrict__ wtr) {
    int s = blockIdx.x * 256 + threadIdx.x;       // 147456 total
    if (s < 147456) {
        int cq = s & 63, r = s >> 6;              // r = c*9+kk
        wtr[s] = wm[(size_t)cq * 2304 + r];
    }
}

// ---------------- conv3x3 v8: split-K x2, 2 h-rows/block, issue-early staging ----
// grid 768 ((n*48+hp)*2+half), block 256 (4 waves; hsel = t>>7, 16cg x 8wg per half).
// Thread tile 12w x 4cq x 1h. 4 ch/iter, 32 iters. Weights + 2/3 of x rows shared
// between the two h rows. Register-staged: ISSUE before compute, COMMIT after.
__global__ __launch_bounds__(256) void k_conv3x3(const float* __restrict__ x,
                                                 const float* __restrict__ wtr,
                                                 float* __restrict__ parts) {
    __shared__ __align__(16) float sx[2][4][4][104];  // [buf][ch][r][idx], col=idx-1
    __shared__ __align__(16) float sw[2][4][9][64];   // [buf][ch][tap][cq]
    const int bid = blockIdx.x;
    const int half = bid & 1;
    const int hp = (bid >> 1) % 48, n = bid / 96;
    const int chb = half * 128;
    const int t = threadIdx.x;
    const int hsel = t >> 7;
    const int t128 = t & 127;
    const int cg = t128 & 15, wg = t128 >> 4;
    const int w0 = wg * 12, cq0 = cg * 4;
    const int h = hp * 2 + hsel;
    const float* xb = x + (size_t)n * 256 * 9216;
    const float4 fz = {0.f, 0.f, 0.f, 0.f};

    // x slots: 384 f4 = 4ch x 4r x 24q; slot A = t, slot B = t+256 (t<128)
    const int xchA = t / 96, xrA = (t % 96) / 24, xqA = t % 24;
    const int rowA = hp * 2 - 1 + xrA;
    const bool xvA = (rowA >= 0) && (rowA < 96);
    const int xoffA = xchA * 9216 + (xvA ? rowA : 0) * 96 + xqA * 4;
    const int sB = t + 256;
    const bool hasB = sB < 384;
    const int xchB = hasB ? sB / 96 : 0, xrB = (sB % 96) / 24, xqB = sB % 24;
    const int rowB = hp * 2 - 1 + xrB;
    const bool xvB = hasB && (rowB >= 0) && (rowB < 96);
    const int xoffB = xchB * 9216 + (xvB ? rowB : 0) * 96 + xqB * 4;
    // w slots: 576 f4 = 4ch x 9kk x 16q; slots t, t+256, t+512 (t<64)
    const int wchA = t / 144,         wkkA = (t % 144) / 16,         wqA = t % 16;
    const int wchB = (t + 256) / 144, wkkB = ((t + 256) % 144) / 16, wqB = (t + 256) % 16;
    const bool whasC = t < 64;
    const int wchC = (t + 512) / 144, wkkC = ((t + 512) % 144) / 16, wqC = (t + 512) % 16;

    float acc[12][4];
#pragma unroll
    for (int j = 0; j < 12; ++j)
#pragma unroll
        for (int q = 0; q < 4; ++q) acc[j][q] = 0.f;

    float4 xgA, xgB, wgA, wgB, wgC;
#define C3_ISSUE(cb)                                                              \
    do {                                                                          \
        const float* xc = xb + (size_t)(cb) * 9216;                               \
        xgA = xvA ? *(const float4*)(xc + xoffA) : fz;                            \
        xgB = xvB ? *(const float4*)(xc + xoffB) : fz;                            \
        const float* wc = wtr + (size_t)(cb) * 576;                               \
        wgA = *(const float4*)(wc + (wchA * 9 + wkkA) * 64 + wqA * 4);            \
        wgB = *(const float4*)(wc + (wchB * 9 + wkkB) * 64 + wqB * 4);            \
        wgC = whasC ? *(const float4*)(wc + (wchC * 9 + wkkC) * 64 + wqC * 4) : fz; \
    } while (0)
#define C3_COMMIT(buf)                                                            \
    do {                                                                          \
        float* dA = &sx[buf][xchA][xrA][xqA * 4 + 1];                             \
        dA[0] = xgA.x; dA[1] = xgA.y; dA[2] = xgA.z; dA[3] = xgA.w;               \
        if (hasB) {                                                               \
            float* dB = &sx[buf][xchB][xrB][xqB * 4 + 1];                         \
            dB[0] = xgB.x; dB[1] = xgB.y; dB[2] = xgB.z; dB[3] = xgB.w;           \
        }                                                                         \
        *(float4*)&sw[buf][wchA][wkkA][wqA * 4] = wgA;                            \
        *(float4*)&sw[buf][wchB][wkkB][wqB * 4] = wgB;                            \
        if (whasC) *(float4*)&sw[buf][wchC][wkkC][wqC * 4] = wgC;                 \
    } while (0)

    // zero edge cols (idx 0, 97..103): 2buf x 4ch x 4r x 8idx = 256 slots, 1/thread
    {
        int buf = t >> 7, rem = t & 127;
        int ch = rem >> 5, rr = (rem >> 3) & 3, e = rem & 7;
        int idx = (e == 0) ? 0 : 96 + e;
        sx[buf][ch][rr][idx] = 0.f;
    }
    C3_ISSUE(chb);
    C3_COMMIT(0);
    __syncthreads();

    for (int it = 0; it < 32; ++it) {
        const int cur = it & 1;
        if (it < 31) C3_ISSUE(chb + (it + 1) * 4);
#pragma unroll
        for (int ch = 0; ch < 4; ++ch) {
#pragma unroll
            for (int dh = 0; dh < 3; ++dh) {
                float4 wv0 = *(const float4*)&sw[cur][ch][dh * 3 + 0][cq0];
                float4 wv1 = *(const float4*)&sw[cur][ch][dh * 3 + 1][cq0];
                float4 wv2 = *(const float4*)&sw[cur][ch][dh * 3 + 2][cq0];
                float xr[16];
#pragma unroll
                for (int q = 0; q < 4; ++q) {
                    float4 v = *(const float4*)&sx[cur][ch][hsel + dh][w0 + q * 4];
                    xr[q * 4 + 0] = v.x; xr[q * 4 + 1] = v.y;
                    xr[q * 4 + 2] = v.z; xr[q * 4 + 3] = v.w;
                }
#pragma unroll
                for (int j = 0; j < 12; ++j) {
                    acc[j][0] += xr[j + 0] * wv0.x;
                    acc[j][1] += xr[j + 0] * wv0.y;
                    acc[j][2] += xr[j + 0] * wv0.z;
                    acc[j][3] += xr[j + 0] * wv0.w;
                }
#pragma unroll
                for (int j = 0; j < 12; ++j) {
                    acc[j][0] += xr[j + 1] * wv1.x;
                    acc[j][1] += xr[j + 1] * wv1.y;
                    acc[j][2] += xr[j + 1] * wv1.z;
                    acc[j][3] += xr[j + 1] * wv1.w;
                }
#pragma unroll
                for (int j = 0; j < 12; ++j) {
                    acc[j][0] += xr[j + 2] * wv2.x;
                    acc[j][1] += xr[j + 2] * wv2.y;
                    acc[j][2] += xr[j + 2] * wv2.z;
                    acc[j][3] += xr[j + 2] * wv2.w;
                }
            }
        }
        if (it < 31) C3_COMMIT(cur ^ 1);
        __syncthreads();
    }
#undef C3_ISSUE
#undef C3_COMMIT

    float* pb = parts + (size_t)half * 4718592;
#pragma unroll
    for (int j = 0; j < 12; ++j) {
        float4 o = {acc[j][0], acc[j][1], acc[j][2], acc[j][3]};
        *(float4*)&pb[((size_t)n * L_ + (size_t)h * 96 + w0 + j) * 64 + cq0] = o;
    }
}

// ---------------- combine split-K partials + bias -> xe ----------------
__global__ __launch_bounds__(256) void k_c3sum(const float* __restrict__ parts,
                                               const float* __restrict__ bm,
                                               float* __restrict__ xe) {
    size_t i = (size_t)blockIdx.x * 256 + threadIdx.x;   // f4 index; grid 4608
    float4 a = ((const float4*)parts)[i];
    float4 b = ((const float4*)parts)[i + 1179648];
    float4 bi = ((const float4*)bm)[i & 15];
    float4 o = {a.x + b.x + bi.x, a.y + b.y + bi.y, a.z + b.z + bi.z, a.w + b.w + bi.w};
    ((float4*)xe)[i] = o;
}

// ---------------- conv1x1 via bf16 MFMA: ye[8,9216,256] fp32 ----------------
__global__ __launch_bounds__(256) void k_conv1x1(const float* __restrict__ x,
                                                 const float* __restrict__ wa,
                                                 const float* __restrict__ ba,
                                                 float* __restrict__ ye) {
    __shared__ __align__(16) unsigned short pA[64 * 40];  // [co][k], pad 40
    __shared__ __align__(16) unsigned short pB[32 * 68];  // [k][l],  pad 68
    __shared__ __align__(16) float det[64 * 67];          // [co][l], pad 67
    const int bid = blockIdx.x;
    const int n = bid / 576, rem = bid % 576;
    const int l0 = (rem >> 2) * 64, co0 = (rem & 3) * 64;
    const int t = threadIdx.x, lane = t & 63, nq = t >> 6;

    f32x4 acc[4];
#pragma unroll
    for (int nt = 0; nt < 4; ++nt) { f32x4 z = {0.f, 0.f, 0.f, 0.f}; acc[nt] = z; }

    const int aOff = (nq * 16 + (lane & 15)) * 40 + (lane >> 4) * 8;
    const int bK = (lane >> 4) * 8, bL = lane & 15;

    for (int kc = 0; kc < 8; ++kc) {
        const int c0 = kc * 32;
        __syncthreads();
        for (int s = t; s < 512; s += 256) {
            int co = s >> 3, q = s & 7;
            float4 v = *(const float4*)&wa[(size_t)(co0 + co) * 256 + c0 + q * 4];
            ushort4 b = {f2bf(v.x), f2bf(v.y), f2bf(v.z), f2bf(v.w)};
            *(ushort4*)&pA[co * 40 + q * 4] = b;
        }
        for (int s = t; s < 512; s += 256) {
            int c = s >> 4, l4 = s & 15;
            float4 v = *(const float4*)&x[((size_t)n * 256 + c0 + c) * L_ + l0 + l4 * 4];
            ushort4 b = {f2bf(v.x), f2bf(v.y), f2bf(v.z), f2bf(v.w)};
            *(ushort4*)&pB[c * 68 + l4 * 4] = b;
        }
        __syncthreads();
        u16x8 au = *(const u16x8*)&pA[aOff];
        bf16x8 af = __builtin_bit_cast(bf16x8, au);
#pragma unroll
        for (int nt = 0; nt < 4; ++nt) {
            u16x8 bu;
#pragma unroll
            for (int j = 0; j < 8; ++j) bu[j] = pB[(bK + j) * 68 + nt * 16 + bL];
            bf16x8 bf = __builtin_bit_cast(bf16x8, bu);
            acc[nt] = __builtin_amdgcn_mfma_f32_16x16x32_bf16(af, bf, acc[nt], 0, 0, 0);
        }
    }
    __syncthreads();
#pragma unroll
    for (int nt = 0; nt < 4; ++nt)
#pragma unroll
        for (int r = 0; r < 4; ++r)
            det[(nq * 16 + (lane >> 4) * 4 + r) * 67 + nt * 16 + (lane & 15)] = acc[nt][r];
    __syncthreads();
    for (int s = t; s < 1024; s += 256) {
        int l = s >> 4, c4 = s & 15;
        float4 bi = *(const float4*)&ba[co0 + c4 * 4];
        float4 o = {det[(c4 * 4 + 0) * 67 + l] + bi.x,
                    det[(c4 * 4 + 1) * 67 + l] + bi.y,
                    det[(c4 * 4 + 2) * 67 + l] + bi.z,
                    det[(c4 * 4 + 3) * 67 + l] + bi.w};
        *(float4*)&ye[((size_t)n * L_ + l0 + l) * 256 + co0 + c4 * 4] = o;
    }
}

// ---------------- kmeans assign (fp64 dot; norm is argmax-invariant) ----------------
__global__ __launch_bounds__(256) void k_assign(const float* __restrict__ xe,
                                                const float* __restrict__ means,
                                                int* __restrict__ codes_i,
                                                float* __restrict__ codes_f) {
    __shared__ float sm[128 * 64];
    for (int s = threadIdx.x; s < 8192; s += 256) sm[s] = means[s];
    __syncthreads();
    const int g = blockIdx.x * 256 + threadIdx.x;
    const float* row = xe + (size_t)g * 64;
    float v[64];
#pragma unroll
    for (int c4 = 0; c4 < 16; c4++) {
        float4 t4 = *(const float4*)(row + c4 * 4);
        v[c4 * 4 + 0] = t4.x; v[c4 * 4 + 1] = t4.y; v[c4 * 4 + 2] = t4.z; v[c4 * 4 + 3] = t4.w;
    }
    int best = 0;
    double bd = -1e300;
    for (int cl = 0; cl < 128; cl++) {
        double d = 0.0;
#pragma unroll
        for (int c4 = 0; c4 < 16; c4++) {
            float4 m4 = *(const float4*)(sm + cl * 64 + c4 * 4);
            d += (double)v[c4 * 4 + 0] * (double)m4.x + (double)v[c4 * 4 + 1] * (double)m4.y +
                 (double)v[c4 * 4 + 2] * (double)m4.z + (double)v[c4 * 4 + 3] * (double)m4.w;
        }
        if (d > bd) { bd = d; best = cl; }
    }
    codes_i[g] = best;
    codes_f[g] = (float)best;
}

// ---------------- stable counting sort ----------------
__global__ void k_hist(const int* __restrict__ codes_i, int* __restrict__ hist) {
    __shared__ int h[128];
    if (threadIdx.x < 128) h[threadIdx.x] = 0;
    __syncthreads();
    int n = blockIdx.x / 36, ch = blockIdx.x % 36;
    int c = codes_i[n * L_ + ch * 256 + threadIdx.x];
    atomicAdd(&h[c], 1);
    __syncthreads();
    if (threadIdx.x < 128) hist[(n * 36 + ch) * 128 + threadIdx.x] = h[threadIdx.x];
}

__global__ void k_scan(const int* __restrict__ hist, int* __restrict__ basebuf) {
    __shared__ int tot[128];
    __shared__ int binstart[128];
    int n = blockIdx.x, c = threadIdx.x;
    int run = 0;
    int local[36];
    for (int ch = 0; ch < 36; ch++) { local[ch] = run; run += hist[(n * 36 + ch) * 128 + c]; }
    tot[c] = run;
    __syncthreads();
    if (c == 0) {
        int s = 0;
        for (int b = 0; b < 128; b++) { binstart[b] = s; s += tot[b]; }
    }
    __syncthreads();
    int bs0 = binstart[c];
    for (int ch = 0; ch < 36; ch++) basebuf[(n * 36 + ch) * 128 + c] = bs0 + local[ch];
}

__global__ void k_rank(const int* __restrict__ codes_i, const int* __restrict__ basebuf,
                       int* __restrict__ idxb, int* __restrict__ undo) {
    __shared__ int sc[256];
    __shared__ int sb[128];
    int n = blockIdx.x / 36, ch = blockIdx.x % 36;
    int i = threadIdx.x;
    int l = ch * 256 + i;
    int c = codes_i[n * L_ + l];
    sc[i] = c;
    if (i < 128) sb[i] = basebuf[(n * 36 + ch) * 128 + i];
    __syncthreads();
    int r = 0;
    for (int j = 0; j < i; j++) r += (sc[j] == c);
    int pos = sb[c] + r;
    idxb[n * L_ + pos] = l;
    undo[n * L_ + l] = pos;
}

// ---------------- QK via bf16 MFMA: raw[i,j] = (xn_i . xn_j) * s_i ----------------
__global__ __launch_bounds__(256) void k_qk_mfma(const float* __restrict__ xe,
                                                 const int* __restrict__ idxb,
                                                 float* __restrict__ raw) {
    __shared__ __align__(16) unsigned short kb[432 * 72];
    __shared__ float snorm[144];
    __shared__ int sidx[432];
    const int bid = blockIdx.x;
    const int n = bid >> 6, k = bid & 63;
    const int t = threadIdx.x, lane = t & 63, nq = t >> 6;

    for (int s = t; s < 432; s += 256) {
        int wb = s / 144, jj = s % 144;
        int wk = (wb == 0) ? k : (wb == 1) ? ((k + 63) & 63) : ((k + 1) & 63);
        sidx[s] = idxb[n * L_ + wk * WIN + jj];
    }
    __syncthreads();
    for (int s = t; s < 6912; s += 256) {
        int row = s >> 4, q4 = s & 15;
        float4 v = *(const float4*)(xe + ((size_t)n * L_ + sidx[row]) * 64 + q4 * 4);
        float ss = v.x * v.x + v.y * v.y + v.z * v.z + v.w * v.w;
        ss += __shfl_xor(ss, 1); ss += __shfl_xor(ss, 2);
        ss += __shfl_xor(ss, 4); ss += __shfl_xor(ss, 8);
        float nr = fmaxf(sqrtf(ss), 5e-5f);
        float inv = 1.0f / nr;
        ushort4 b = {f2bf(v.x * inv), f2bf(v.y * inv), f2bf(v.z * inv), f2bf(v.w * inv)};
        *(ushort4*)&kb[row * 72 + q4 * 4] = b;
        if (q4 == 0 && row < 144) snorm[row] = nr;
    }
    __syncthreads();
    const int arow = lane & 15, aks = (lane >> 4) * 8;
    bf16x8 af[9][2];
#pragma unroll
    for (int mt = 0; mt < 9; ++mt) {
        af[mt][0] = *(const bf16x8*)&kb[(mt * 16 + arow) * 72 + aks];
        af[mt][1] = *(const bf16x8*)&kb[(mt * 16 + arow) * 72 + 32 + aks];
    }
    float sc[9][4];
#pragma unroll
    for (int mt = 0; mt < 9; ++mt)
#pragma unroll
        for (int r = 0; r < 4; ++r)
            sc[mt][r] = snorm[mt * 16 + (lane >> 4) * 4 + r];
    float* rbase = raw + (size_t)(n * NWIN + k) * WIN * KJ;
    for (int nt = nq; nt < 27; nt += 4) {
        const int col = nt * 16 + (lane & 15);
        bf16x8 b0 = *(const bf16x8*)&kb[col * 72 + aks];
        bf16x8 b1 = *(const bf16x8*)&kb[col * 72 + 32 + aks];
#pragma unroll
        for (int mt = 0; mt < 9; ++mt) {
            f32x4 acc = {0.f, 0.f, 0.f, 0.f};
            acc = __builtin_amdgcn_mfma_f32_16x16x32_bf16(af[mt][0], b0, acc, 0, 0, 0);
            acc = __builtin_amdgcn_mfma_f32_16x16x32_bf16(af[mt][1], b1, acc, 0, 0, 0);
#pragma unroll
            for (int r = 0; r < 4; ++r)
                rbase[(size_t)(mt * 16 + (lane >> 4) * 4 + r) * KJ + nt * 16 + (lane & 15)] =
                    acc[r] * sc[mt][r];
        }
    }
}

// ---------------- PV + fused softmax: probs->score, bs, ret = P @ Y3 ----------------
__global__ __launch_bounds__(256) void k_pv_sm(const float* __restrict__ ye,
                                               const int* __restrict__ idxb,
                                               float* __restrict__ score,
                                               float* __restrict__ bs,
                                               float* __restrict__ ret) {
    __shared__ __align__(16) unsigned short pA[144 * 72];   // P[i][kk], stride 72
    __shared__ __align__(16) unsigned short pB[64 * 258];   // Y[kk][co], stride 258
    __shared__ int sidx[432];
    __shared__ float smax[144], sinv[144];
    const int bid = blockIdx.x;
    const int n = bid >> 6, k = bid & 63;
    const int t = threadIdx.x, lane = t & 63, nq = t >> 6;

    for (int s = t; s < 432; s += 256) {
        int wb = s / 144, jj = s % 144;
        int wk = (wb == 0) ? k : (wb == 1) ? ((k + 63) & 63) : ((k + 1) & 63);
        sidx[s] = idxb[n * L_ + wk * WIN + jj];
    }

    float* srow = score + (size_t)(n * NWIN + k) * WIN * KJ;
    for (int rr = 0; rr < 36; ++rr) {
        const int row = nq * 36 + rr;
        float v[7];
        float m = -1e30f;
#pragma unroll
        for (int it = 0; it < 7; ++it) {
            int j = lane + it * 64;
            v[it] = (j < KJ) ? srow[(size_t)row * KJ + j] : -1e30f;
            m = fmaxf(m, v[it]);
        }
#pragma unroll
        for (int o = 32; o >= 1; o >>= 1) m = fmaxf(m, __shfl_xor(m, o));
        float s = 0.f;
#pragma unroll
        for (int it = 0; it < 7; ++it)
            s += (lane + it * 64 < KJ) ? __expf(v[it] - m) : 0.f;
#pragma unroll
        for (int o = 32; o >= 1; o >>= 1) s += __shfl_xor(s, o);
        if (lane == 0) {
            smax[row] = m;
            sinv[row] = 1.f / s;
            bs[(size_t)(n * NWIN + k) * WIN + row] = m + logf(s);
        }
    }

    f32x4 acc[9][4];
#pragma unroll
    for (int mt = 0; mt < 9; ++mt)
#pragma unroll
        for (int nt = 0; nt < 4; ++nt) {
            f32x4 z = {0.f, 0.f, 0.f, 0.f};
            acc[mt][nt] = z;
        }

    const float* yb = ye + (size_t)n * L_ * 256;
    const int aBase = (lane & 15) * 72 + (lane >> 4) * 8;
    const int bBase = (lane >> 4) * 8 * 258 + nq * 64 + (lane & 15);

    for (int kc = 0; kc < 7; ++kc) {
        __syncthreads();
        for (int s = t; s < 2304; s += 256) {
            int i = s >> 4, c4 = s & 15;
            int kcol = kc * 64 + c4 * 4;
            ushort4 b = {0, 0, 0, 0};
            if (kcol < KJ) {
                float4 v = *(const float4*)(srow + (size_t)i * KJ + kcol);
                float m = smax[i], iv = sinv[i];
                float4 p = {__expf(v.x - m) * iv, __expf(v.y - m) * iv,
                            __expf(v.z - m) * iv, __expf(v.w - m) * iv};
                *(float4*)(srow + (size_t)i * KJ + kcol) = p;
                b.x = f2bf(p.x); b.y = f2bf(p.y); b.z = f2bf(p.z); b.w = f2bf(p.w);
            }
            *(ushort4*)&pA[i * 72 + c4 * 4] = b;
        }
        for (int s = t; s < 4096; s += 256) {
            int j = s >> 6, c4g = s & 63;
            int kk = kc * 64 + j;
            float4 v = {0.f, 0.f, 0.f, 0.f};
            if (kk < KJ) v = *(const float4*)(yb + (size_t)sidx[kk] * 256 + c4g * 4);
            ushort2 b0 = {f2bf(v.x), f2bf(v.y)};
            ushort2 b1 = {f2bf(v.z), f2bf(v.w)};
            *(ushort2*)&pB[j * 258 + c4g * 4] = b0;
            *(ushort2*)&pB[j * 258 + c4g * 4 + 2] = b1;
        }
        __syncthreads();
#pragma unroll
        for (int ks = 0; ks < 2; ++ks) {
            bf16x8 af[9];
#pragma unroll
            for (int mt = 0; mt < 9; ++mt)
                af[mt] = *(const bf16x8*)&pA[aBase + mt * 1152 + ks * 32];
#pragma unroll
            for (int nt = 0; nt < 4; ++nt) {
                const int e = bBase + ks * 32 * 258 + nt * 16;
                u16x8 bu;
#pragma unroll
                for (int j = 0; j < 8; ++j) bu[j] = pB[e + j * 258];
                bf16x8 bf = __builtin_bit_cast(bf16x8, bu);
#pragma unroll
                for (int mt = 0; mt < 9; ++mt)
                    acc[mt][nt] = __builtin_amdgcn_mfma_f32_16x16x32_bf16(af[mt], bf, acc[mt][nt], 0, 0, 0);
            }
        }
    }
    float* rbase = ret + ((size_t)n * L_ + (size_t)k * WIN) * 256;
    const int rowb = (lane >> 4) * 4;
    const int colb = nq * 64 + (lane & 15);
#pragma unroll
    for (int mt = 0; mt < 9; ++mt)
#pragma unroll
        for (int nt = 0; nt < 4; ++nt)
#pragma unroll
            for (int r = 0; r < 4; ++r)
                rbase[(size_t)(mt * 16 + rowb + r) * 256 + colb + nt * 16] = acc[mt][nt][r];
}

// ---------------- final scatter: out = x + 0.1 * ret[undo] ----------------
__global__ __launch_bounds__(256) void k_out(const float* __restrict__ x,
                                             const float* __restrict__ ret,
                                             const int* __restrict__ undo,
                                             float* __restrict__ out) {
    __shared__ float sr[32 * 257];
    const int n = blockIdx.x / 288, lt = blockIdx.x % 288;
    const int lbase = lt * 32;
    const int t = threadIdx.x;
    for (int s = t; s < 32 * 64; s += 256) {
        int lr = s >> 6, q = s & 63;
        int p = undo[n * L_ + lbase + lr];
        *(float4*)(sr + lr * 257 + q * 4) = *(const float4*)(ret + ((size_t)n * L_ + p) * 256 + q * 4);
    }
    __syncthreads();
    const int lr = t & 31, cog = t >> 5;
    for (int cc = 0; cc < 32; cc++) {
        int co = cog * 32 + cc;
        size_t gi = ((size_t)(n * 256 + co)) * L_ + lbase + lr;
        out[gi] = x[gi] + 0.1f * sr[lr * 257 + co];
    }
}

extern "C" void kernel_launch(void* const* d_in, const int* in_sizes, int n_in,
                              void* d_out, int out_size, void* d_ws, size_t ws_size,
                              hipStream_t stream) {
    (void)in_sizes; (void)n_in; (void)out_size; (void)ws_size;
    const float* x     = (const float*)d_in[0];
    const float* means = (const float*)d_in[1];
    const float* wm    = (const float*)d_in[2];
    const float* bm    = (const float*)d_in[3];
    const float* wa    = (const float*)d_in[4];
    const float* ba    = (const float*)d_in[5];

    float* out   = (float*)d_out;
    float* score = out + (size_t)8 * 256 * L_;
    float* bs    = score + (size_t)8 * NWIN * WIN * KJ;
    float* codesf = bs + (size_t)8 * L_;

    float* xe  = (float*)d_ws;
    float* ye  = xe + (size_t)8 * L_ * 64;
    float* ret = ye + (size_t)8 * L_ * 256;
    float* wtr = ret + (size_t)8 * L_ * 256;
    int* codes_i = (int*)(wtr + 147456);
    int* idxb    = codes_i + 8 * L_;
    int* undo    = idxb + 8 * L_;
    int* hist    = undo + 8 * L_;
    int* basebuf = hist + 8 * 36 * 128;

    float* parts = ret;   // conv3x3 partials live in ret region until c3sum

    k_wprep  <<<576, 256, 0, stream>>>(wm, wtr);
    k_conv3x3<<<768, 256, 0, stream>>>(x, wtr, parts);
    k_c3sum  <<<4608, 256, 0, stream>>>(parts, bm, xe);
    k_conv1x1<<<4608, 256, 0, stream>>>(x, wa, ba, ye);
    k_assign <<<288, 256, 0, stream>>>(xe, means, codes_i, codesf);
    k_hist   <<<288, 256, 0, stream>>>(codes_i, hist);
    k_scan   <<<8, 128, 0, stream>>>(hist, basebuf);
    k_rank   <<<288, 256, 0, stream>>>(codes_i, basebuf, idxb, undo);
    k_qk_mfma<<<512, 256, 0, stream>>>(xe, idxb, score);
    k_pv_sm  <<<512, 256, 0, stream>>>(ye, idxb, score, bs, ret);
    k_out    <<<2304, 256, 0, stream>>>(x, ret, undo, out);
}

// Round 11
// 766.753 us; speedup vs baseline: 5.3987x; 1.1534x over previous
//
#include <hip/hip_runtime.h>
#include <math.h>

#define L_    9216
#define WIN   144
#define NWIN  64
#define KJ    432

typedef __bf16 bf16x8 __attribute__((ext_vector_type(8)));
typedef unsigned short u16x8 __attribute__((ext_vector_type(8)));
typedef float f32x4 __attribute__((ext_vector_type(4)));

__device__ __forceinline__ unsigned short f2bf(float f) {
    unsigned int u = __builtin_bit_cast(unsigned int, f);
    u = (u + 0x7FFFu + ((u >> 16) & 1u)) >> 16;
    return (unsigned short)u;
}
__device__ __forceinline__ float bf2f(unsigned short u) {
    return __builtin_bit_cast(float, (unsigned int)u << 16);
}
__device__ __forceinline__ void load_lds16(const float* g, float* l) {
    __builtin_amdgcn_global_load_lds(
        (const __attribute__((address_space(1))) void*)g,
        (__attribute__((address_space(3))) void*)l, 16, 0, 0);
}

// ---------------- weight pre-transpose for conv3x3 (+ zero region) ----------------
__global__ void k_wprep(const float* __restrict__ wm, float* __restrict__ wtr,
                        float* __restrict__ zeros) {
    int s = blockIdx.x * 256 + threadIdx.x;       // 147456 total
    if (s < 147456) {
        int cq = s & 63, r = s >> 6;              // r = c*9+kk
        wtr[s] = wm[(size_t)cq * 2304 + r];
    }
    if (blockIdx.x == 0 && threadIdx.x < 64) zeros[threadIdx.x] = 0.f;
}

// ---------------- conv3x3 v9: split-K x2, async global_load_lds staging ----------
// grid 1536 ((n*96+h)*2+half), block 128 (16cg x 8wg); tile 12w x 4cq; 32 iters.
// LDS linear: [x: 4ch x 3r x 96][w: 4ch x 9kk x 64] = 3456 f + 128 f pad slots.
// Edge columns handled in compute (clamped reads + select 0); OOB rows -> zeros.
__global__ __launch_bounds__(128) void k_conv3x3(const float* __restrict__ x,
                                                 const float* __restrict__ wtr,
                                                 const float* __restrict__ zeros,
                                                 float* __restrict__ parts) {
    __shared__ __align__(16) float stg[2][3584];   // 7 x 128 f4 slots per buffer
    const int bid = blockIdx.x;
    const int half = bid & 1;
    const int h = (bid >> 1) % 96, n = bid / 192;
    const int chb = half * 128;
    const int t = threadIdx.x;
    const int cg = t & 15, wg = t >> 4;
    const int w0 = wg * 12, cq0 = cg * 4;
    const float* xb = x + (size_t)n * 256 * 9216;

    // staging descriptors: slot s = c*128 + t; s<288 = x, 288..863 = w, >=864 pad->zeros
    int grel[7], gkind[7];                // kind: 0=x, 1=w, 2=zeros
#pragma unroll
    for (int c = 0; c < 7; ++c) {
        int s = c * 128 + t;
        if (s < 288) {
            int ch = s / 72, rr = (s / 24) % 3, q = s % 24;
            int hh = h + rr - 1;
            if (hh >= 0 && hh < 96) { gkind[c] = 0; grel[c] = ch * 9216 + hh * 96 + q * 4; }
            else                    { gkind[c] = 2; grel[c] = 0; }
        } else if (s < 864) {
            int u = s - 288;
            int ch = u / 144, kk = (u % 144) >> 4, q = u & 15;
            gkind[c] = 1; grel[c] = ch * 576 + kk * 64 + q * 4;
        } else {
            gkind[c] = 2; grel[c] = 0;
        }
    }
    const int wvbase = t & 64;            // wave slot base within the 128-thread block

#define C3_STAGE(buf, cb)                                                         \
    do {                                                                          \
        _Pragma("unroll")                                                         \
        for (int c = 0; c < 7; ++c) {                                             \
            const float* g = (gkind[c] == 0) ? (xb + (size_t)(cb) * 9216 + grel[c]) \
                           : (gkind[c] == 1) ? (wtr + (size_t)(cb) * 576 + grel[c]) \
                                             : zeros;                             \
            load_lds16(g, &stg[buf][(c * 128 + wvbase) * 4]);                     \
        }                                                                         \
    } while (0)

    float acc[12][4];
#pragma unroll
    for (int j = 0; j < 12; ++j)
#pragma unroll
        for (int q = 0; q < 4; ++q) acc[j][q] = 0.f;

    C3_STAGE(0, chb);
    __syncthreads();

    const int liIdx = (wg == 0) ? 0 : (w0 - 1);     // clamped in-bounds
    const int riIdx = (wg == 7) ? 95 : (w0 + 12);

    for (int it = 0; it < 32; ++it) {
        const int cur = it & 1;
        if (it < 31) C3_STAGE(cur ^ 1, chb + (it + 1) * 4);
        const float* xs = stg[cur];
        const float* ws = stg[cur] + 1152;
#pragma unroll
        for (int ch = 0; ch < 4; ++ch) {
#pragma unroll
            for (int dh = 0; dh < 3; ++dh) {
                const float* xrow = xs + ch * 288 + dh * 96;
                float4 wv0 = *(const float4*)(ws + ch * 576 + (dh * 3 + 0) * 64 + cq0);
                float4 wv1 = *(const float4*)(ws + ch * 576 + (dh * 3 + 1) * 64 + cq0);
                float4 wv2 = *(const float4*)(ws + ch * 576 + (dh * 3 + 2) * 64 + cq0);
                float xf[14];
                {
                    float lv = xrow[liIdx];
                    xf[0] = (wg == 0) ? 0.f : lv;
                    float4 a = *(const float4*)(xrow + w0);
                    float4 b = *(const float4*)(xrow + w0 + 4);
                    float4 c4v = *(const float4*)(xrow + w0 + 8);
                    xf[1] = a.x;  xf[2] = a.y;  xf[3] = a.z;  xf[4] = a.w;
                    xf[5] = b.x;  xf[6] = b.y;  xf[7] = b.z;  xf[8] = b.w;
                    xf[9] = c4v.x; xf[10] = c4v.y; xf[11] = c4v.z; xf[12] = c4v.w;
                    float rv = xrow[riIdx];
                    xf[13] = (wg == 7) ? 0.f : rv;
                }
#pragma unroll
                for (int j = 0; j < 12; ++j) {
                    acc[j][0] += xf[j] * wv0.x;
                    acc[j][1] += xf[j] * wv0.y;
                    acc[j][2] += xf[j] * wv0.z;
                    acc[j][3] += xf[j] * wv0.w;
                }
#pragma unroll
                for (int j = 0; j < 12; ++j) {
                    acc[j][0] += xf[j + 1] * wv1.x;
                    acc[j][1] += xf[j + 1] * wv1.y;
                    acc[j][2] += xf[j + 1] * wv1.z;
                    acc[j][3] += xf[j + 1] * wv1.w;
                }
#pragma unroll
                for (int j = 0; j < 12; ++j) {
                    acc[j][0] += xf[j + 2] * wv2.x;
                    acc[j][1] += xf[j + 2] * wv2.y;
                    acc[j][2] += xf[j + 2] * wv2.z;
                    acc[j][3] += xf[j + 2] * wv2.w;
                }
            }
        }
        __syncthreads();
    }
#undef C3_STAGE

    float* pb = parts + (size_t)half * 4718592;
#pragma unroll
    for (int j = 0; j < 12; ++j) {
        float4 o = {acc[j][0], acc[j][1], acc[j][2], acc[j][3]};
        *(float4*)&pb[((size_t)n * L_ + (size_t)h * 96 + w0 + j) * 64 + cq0] = o;
    }
}

// ---------------- combine split-K partials + bias -> xe ----------------
__global__ __launch_bounds__(256) void k_c3sum(const float* __restrict__ parts,
                                               const float* __restrict__ bm,
                                               float* __restrict__ xe) {
    size_t i = (size_t)blockIdx.x * 256 + threadIdx.x;   // f4 index; grid 4608
    float4 a = ((const float4*)parts)[i];
    float4 b = ((const float4*)parts)[i + 1179648];
    float4 bi = ((const float4*)bm)[i & 15];
    float4 o = {a.x + b.x + bi.x, a.y + b.y + bi.y, a.z + b.z + bi.z, a.w + b.w + bi.w};
    ((float4*)xe)[i] = o;
}

// ---------------- conv1x1 via bf16 MFMA -> yeb bf16 [8,9216,256] ----------------
__global__ __launch_bounds__(256) void k_conv1x1(const float* __restrict__ x,
                                                 const float* __restrict__ wa,
                                                 const float* __restrict__ ba,
                                                 unsigned short* __restrict__ yeb) {
    __shared__ __align__(16) unsigned short pA[64 * 40];  // [co][k], pad 40
    __shared__ __align__(16) unsigned short pB[32 * 68];  // [k][l],  pad 68
    __shared__ __align__(16) float det[64 * 67];          // [co][l], pad 67
    const int bid = blockIdx.x;
    const int n = bid / 576, rem = bid % 576;
    const int l0 = (rem >> 2) * 64, co0 = (rem & 3) * 64;
    const int t = threadIdx.x, lane = t & 63, nq = t >> 6;

    f32x4 acc[4];
#pragma unroll
    for (int nt = 0; nt < 4; ++nt) { f32x4 z = {0.f, 0.f, 0.f, 0.f}; acc[nt] = z; }

    const int aOff = (nq * 16 + (lane & 15)) * 40 + (lane >> 4) * 8;
    const int bK = (lane >> 4) * 8, bL = lane & 15;

    for (int kc = 0; kc < 8; ++kc) {
        const int c0 = kc * 32;
        __syncthreads();
        for (int s = t; s < 512; s += 256) {
            int co = s >> 3, q = s & 7;
            float4 v = *(const float4*)&wa[(size_t)(co0 + co) * 256 + c0 + q * 4];
            ushort4 b = {f2bf(v.x), f2bf(v.y), f2bf(v.z), f2bf(v.w)};
            *(ushort4*)&pA[co * 40 + q * 4] = b;
        }
        for (int s = t; s < 512; s += 256) {
            int c = s >> 4, l4 = s & 15;
            float4 v = *(const float4*)&x[((size_t)n * 256 + c0 + c) * L_ + l0 + l4 * 4];
            ushort4 b = {f2bf(v.x), f2bf(v.y), f2bf(v.z), f2bf(v.w)};
            *(ushort4*)&pB[c * 68 + l4 * 4] = b;
        }
        __syncthreads();
        u16x8 au = *(const u16x8*)&pA[aOff];
        bf16x8 af = __builtin_bit_cast(bf16x8, au);
#pragma unroll
        for (int nt = 0; nt < 4; ++nt) {
            u16x8 bu;
#pragma unroll
            for (int j = 0; j < 8; ++j) bu[j] = pB[(bK + j) * 68 + nt * 16 + bL];
            bf16x8 bf = __builtin_bit_cast(bf16x8, bu);
            acc[nt] = __builtin_amdgcn_mfma_f32_16x16x32_bf16(af, bf, acc[nt], 0, 0, 0);
        }
    }
    __syncthreads();
#pragma unroll
    for (int nt = 0; nt < 4; ++nt)
#pragma unroll
        for (int r = 0; r < 4; ++r)
            det[(nq * 16 + (lane >> 4) * 4 + r) * 67 + nt * 16 + (lane & 15)] = acc[nt][r];
    __syncthreads();
    for (int s = t; s < 512; s += 256) {
        int l = s >> 3, c8 = s & 7;       // 8 co per slot
        u16x8 o;
#pragma unroll
        for (int e = 0; e < 8; ++e) {
            int co = c8 * 8 + e;
            o[e] = f2bf(det[co * 67 + l] + ba[co0 + co]);
        }
        *(u16x8*)&yeb[((size_t)n * L_ + l0 + l) * 256 + co0 + c8 * 8] = o;
    }
}

// ---------------- kmeans assign (fp64 dot; norm is argmax-invariant) ----------------
__global__ __launch_bounds__(256) void k_assign(const float* __restrict__ xe,
                                                const float* __restrict__ means,
                                                int* __restrict__ codes_i,
                                                float* __restrict__ codes_f) {
    __shared__ float sm[128 * 64];
    for (int s = threadIdx.x; s < 8192; s += 256) sm[s] = means[s];
    __syncthreads();
    const int g = blockIdx.x * 256 + threadIdx.x;
    const float* row = xe + (size_t)g * 64;
    float v[64];
#pragma unroll
    for (int c4 = 0; c4 < 16; c4++) {
        float4 t4 = *(const float4*)(row + c4 * 4);
        v[c4 * 4 + 0] = t4.x; v[c4 * 4 + 1] = t4.y; v[c4 * 4 + 2] = t4.z; v[c4 * 4 + 3] = t4.w;
    }
    int best = 0;
    double bd = -1e300;
    for (int cl = 0; cl < 128; cl++) {
        double d = 0.0;
#pragma unroll
        for (int c4 = 0; c4 < 16; c4++) {
            float4 m4 = *(const float4*)(sm + cl * 64 + c4 * 4);
            d += (double)v[c4 * 4 + 0] * (double)m4.x + (double)v[c4 * 4 + 1] * (double)m4.y +
                 (double)v[c4 * 4 + 2] * (double)m4.z + (double)v[c4 * 4 + 3] * (double)m4.w;
        }
        if (d > bd) { bd = d; best = cl; }
    }
    codes_i[g] = best;
    codes_f[g] = (float)best;
}

// ---------------- stable counting sort ----------------
__global__ void k_hist(const int* __restrict__ codes_i, int* __restrict__ hist) {
    __shared__ int h[128];
    if (threadIdx.x < 128) h[threadIdx.x] = 0;
    __syncthreads();
    int n = blockIdx.x / 36, ch = blockIdx.x % 36;
    int c = codes_i[n * L_ + ch * 256 + threadIdx.x];
    atomicAdd(&h[c], 1);
    __syncthreads();
    if (threadIdx.x < 128) hist[(n * 36 + ch) * 128 + threadIdx.x] = h[threadIdx.x];
}

__global__ void k_scan(const int* __restrict__ hist, int* __restrict__ basebuf) {
    __shared__ int tot[128];
    __shared__ int binstart[128];
    int n = blockIdx.x, c = threadIdx.x;
    int run = 0;
    int local[36];
    for (int ch = 0; ch < 36; ch++) { local[ch] = run; run += hist[(n * 36 + ch) * 128 + c]; }
    tot[c] = run;
    __syncthreads();
    if (c == 0) {
        int s = 0;
        for (int b = 0; b < 128; b++) { binstart[b] = s; s += tot[b]; }
    }
    __syncthreads();
    int bs0 = binstart[c];
    for (int ch = 0; ch < 36; ch++) basebuf[(n * 36 + ch) * 128 + c] = bs0 + local[ch];
}

__global__ void k_rank(const int* __restrict__ codes_i, const int* __restrict__ basebuf,
                       int* __restrict__ idxb) {
    __shared__ int sc[256];
    __shared__ int sb[128];
    int n = blockIdx.x / 36, ch = blockIdx.x % 36;
    int i = threadIdx.x;
    int l = ch * 256 + i;
    int c = codes_i[n * L_ + l];
    sc[i] = c;
    if (i < 128) sb[i] = basebuf[(n * 36 + ch) * 128 + i];
    __syncthreads();
    int r = 0;
    for (int j = 0; j < i; j++) r += (sc[j] == c);
    int pos = sb[c] + r;
    idxb[n * L_ + pos] = l;
}

// ---------------- QK via bf16 MFMA: raw[i,j] = (xn_i . xn_j) * s_i ----------------
__global__ __launch_bounds__(256) void k_qk_mfma(const float* __restrict__ xe,
                                                 const int* __restrict__ idxb,
                                                 float* __restrict__ raw) {
    __shared__ __align__(16) unsigned short kb[432 * 72];
    __shared__ float snorm[144];
    __shared__ int sidx[432];
    const int bid = blockIdx.x;
    const int n = bid >> 6, k = bid & 63;
    const int t = threadIdx.x, lane = t & 63, nq = t >> 6;

    for (int s = t; s < 432; s += 256) {
        int wb = s / 144, jj = s % 144;
        int wk = (wb == 0) ? k : (wb == 1) ? ((k + 63) & 63) : ((k + 1) & 63);
        sidx[s] = idxb[n * L_ + wk * WIN + jj];
    }
    __syncthreads();
    for (int s = t; s < 6912; s += 256) {
        int row = s >> 4, q4 = s & 15;
        float4 v = *(const float4*)(xe + ((size_t)n * L_ + sidx[row]) * 64 + q4 * 4);
        float ss = v.x * v.x + v.y * v.y + v.z * v.z + v.w * v.w;
        ss += __shfl_xor(ss, 1); ss += __shfl_xor(ss, 2);
        ss += __shfl_xor(ss, 4); ss += __shfl_xor(ss, 8);
        float nr = fmaxf(sqrtf(ss), 5e-5f);
        float inv = 1.0f / nr;
        ushort4 b = {f2bf(v.x * inv), f2bf(v.y * inv), f2bf(v.z * inv), f2bf(v.w * inv)};
        *(ushort4*)&kb[row * 72 + q4 * 4] = b;
        if (q4 == 0 && row < 144) snorm[row] = nr;
    }
    __syncthreads();
    const int arow = lane & 15, aks = (lane >> 4) * 8;
    bf16x8 af[9][2];
#pragma unroll
    for (int mt = 0; mt < 9; ++mt) {
        af[mt][0] = *(const bf16x8*)&kb[(mt * 16 + arow) * 72 + aks];
        af[mt][1] = *(const bf16x8*)&kb[(mt * 16 + arow) * 72 + 32 + aks];
    }
    float sc[9][4];
#pragma unroll
    for (int mt = 0; mt < 9; ++mt)
#pragma unroll
        for (int r = 0; r < 4; ++r)
            sc[mt][r] = snorm[mt * 16 + (lane >> 4) * 4 + r];
    float* rbase = raw + (size_t)(n * NWIN + k) * WIN * KJ;
    for (int nt = nq; nt < 27; nt += 4) {
        const int col = nt * 16 + (lane & 15);
        bf16x8 b0 = *(const bf16x8*)&kb[col * 72 + aks];
        bf16x8 b1 = *(const bf16x8*)&kb[col * 72 + 32 + aks];
#pragma unroll
        for (int mt = 0; mt < 9; ++mt) {
            f32x4 acc = {0.f, 0.f, 0.f, 0.f};
            acc = __builtin_amdgcn_mfma_f32_16x16x32_bf16(af[mt][0], b0, acc, 0, 0, 0);
            acc = __builtin_amdgcn_mfma_f32_16x16x32_bf16(af[mt][1], b1, acc, 0, 0, 0);
#pragma unroll
            for (int r = 0; r < 4; ++r)
                rbase[(size_t)(mt * 16 + (lane >> 4) * 4 + r) * KJ + nt * 16 + (lane & 15)] =
                    acc[r] * sc[mt][r];
        }
    }
}

// ---------------- PV + fused softmax: probs->score, bs, retb (token order, bf16) ----
__global__ __launch_bounds__(256) void k_pv_sm(const unsigned short* __restrict__ yeb,
                                               const int* __restrict__ idxb,
                                               float* __restrict__ score,
                                               float* __restrict__ bs,
                                               unsigned short* __restrict__ retb) {
    __shared__ __align__(16) unsigned short pA[144 * 72];   // P[i][kk], stride 72
    __shared__ __align__(16) unsigned short pB[64 * 264];   // Y[kk][co], stride 264
    __shared__ int sidx[432];
    __shared__ float smax[144], sinv[144];
    const int bid = blockIdx.x;
    const int n = bid >> 6, k = bid & 63;
    const int t = threadIdx.x, lane = t & 63, nq = t >> 6;

    for (int s = t; s < 432; s += 256) {
        int wb = s / 144, jj = s % 144;
        int wk = (wb == 0) ? k : (wb == 1) ? ((k + 63) & 63) : ((k + 1) & 63);
        sidx[s] = idxb[n * L_ + wk * WIN + jj];
    }

    float* srow = score + (size_t)(n * NWIN + k) * WIN * KJ;
    for (int rr = 0; rr < 36; ++rr) {
        const int row = nq * 36 + rr;
        float v[7];
        float m = -1e30f;
#pragma unroll
        for (int it = 0; it < 7; ++it) {
            int j = lane + it * 64;
            v[it] = (j < KJ) ? srow[(size_t)row * KJ + j] : -1e30f;
            m = fmaxf(m, v[it]);
        }
#pragma unroll
        for (int o = 32; o >= 1; o >>= 1) m = fmaxf(m, __shfl_xor(m, o));
        float s = 0.f;
#pragma unroll
        for (int it = 0; it < 7; ++it)
            s += (lane + it * 64 < KJ) ? __expf(v[it] - m) : 0.f;
#pragma unroll
        for (int o = 32; o >= 1; o >>= 1) s += __shfl_xor(s, o);
        if (lane == 0) {
            smax[row] = m;
            sinv[row] = 1.f / s;
            bs[(size_t)(n * NWIN + k) * WIN + row] = m + logf(s);
        }
    }

    f32x4 acc[9][4];
#pragma unroll
    for (int mt = 0; mt < 9; ++mt)
#pragma unroll
        for (int nt = 0; nt < 4; ++nt) {
            f32x4 z = {0.f, 0.f, 0.f, 0.f};
            acc[mt][nt] = z;
        }

    const int aBase = (lane & 15) * 72 + (lane >> 4) * 8;
    const int bBase = (lane >> 4) * 8 * 264 + nq * 64 + (lane & 15);

    for (int kc = 0; kc < 7; ++kc) {
        __syncthreads();
        for (int s = t; s < 2304; s += 256) {
            int i = s >> 4, c4 = s & 15;
            int kcol = kc * 64 + c4 * 4;
            ushort4 b = {0, 0, 0, 0};
            if (kcol < KJ) {
                float4 v = *(const float4*)(srow + (size_t)i * KJ + kcol);
                float m = smax[i], iv = sinv[i];
                float4 p = {__expf(v.x - m) * iv, __expf(v.y - m) * iv,
                            __expf(v.z - m) * iv, __expf(v.w - m) * iv};
                *(float4*)(srow + (size_t)i * KJ + kcol) = p;
                b.x = f2bf(p.x); b.y = f2bf(p.y); b.z = f2bf(p.z); b.w = f2bf(p.w);
            }
            *(ushort4*)&pA[i * 72 + c4 * 4] = b;
        }
        for (int s = t; s < 2048; s += 256) {
            int j = s >> 5, c8 = s & 31;
            int kk = kc * 64 + j;
            u16x8 u = {0, 0, 0, 0, 0, 0, 0, 0};
            if (kk < KJ) u = *(const u16x8*)&yeb[(size_t)sidx[kk] * 256 +
                                                (size_t)n * L_ * 256 + c8 * 8];
            *(u16x8*)&pB[j * 264 + c8 * 8] = u;
        }
        __syncthreads();
#pragma unroll
        for (int ks = 0; ks < 2; ++ks) {
            bf16x8 af[9];
#pragma unroll
            for (int mt = 0; mt < 9; ++mt)
                af[mt] = *(const bf16x8*)&pA[aBase + mt * 1152 + ks * 32];
#pragma unroll
            for (int nt = 0; nt < 4; ++nt) {
                const int e = bBase + ks * 32 * 264 + nt * 16;
                u16x8 bu;
#pragma unroll
                for (int j = 0; j < 8; ++j) bu[j] = pB[e + j * 264];
                bf16x8 bf = __builtin_bit_cast(bf16x8, bu);
#pragma unroll
                for (int mt = 0; mt < 9; ++mt)
                    acc[mt][nt] = __builtin_amdgcn_mfma_f32_16x16x32_bf16(af[mt], bf, acc[mt][nt], 0, 0, 0);
            }
        }
    }
    const int rowb = (lane >> 4) * 4;
    const int colb = nq * 64 + (lane & 15);
#pragma unroll
    for (int mt = 0; mt < 9; ++mt)
#pragma unroll
        for (int nt = 0; nt < 4; ++nt)
#pragma unroll
            for (int r = 0; r < 4; ++r) {
                int row = mt * 16 + rowb + r;
                int tok = sidx[row];
                retb[((size_t)n * L_ + tok) * 256 + colb + nt * 16] = f2bf(acc[mt][nt][r]);
            }
}

// ---------------- final: out = x + 0.1 * retb (token order, bf16) ----------------
__global__ __launch_bounds__(256) void k_out(const float* __restrict__ x,
                                             const unsigned short* __restrict__ retb,
                                             float* __restrict__ out) {
    __shared__ float sr[32 * 257];
    const int n = blockIdx.x / 288, lt = blockIdx.x % 288;
    const int lbase = lt * 32;
    const int t = threadIdx.x;
    for (int s = t; s < 1024; s += 256) {
        int lr = s >> 5, c8 = s & 31;
        u16x8 u = *(const u16x8*)&retb[((size_t)n * L_ + lbase + lr) * 256 + c8 * 8];
#pragma unroll
        for (int e = 0; e < 8; ++e) sr[lr * 257 + c8 * 8 + e] = bf2f(u[e]);
    }
    __syncthreads();
    const int lr = t & 31, cog = t >> 5;
    for (int cc = 0; cc < 32; cc++) {
        int co = cog * 32 + cc;
        size_t gi = ((size_t)(n * 256 + co)) * L_ + lbase + lr;
        out[gi] = x[gi] + 0.1f * sr[lr * 257 + co];
    }
}

extern "C" void kernel_launch(void* const* d_in, const int* in_sizes, int n_in,
                              void* d_out, int out_size, void* d_ws, size_t ws_size,
                              hipStream_t stream) {
    (void)in_sizes; (void)n_in; (void)out_size; (void)ws_size;
    const float* x     = (const float*)d_in[0];
    const float* means = (const float*)d_in[1];
    const float* wm    = (const float*)d_in[2];
    const float* bm    = (const float*)d_in[3];
    const float* wa    = (const float*)d_in[4];
    const float* ba    = (const float*)d_in[5];

    float* out   = (float*)d_out;
    float* score = out + (size_t)8 * 256 * L_;
    float* bs    = score + (size_t)8 * NWIN * WIN * KJ;
    float* codesf = bs + (size_t)8 * L_;

    float* xe  = (float*)d_ws;
    float* ye  = xe + (size_t)8 * L_ * 64;                  // region reused as bf16 yeb
    float* ret = ye + (size_t)8 * L_ * 256;                 // parts (f32) then retb (bf16)
    float* wtr = ret + (size_t)8 * L_ * 256;
    int* codes_i = (int*)(wtr + 147456);
    int* idxb    = codes_i + 8 * L_;
    int* undo    = idxb + 8 * L_;                           // unused, keeps layout
    int* hist    = undo + 8 * L_;
    int* basebuf = hist + 8 * 36 * 128;
    float* zeros = (float*)(basebuf + 8 * 36 * 128);

    float* parts = ret;
    unsigned short* yeb  = (unsigned short*)ye;
    unsigned short* retb = (unsigned short*)ret;

    k_wprep  <<<576, 256, 0, stream>>>(wm, wtr, zeros);
    k_conv3x3<<<1536, 128, 0, stream>>>(x, wtr, zeros, parts);
    k_c3sum  <<<4608, 256, 0, stream>>>(parts, bm, xe);
    k_conv1x1<<<4608, 256, 0, stream>>>(x, wa, ba, yeb);
    k_assign <<<288, 256, 0, stream>>>(xe, means, codes_i, codesf);
    k_hist   <<<288, 256, 0, stream>>>(codes_i, hist);
    k_scan   <<<8, 128, 0, stream>>>(hist, basebuf);
    k_rank   <<<288, 256, 0, stream>>>(codes_i, basebuf, idxb);
    k_qk_mfma<<<512, 256, 0, stream>>>(xe, idxb, score);
    k_pv_sm  <<<512, 256, 0, stream>>>(yeb, idxb, score, bs, retb);
    k_out    <<<2304, 256, 0, stream>>>(x, retb, out);
}

// Round 12
// 699.826 us; speedup vs baseline: 5.9150x; 1.0956x over previous
//
#include <hip/hip_runtime.h>
#include <math.h>

#define L_    9216
#define WIN   144
#define NWIN  64
#define KJ    432

typedef __bf16 bf16x8 __attribute__((ext_vector_type(8)));
typedef unsigned short u16x8 __attribute__((ext_vector_type(8)));
typedef float f32x4 __attribute__((ext_vector_type(4)));

__device__ __forceinline__ unsigned short f2bf(float f) {
    unsigned int u = __builtin_bit_cast(unsigned int, f);
    u = (u + 0x7FFFu + ((u >> 16) & 1u)) >> 16;
    return (unsigned short)u;
}
__device__ __forceinline__ float bf2f(unsigned short u) {
    return __builtin_bit_cast(float, (unsigned int)u << 16);
}
__device__ __forceinline__ void load_lds16(const float* g, float* l) {
    __builtin_amdgcn_global_load_lds(
        (const __attribute__((address_space(1))) void*)g,
        (__attribute__((address_space(3))) void*)l, 16, 0, 0);
}

// ---------------- weight pre-transpose for conv3x3 (+ zero region) ----------------
__global__ void k_wprep(const float* __restrict__ wm, float* __restrict__ wtr,
                        float* __restrict__ zeros) {
    int s = blockIdx.x * 256 + threadIdx.x;       // 147456 total
    if (s < 147456) {
        int cq = s & 63, r = s >> 6;              // r = c*9+kk
        wtr[s] = wm[(size_t)cq * 2304 + r];
    }
    if (blockIdx.x == 0 && threadIdx.x < 64) zeros[threadIdx.x] = 0.f;
}

// ---------------- conv3x3 v10: split-K x2, 2 h-rows/block, async staging ----------
// grid 768 ((n*48+hp)*2+half), block 256 (4 waves; waves 0-1 row hp*2, waves 2-3
// row hp*2+1; per-half 16cg x 8wg); tile 12w x 4cq; 32 iters of 4 ch.
// LDS linear: [x: 4ch x 4r x 96][w: 4ch x 9kk x 64] = 3840 f per buffer.
// 4 shared x rows serve both output rows; weights fully shared.
__global__ __launch_bounds__(256) void k_conv3x3(const float* __restrict__ x,
                                                 const float* __restrict__ wtr,
                                                 const float* __restrict__ zeros,
                                                 float* __restrict__ parts) {
    __shared__ __align__(16) float stg[2][3840];   // 960 f4 slots per buffer
    const int bid = blockIdx.x;
    const int half = bid & 1;
    const int hp = (bid >> 1) % 48, n = bid / 96;
    const int chb = half * 128;
    const int t = threadIdx.x;
    const int hsel = t >> 7;                        // wave-pair selects output row
    const int t128 = t & 127;
    const int cg = t128 & 15, wg = t128 >> 4;
    const int w0 = wg * 12, cq0 = cg * 4;
    const int h = hp * 2 + hsel;
    const float* xb = x + (size_t)n * 256 * 9216;

    // staging: 960 f4 slots; s = c*256+t; s<384 = x (4ch x 4r x 24q), <960 = w, else idle
    int grel[4], gkind[4];                 // 0=x, 1=w, 2=zeros, 3=skip
#pragma unroll
    for (int c = 0; c < 4; ++c) {
        int s = c * 256 + t;
        if (s < 384) {
            int ch = s / 96, rr = (s % 96) / 24, q = s % 24;
            int hh = hp * 2 - 1 + rr;
            if (hh >= 0 && hh < 96) { gkind[c] = 0; grel[c] = ch * 9216 + hh * 96 + q * 4; }
            else                    { gkind[c] = 2; grel[c] = 0; }
        } else if (s < 960) {
            int u = s - 384;
            int ch = u / 144, kk = (u % 144) >> 4, q = u & 15;
            gkind[c] = 1; grel[c] = ch * 576 + kk * 64 + q * 4;
        } else {
            gkind[c] = 3; grel[c] = 0;
        }
    }
    const int wvbase = t & 192;            // wave base within block (lane x 16B implied)

#define C3_STAGE(buf, cb)                                                         \
    do {                                                                          \
        _Pragma("unroll")                                                         \
        for (int c = 0; c < 4; ++c) {                                             \
            if (gkind[c] != 3) {                                                  \
                const float* g = (gkind[c] == 0) ? (xb + (size_t)(cb) * 9216 + grel[c]) \
                               : (gkind[c] == 1) ? (wtr + (size_t)(cb) * 576 + grel[c]) \
                                                 : zeros;                         \
                load_lds16(g, &stg[buf][(c * 256 + wvbase) * 4]);                 \
            }                                                                     \
        }                                                                         \
    } while (0)

    float acc[12][4];
#pragma unroll
    for (int j = 0; j < 12; ++j)
#pragma unroll
        for (int q = 0; q < 4; ++q) acc[j][q] = 0.f;

    C3_STAGE(0, chb);
    __syncthreads();

    const int liIdx = (wg == 0) ? 0 : (w0 - 1);     // clamped in-bounds
    const int riIdx = (wg == 7) ? 95 : (w0 + 12);

    for (int it = 0; it < 32; ++it) {
        const int cur = it & 1;
        if (it < 31) C3_STAGE(cur ^ 1, chb + (it + 1) * 4);
        const float* xs = stg[cur];
        const float* ws = stg[cur] + 1536;
#pragma unroll
        for (int ch = 0; ch < 4; ++ch) {
#pragma unroll
            for (int dh = 0; dh < 3; ++dh) {
                const float* xrow = xs + ch * 384 + (hsel + dh) * 96;
                float4 wv0 = *(const float4*)(ws + ch * 576 + (dh * 3 + 0) * 64 + cq0);
                float4 wv1 = *(const float4*)(ws + ch * 576 + (dh * 3 + 1) * 64 + cq0);
                float4 wv2 = *(const float4*)(ws + ch * 576 + (dh * 3 + 2) * 64 + cq0);
                float xf[14];
                {
                    float lv = xrow[liIdx];
                    xf[0] = (wg == 0) ? 0.f : lv;
                    float4 a = *(const float4*)(xrow + w0);
                    float4 b = *(const float4*)(xrow + w0 + 4);
                    float4 c4v = *(const float4*)(xrow + w0 + 8);
                    xf[1] = a.x;  xf[2] = a.y;  xf[3] = a.z;  xf[4] = a.w;
                    xf[5] = b.x;  xf[6] = b.y;  xf[7] = b.z;  xf[8] = b.w;
                    xf[9] = c4v.x; xf[10] = c4v.y; xf[11] = c4v.z; xf[12] = c4v.w;
                    float rv = xrow[riIdx];
                    xf[13] = (wg == 7) ? 0.f : rv;
                }
#pragma unroll
                for (int j = 0; j < 12; ++j) {
                    acc[j][0] += xf[j] * wv0.x;
                    acc[j][1] += xf[j] * wv0.y;
                    acc[j][2] += xf[j] * wv0.z;
                    acc[j][3] += xf[j] * wv0.w;
                }
#pragma unroll
                for (int j = 0; j < 12; ++j) {
                    acc[j][0] += xf[j + 1] * wv1.x;
                    acc[j][1] += xf[j + 1] * wv1.y;
                    acc[j][2] += xf[j + 1] * wv1.z;
                    acc[j][3] += xf[j + 1] * wv1.w;
                }
#pragma unroll
                for (int j = 0; j < 12; ++j) {
                    acc[j][0] += xf[j + 2] * wv2.x;
                    acc[j][1] += xf[j + 2] * wv2.y;
                    acc[j][2] += xf[j + 2] * wv2.z;
                    acc[j][3] += xf[j + 2] * wv2.w;
                }
            }
        }
        __syncthreads();
    }
#undef C3_STAGE

    float* pb = parts + (size_t)half * 4718592;
#pragma unroll
    for (int j = 0; j < 12; ++j) {
        float4 o = {acc[j][0], acc[j][1], acc[j][2], acc[j][3]};
        *(float4*)&pb[((size_t)n * L_ + (size_t)h * 96 + w0 + j) * 64 + cq0] = o;
    }
}

// ---------------- combine split-K partials + bias -> xe ----------------
__global__ __launch_bounds__(256) void k_c3sum(const float* __restrict__ parts,
                                               const float* __restrict__ bm,
                                               float* __restrict__ xe) {
    size_t i = (size_t)blockIdx.x * 256 + threadIdx.x;   // f4 index; grid 4608
    float4 a = ((const float4*)parts)[i];
    float4 b = ((const float4*)parts)[i + 1179648];
    float4 bi = ((const float4*)bm)[i & 15];
    float4 o = {a.x + b.x + bi.x, a.y + b.y + bi.y, a.z + b.z + bi.z, a.w + b.w + bi.w};
    ((float4*)xe)[i] = o;
}

// ---------------- conv1x1 via bf16 MFMA -> yeb bf16 [8,9216,256] ----------------
__global__ __launch_bounds__(256) void k_conv1x1(const float* __restrict__ x,
                                                 const float* __restrict__ wa,
                                                 const float* __restrict__ ba,
                                                 unsigned short* __restrict__ yeb) {
    __shared__ __align__(16) unsigned short pA[64 * 40];  // [co][k], pad 40
    __shared__ __align__(16) unsigned short pB[32 * 68];  // [k][l],  pad 68
    __shared__ __align__(16) float det[64 * 67];          // [co][l], pad 67
    const int bid = blockIdx.x;
    const int n = bid / 576, rem = bid % 576;
    const int l0 = (rem >> 2) * 64, co0 = (rem & 3) * 64;
    const int t = threadIdx.x, lane = t & 63, nq = t >> 6;

    f32x4 acc[4];
#pragma unroll
    for (int nt = 0; nt < 4; ++nt) { f32x4 z = {0.f, 0.f, 0.f, 0.f}; acc[nt] = z; }

    const int aOff = (nq * 16 + (lane & 15)) * 40 + (lane >> 4) * 8;
    const int bK = (lane >> 4) * 8, bL = lane & 15;

    for (int kc = 0; kc < 8; ++kc) {
        const int c0 = kc * 32;
        __syncthreads();
        for (int s = t; s < 512; s += 256) {
            int co = s >> 3, q = s & 7;
            float4 v = *(const float4*)&wa[(size_t)(co0 + co) * 256 + c0 + q * 4];
            ushort4 b = {f2bf(v.x), f2bf(v.y), f2bf(v.z), f2bf(v.w)};
            *(ushort4*)&pA[co * 40 + q * 4] = b;
        }
        for (int s = t; s < 512; s += 256) {
            int c = s >> 4, l4 = s & 15;
            float4 v = *(const float4*)&x[((size_t)n * 256 + c0 + c) * L_ + l0 + l4 * 4];
            ushort4 b = {f2bf(v.x), f2bf(v.y), f2bf(v.z), f2bf(v.w)};
            *(ushort4*)&pB[c * 68 + l4 * 4] = b;
        }
        __syncthreads();
        u16x8 au = *(const u16x8*)&pA[aOff];
        bf16x8 af = __builtin_bit_cast(bf16x8, au);
#pragma unroll
        for (int nt = 0; nt < 4; ++nt) {
            u16x8 bu;
#pragma unroll
            for (int j = 0; j < 8; ++j) bu[j] = pB[(bK + j) * 68 + nt * 16 + bL];
            bf16x8 bf = __builtin_bit_cast(bf16x8, bu);
            acc[nt] = __builtin_amdgcn_mfma_f32_16x16x32_bf16(af, bf, acc[nt], 0, 0, 0);
        }
    }
    __syncthreads();
#pragma unroll
    for (int nt = 0; nt < 4; ++nt)
#pragma unroll
        for (int r = 0; r < 4; ++r)
            det[(nq * 16 + (lane >> 4) * 4 + r) * 67 + nt * 16 + (lane & 15)] = acc[nt][r];
    __syncthreads();
    for (int s = t; s < 512; s += 256) {
        int l = s >> 3, c8 = s & 7;       // 8 co per slot
        u16x8 o;
#pragma unroll
        for (int e = 0; e < 8; ++e) {
            int co = c8 * 8 + e;
            o[e] = f2bf(det[co * 67 + l] + ba[co0 + co]);
        }
        *(u16x8*)&yeb[((size_t)n * L_ + l0 + l) * 256 + co0 + c8 * 8] = o;
    }
}

// ---------------- kmeans assign (fp64 dot; norm is argmax-invariant) ----------------
__global__ __launch_bounds__(256) void k_assign(const float* __restrict__ xe,
                                                const float* __restrict__ means,
                                                int* __restrict__ codes_i,
                                                float* __restrict__ codes_f) {
    __shared__ float sm[128 * 64];
    for (int s = threadIdx.x; s < 8192; s += 256) sm[s] = means[s];
    __syncthreads();
    const int g = blockIdx.x * 256 + threadIdx.x;
    const float* row = xe + (size_t)g * 64;
    float v[64];
#pragma unroll
    for (int c4 = 0; c4 < 16; c4++) {
        float4 t4 = *(const float4*)(row + c4 * 4);
        v[c4 * 4 + 0] = t4.x; v[c4 * 4 + 1] = t4.y; v[c4 * 4 + 2] = t4.z; v[c4 * 4 + 3] = t4.w;
    }
    int best = 0;
    double bd = -1e300;
    for (int cl = 0; cl < 128; cl++) {
        double d = 0.0;
#pragma unroll
        for (int c4 = 0; c4 < 16; c4++) {
            float4 m4 = *(const float4*)(sm + cl * 64 + c4 * 4);
            d += (double)v[c4 * 4 + 0] * (double)m4.x + (double)v[c4 * 4 + 1] * (double)m4.y +
                 (double)v[c4 * 4 + 2] * (double)m4.z + (double)v[c4 * 4 + 3] * (double)m4.w;
        }
        if (d > bd) { bd = d; best = cl; }
    }
    codes_i[g] = best;
    codes_f[g] = (float)best;
}

// ---------------- stable counting sort ----------------
__global__ void k_hist(const int* __restrict__ codes_i, int* __restrict__ hist) {
    __shared__ int h[128];
    if (threadIdx.x < 128) h[threadIdx.x] = 0;
    __syncthreads();
    int n = blockIdx.x / 36, ch = blockIdx.x % 36;
    int c = codes_i[n * L_ + ch * 256 + threadIdx.x];
    atomicAdd(&h[c], 1);
    __syncthreads();
    if (threadIdx.x < 128) hist[(n * 36 + ch) * 128 + threadIdx.x] = h[threadIdx.x];
}

__global__ void k_scan(const int* __restrict__ hist, int* __restrict__ basebuf) {
    __shared__ int tot[128];
    __shared__ int binstart[128];
    int n = blockIdx.x, c = threadIdx.x;
    int run = 0;
    int local[36];
    for (int ch = 0; ch < 36; ch++) { local[ch] = run; run += hist[(n * 36 + ch) * 128 + c]; }
    tot[c] = run;
    __syncthreads();
    if (c == 0) {
        int s = 0;
        for (int b = 0; b < 128; b++) { binstart[b] = s; s += tot[b]; }
    }
    __syncthreads();
    int bs0 = binstart[c];
    for (int ch = 0; ch < 36; ch++) basebuf[(n * 36 + ch) * 128 + c] = bs0 + local[ch];
}

__global__ void k_rank(const int* __restrict__ codes_i, const int* __restrict__ basebuf,
                       int* __restrict__ idxb) {
    __shared__ int sc[256];
    __shared__ int sb[128];
    int n = blockIdx.x / 36, ch = blockIdx.x % 36;
    int i = threadIdx.x;
    int l = ch * 256 + i;
    int c = codes_i[n * L_ + l];
    sc[i] = c;
    if (i < 128) sb[i] = basebuf[(n * 36 + ch) * 128 + i];
    __syncthreads();
    int r = 0;
    for (int j = 0; j < i; j++) r += (sc[j] == c);
    int pos = sb[c] + r;
    idxb[n * L_ + pos] = l;
}

// ---------------- QK via bf16 MFMA: raw[i,j] = (xn_i . xn_j) * s_i ----------------
__global__ __launch_bounds__(256) void k_qk_mfma(const float* __restrict__ xe,
                                                 const int* __restrict__ idxb,
                                                 float* __restrict__ raw) {
    __shared__ __align__(16) unsigned short kb[432 * 72];
    __shared__ float snorm[144];
    __shared__ int sidx[432];
    const int bid = blockIdx.x;
    const int n = bid >> 6, k = bid & 63;
    const int t = threadIdx.x, lane = t & 63, nq = t >> 6;

    for (int s = t; s < 432; s += 256) {
        int wb = s / 144, jj = s % 144;
        int wk = (wb == 0) ? k : (wb == 1) ? ((k + 63) & 63) : ((k + 1) & 63);
        sidx[s] = idxb[n * L_ + wk * WIN + jj];
    }
    __syncthreads();
    for (int s = t; s < 6912; s += 256) {
        int row = s >> 4, q4 = s & 15;
        float4 v = *(const float4*)(xe + ((size_t)n * L_ + sidx[row]) * 64 + q4 * 4);
        float ss = v.x * v.x + v.y * v.y + v.z * v.z + v.w * v.w;
        ss += __shfl_xor(ss, 1); ss += __shfl_xor(ss, 2);
        ss += __shfl_xor(ss, 4); ss += __shfl_xor(ss, 8);
        float nr = fmaxf(sqrtf(ss), 5e-5f);
        float inv = 1.0f / nr;
        ushort4 b = {f2bf(v.x * inv), f2bf(v.y * inv), f2bf(v.z * inv), f2bf(v.w * inv)};
        *(ushort4*)&kb[row * 72 + q4 * 4] = b;
        if (q4 == 0 && row < 144) snorm[row] = nr;
    }
    __syncthreads();
    const int arow = lane & 15, aks = (lane >> 4) * 8;
    bf16x8 af[9][2];
#pragma unroll
    for (int mt = 0; mt < 9; ++mt) {
        af[mt][0] = *(const bf16x8*)&kb[(mt * 16 + arow) * 72 + aks];
        af[mt][1] = *(const bf16x8*)&kb[(mt * 16 + arow) * 72 + 32 + aks];
    }
    float sc[9][4];
#pragma unroll
    for (int mt = 0; mt < 9; ++mt)
#pragma unroll
        for (int r = 0; r < 4; ++r)
            sc[mt][r] = snorm[mt * 16 + (lane >> 4) * 4 + r];
    float* rbase = raw + (size_t)(n * NWIN + k) * WIN * KJ;
    for (int nt = nq; nt < 27; nt += 4) {
        const int col = nt * 16 + (lane & 15);
        bf16x8 b0 = *(const bf16x8*)&kb[col * 72 + aks];
        bf16x8 b1 = *(const bf16x8*)&kb[col * 72 + 32 + aks];
#pragma unroll
        for (int mt = 0; mt < 9; ++mt) {
            f32x4 acc = {0.f, 0.f, 0.f, 0.f};
            acc = __builtin_amdgcn_mfma_f32_16x16x32_bf16(af[mt][0], b0, acc, 0, 0, 0);
            acc = __builtin_amdgcn_mfma_f32_16x16x32_bf16(af[mt][1], b1, acc, 0, 0, 0);
#pragma unroll
            for (int r = 0; r < 4; ++r)
                rbase[(size_t)(mt * 16 + (lane >> 4) * 4 + r) * KJ + nt * 16 + (lane & 15)] =
                    acc[r] * sc[mt][r];
        }
    }
}

// ---------------- PV + fused softmax: probs->score, bs, retb (token order, bf16) ----
__global__ __launch_bounds__(256) void k_pv_sm(const unsigned short* __restrict__ yeb,
                                               const int* __restrict__ idxb,
                                               float* __restrict__ score,
                                               float* __restrict__ bs,
                                               unsigned short* __restrict__ retb) {
    __shared__ __align__(16) unsigned short pA[144 * 72];   // P[i][kk], stride 72
    __shared__ __align__(16) unsigned short pB[64 * 264];   // Y[kk][co], stride 264
    __shared__ int sidx[432];
    __shared__ float smax[144], sinv[144];
    const int bid = blockIdx.x;
    const int n = bid >> 6, k = bid & 63;
    const int t = threadIdx.x, lane = t & 63, nq = t >> 6;

    for (int s = t; s < 432; s += 256) {
        int wb = s / 144, jj = s % 144;
        int wk = (wb == 0) ? k : (wb == 1) ? ((k + 63) & 63) : ((k + 1) & 63);
        sidx[s] = idxb[n * L_ + wk * WIN + jj];
    }

    float* srow = score + (size_t)(n * NWIN + k) * WIN * KJ;
    for (int rr = 0; rr < 36; ++rr) {
        const int row = nq * 36 + rr;
        float v[7];
        float m = -1e30f;
#pragma unroll
        for (int it = 0; it < 7; ++it) {
            int j = lane + it * 64;
            v[it] = (j < KJ) ? srow[(size_t)row * KJ + j] : -1e30f;
            m = fmaxf(m, v[it]);
        }
#pragma unroll
        for (int o = 32; o >= 1; o >>= 1) m = fmaxf(m, __shfl_xor(m, o));
        float s = 0.f;
#pragma unroll
        for (int it = 0; it < 7; ++it)
            s += (lane + it * 64 < KJ) ? __expf(v[it] - m) : 0.f;
#pragma unroll
        for (int o = 32; o >= 1; o >>= 1) s += __shfl_xor(s, o);
        if (lane == 0) {
            smax[row] = m;
            sinv[row] = 1.f / s;
            bs[(size_t)(n * NWIN + k) * WIN + row] = m + logf(s);
        }
    }

    f32x4 acc[9][4];
#pragma unroll
    for (int mt = 0; mt < 9; ++mt)
#pragma unroll
        for (int nt = 0; nt < 4; ++nt) {
            f32x4 z = {0.f, 0.f, 0.f, 0.f};
            acc[mt][nt] = z;
        }

    const int aBase = (lane & 15) * 72 + (lane >> 4) * 8;
    const int bBase = (lane >> 4) * 8 * 264 + nq * 64 + (lane & 15);

    for (int kc = 0; kc < 7; ++kc) {
        __syncthreads();
        for (int s = t; s < 2304; s += 256) {
            int i = s >> 4, c4 = s & 15;
            int kcol = kc * 64 + c4 * 4;
            ushort4 b = {0, 0, 0, 0};
            if (kcol < KJ) {
                float4 v = *(const float4*)(srow + (size_t)i * KJ + kcol);
                float m = smax[i], iv = sinv[i];
                float4 p = {__expf(v.x - m) * iv, __expf(v.y - m) * iv,
                            __expf(v.z - m) * iv, __expf(v.w - m) * iv};
                *(float4*)(srow + (size_t)i * KJ + kcol) = p;
                b.x = f2bf(p.x); b.y = f2bf(p.y); b.z = f2bf(p.z); b.w = f2bf(p.w);
            }
            *(ushort4*)&pA[i * 72 + c4 * 4] = b;
        }
        for (int s = t; s < 2048; s += 256) {
            int j = s >> 5, c8 = s & 31;
            int kk = kc * 64 + j;
            u16x8 u = {0, 0, 0, 0, 0, 0, 0, 0};
            if (kk < KJ) u = *(const u16x8*)&yeb[(size_t)sidx[kk] * 256 +
                                                (size_t)n * L_ * 256 + c8 * 8];
            *(u16x8*)&pB[j * 264 + c8 * 8] = u;
        }
        __syncthreads();
#pragma unroll
        for (int ks = 0; ks < 2; ++ks) {
            bf16x8 af[9];
#pragma unroll
            for (int mt = 0; mt < 9; ++mt)
                af[mt] = *(const bf16x8*)&pA[aBase + mt * 1152 + ks * 32];
#pragma unroll
            for (int nt = 0; nt < 4; ++nt) {
                const int e = bBase + ks * 32 * 264 + nt * 16;
                u16x8 bu;
#pragma unroll
                for (int j = 0; j < 8; ++j) bu[j] = pB[e + j * 264];
                bf16x8 bf = __builtin_bit_cast(bf16x8, bu);
#pragma unroll
                for (int mt = 0; mt < 9; ++mt)
                    acc[mt][nt] = __builtin_amdgcn_mfma_f32_16x16x32_bf16(af[mt], bf, acc[mt][nt], 0, 0, 0);
            }
        }
    }
    const int rowb = (lane >> 4) * 4;
    const int colb = nq * 64 + (lane & 15);
#pragma unroll
    for (int mt = 0; mt < 9; ++mt)
#pragma unroll
        for (int nt = 0; nt < 4; ++nt)
#pragma unroll
            for (int r = 0; r < 4; ++r) {
                int row = mt * 16 + rowb + r;
                int tok = sidx[row];
                retb[((size_t)n * L_ + tok) * 256 + colb + nt * 16] = f2bf(acc[mt][nt][r]);
            }
}

// ---------------- final: out = x + 0.1 * retb (token order, bf16) ----------------
__global__ __launch_bounds__(256) void k_out(const float* __restrict__ x,
                                             const unsigned short* __restrict__ retb,
                                             float* __restrict__ out) {
    __shared__ float sr[32 * 257];
    const int n = blockIdx.x / 288, lt = blockIdx.x % 288;
    const int lbase = lt * 32;
    const int t = threadIdx.x;
    for (int s = t; s < 1024; s += 256) {
        int lr = s >> 5, c8 = s & 31;
        u16x8 u = *(const u16x8*)&retb[((size_t)n * L_ + lbase + lr) * 256 + c8 * 8];
#pragma unroll
        for (int e = 0; e < 8; ++e) sr[lr * 257 + c8 * 8 + e] = bf2f(u[e]);
    }
    __syncthreads();
    const int lr = t & 31, cog = t >> 5;
    for (int cc = 0; cc < 32; cc++) {
        int co = cog * 32 + cc;
        size_t gi = ((size_t)(n * 256 + co)) * L_ + lbase + lr;
        out[gi] = x[gi] + 0.1f * sr[lr * 257 + co];
    }
}

extern "C" void kernel_launch(void* const* d_in, const int* in_sizes, int n_in,
                              void* d_out, int out_size, void* d_ws, size_t ws_size,
                              hipStream_t stream) {
    (void)in_sizes; (void)n_in; (void)out_size; (void)ws_size;
    const float* x     = (const float*)d_in[0];
    const float* means = (const float*)d_in[1];
    const float* wm    = (const float*)d_in[2];
    const float* bm    = (const float*)d_in[3];
    const float* wa    = (const float*)d_in[4];
    const float* ba    = (const float*)d_in[5];

    float* out   = (float*)d_out;
    float* score = out + (size_t)8 * 256 * L_;
    float* bs    = score + (size_t)8 * NWIN * WIN * KJ;
    float* codesf = bs + (size_t)8 * L_;

    float* xe  = (float*)d_ws;
    float* ye  = xe + (size_t)8 * L_ * 64;                  // region reused as bf16 yeb
    float* ret = ye + (size_t)8 * L_ * 256;                 // parts (f32) then retb (bf16)
    float* wtr = ret + (size_t)8 * L_ * 256;
    int* codes_i = (int*)(wtr + 147456);
    int* idxb    = codes_i + 8 * L_;
    int* undo    = idxb + 8 * L_;                           // unused, keeps layout
    int* hist    = undo + 8 * L_;
    int* basebuf = hist + 8 * 36 * 128;
    float* zeros = (float*)(basebuf + 8 * 36 * 128);

    float* parts = ret;
    unsigned short* yeb  = (unsigned short*)ye;
    unsigned short* retb = (unsigned short*)ret;

    k_wprep  <<<576, 256, 0, stream>>>(wm, wtr, zeros);
    k_conv3x3<<<768, 256, 0, stream>>>(x, wtr, zeros, parts);
    k_c3sum  <<<4608, 256, 0, stream>>>(parts, bm, xe);
    k_conv1x1<<<4608, 256, 0, stream>>>(x, wa, ba, yeb);
    k_assign <<<288, 256, 0, stream>>>(xe, means, codes_i, codesf);
    k_hist   <<<288, 256, 0, stream>>>(codes_i, hist);
    k_scan   <<<8, 128, 0, stream>>>(hist, basebuf);
    k_rank   <<<288, 256, 0, stream>>>(codes_i, basebuf, idxb);
    k_qk_mfma<<<512, 256, 0, stream>>>(xe, idxb, score);
    k_pv_sm  <<<512, 256, 0, stream>>>(yeb, idxb, score, bs, retb);
    k_out    <<<2304, 256, 0, stream>>>(x, retb, out);
}

// Round 13
// 667.805 us; speedup vs baseline: 6.1986x; 1.0479x over previous
//
#include <hip/hip_runtime.h>
#include <math.h>

#define L_    9216
#define WIN   144
#define NWIN  64
#define KJ    432

typedef __bf16 bf16x8 __attribute__((ext_vector_type(8)));
typedef unsigned short u16x8 __attribute__((ext_vector_type(8)));
typedef float f32x4 __attribute__((ext_vector_type(4)));

__device__ __forceinline__ unsigned short f2bf(float f) {
    unsigned int u = __builtin_bit_cast(unsigned int, f);
    u = (u + 0x7FFFu + ((u >> 16) & 1u)) >> 16;
    return (unsigned short)u;
}
__device__ __forceinline__ float bf2f(unsigned short u) {
    return __builtin_bit_cast(float, (unsigned int)u << 16);
}
__device__ __forceinline__ void load_lds16(const float* g, float* l) {
    __builtin_amdgcn_global_load_lds(
        (const __attribute__((address_space(1))) void*)g,
        (__attribute__((address_space(3))) void*)l, 16, 0, 0);
}

// ---------------- weight pre-transpose for conv3x3 (+ zero region) ----------------
__global__ void k_wprep(const float* __restrict__ wm, float* __restrict__ wtr,
                        float* __restrict__ zeros) {
    int s = blockIdx.x * 256 + threadIdx.x;       // 147456 total
    if (s < 147456) {
        int cq = s & 63, r = s >> 6;              // r = c*9+kk
        wtr[s] = wm[(size_t)cq * 2304 + r];
    }
    if (blockIdx.x == 0 && threadIdx.x < 64) zeros[threadIdx.x] = 0.f;
}

// ---------------- conv3x3 v10: split-K x2, 2 h-rows/block, async staging ----------
__global__ __launch_bounds__(256) void k_conv3x3(const float* __restrict__ x,
                                                 const float* __restrict__ wtr,
                                                 const float* __restrict__ zeros,
                                                 float* __restrict__ parts) {
    __shared__ __align__(16) float stg[2][3840];   // 960 f4 slots per buffer
    const int bid = blockIdx.x;
    const int half = bid & 1;
    const int hp = (bid >> 1) % 48, n = bid / 96;
    const int chb = half * 128;
    const int t = threadIdx.x;
    const int hsel = t >> 7;                        // wave-pair selects output row
    const int t128 = t & 127;
    const int cg = t128 & 15, wg = t128 >> 4;
    const int w0 = wg * 12, cq0 = cg * 4;
    const int h = hp * 2 + hsel;
    const float* xb = x + (size_t)n * 256 * 9216;

    int grel[4], gkind[4];                 // 0=x, 1=w, 2=zeros, 3=skip
#pragma unroll
    for (int c = 0; c < 4; ++c) {
        int s = c * 256 + t;
        if (s < 384) {
            int ch = s / 96, rr = (s % 96) / 24, q = s % 24;
            int hh = hp * 2 - 1 + rr;
            if (hh >= 0 && hh < 96) { gkind[c] = 0; grel[c] = ch * 9216 + hh * 96 + q * 4; }
            else                    { gkind[c] = 2; grel[c] = 0; }
        } else if (s < 960) {
            int u = s - 384;
            int ch = u / 144, kk = (u % 144) >> 4, q = u & 15;
            gkind[c] = 1; grel[c] = ch * 576 + kk * 64 + q * 4;
        } else {
            gkind[c] = 3; grel[c] = 0;
        }
    }
    const int wvbase = t & 192;

#define C3_STAGE(buf, cb)                                                         \
    do {                                                                          \
        _Pragma("unroll")                                                         \
        for (int c = 0; c < 4; ++c) {                                             \
            if (gkind[c] != 3) {                                                  \
                const float* g = (gkind[c] == 0) ? (xb + (size_t)(cb) * 9216 + grel[c]) \
                               : (gkind[c] == 1) ? (wtr + (size_t)(cb) * 576 + grel[c]) \
                                                 : zeros;                         \
                load_lds16(g, &stg[buf][(c * 256 + wvbase) * 4]);                 \
            }                                                                     \
        }                                                                         \
    } while (0)

    float acc[12][4];
#pragma unroll
    for (int j = 0; j < 12; ++j)
#pragma unroll
        for (int q = 0; q < 4; ++q) acc[j][q] = 0.f;

    C3_STAGE(0, chb);
    __syncthreads();

    const int liIdx = (wg == 0) ? 0 : (w0 - 1);
    const int riIdx = (wg == 7) ? 95 : (w0 + 12);

    for (int it = 0; it < 32; ++it) {
        const int cur = it & 1;
        if (it < 31) C3_STAGE(cur ^ 1, chb + (it + 1) * 4);
        const float* xs = stg[cur];
        const float* ws = stg[cur] + 1536;
#pragma unroll
        for (int ch = 0; ch < 4; ++ch) {
#pragma unroll
            for (int dh = 0; dh < 3; ++dh) {
                const float* xrow = xs + ch * 384 + (hsel + dh) * 96;
                float4 wv0 = *(const float4*)(ws + ch * 576 + (dh * 3 + 0) * 64 + cq0);
                float4 wv1 = *(const float4*)(ws + ch * 576 + (dh * 3 + 1) * 64 + cq0);
                float4 wv2 = *(const float4*)(ws + ch * 576 + (dh * 3 + 2) * 64 + cq0);
                float xf[14];
                {
                    float lv = xrow[liIdx];
                    xf[0] = (wg == 0) ? 0.f : lv;
                    float4 a = *(const float4*)(xrow + w0);
                    float4 b = *(const float4*)(xrow + w0 + 4);
                    float4 c4v = *(const float4*)(xrow + w0 + 8);
                    xf[1] = a.x;  xf[2] = a.y;  xf[3] = a.z;  xf[4] = a.w;
                    xf[5] = b.x;  xf[6] = b.y;  xf[7] = b.z;  xf[8] = b.w;
                    xf[9] = c4v.x; xf[10] = c4v.y; xf[11] = c4v.z; xf[12] = c4v.w;
                    float rv = xrow[riIdx];
                    xf[13] = (wg == 7) ? 0.f : rv;
                }
#pragma unroll
                for (int j = 0; j < 12; ++j) {
                    acc[j][0] += xf[j] * wv0.x;
                    acc[j][1] += xf[j] * wv0.y;
                    acc[j][2] += xf[j] * wv0.z;
                    acc[j][3] += xf[j] * wv0.w;
                }
#pragma unroll
                for (int j = 0; j < 12; ++j) {
                    acc[j][0] += xf[j + 1] * wv1.x;
                    acc[j][1] += xf[j + 1] * wv1.y;
                    acc[j][2] += xf[j + 1] * wv1.z;
                    acc[j][3] += xf[j + 1] * wv1.w;
                }
#pragma unroll
                for (int j = 0; j < 12; ++j) {
                    acc[j][0] += xf[j + 2] * wv2.x;
                    acc[j][1] += xf[j + 2] * wv2.y;
                    acc[j][2] += xf[j + 2] * wv2.z;
                    acc[j][3] += xf[j + 2] * wv2.w;
                }
            }
        }
        __syncthreads();
    }
#undef C3_STAGE

    float* pb = parts + (size_t)half * 4718592;
#pragma unroll
    for (int j = 0; j < 12; ++j) {
        float4 o = {acc[j][0], acc[j][1], acc[j][2], acc[j][3]};
        *(float4*)&pb[((size_t)n * L_ + (size_t)h * 96 + w0 + j) * 64 + cq0] = o;
    }
}

// ---------------- combine split-K partials + bias -> xe ----------------
__global__ __launch_bounds__(256) void k_c3sum(const float* __restrict__ parts,
                                               const float* __restrict__ bm,
                                               float* __restrict__ xe) {
    size_t i = (size_t)blockIdx.x * 256 + threadIdx.x;   // f4 index; grid 4608
    float4 a = ((const float4*)parts)[i];
    float4 b = ((const float4*)parts)[i + 1179648];
    float4 bi = ((const float4*)bm)[i & 15];
    float4 o = {a.x + b.x + bi.x, a.y + b.y + bi.y, a.z + b.z + bi.z, a.w + b.w + bi.w};
    ((float4*)xe)[i] = o;
}

// ---------------- conv1x1 via bf16 MFMA -> yeb bf16 [8,9216,256] ----------------
__global__ __launch_bounds__(256) void k_conv1x1(const float* __restrict__ x,
                                                 const float* __restrict__ wa,
                                                 const float* __restrict__ ba,
                                                 unsigned short* __restrict__ yeb) {
    __shared__ __align__(16) unsigned short pA[64 * 40];  // [co][k], pad 40
    __shared__ __align__(16) unsigned short pB[32 * 68];  // [k][l],  pad 68
    __shared__ __align__(16) float det[64 * 67];          // [co][l], pad 67
    const int bid = blockIdx.x;
    const int n = bid / 576, rem = bid % 576;
    const int l0 = (rem >> 2) * 64, co0 = (rem & 3) * 64;
    const int t = threadIdx.x, lane = t & 63, nq = t >> 6;

    f32x4 acc[4];
#pragma unroll
    for (int nt = 0; nt < 4; ++nt) { f32x4 z = {0.f, 0.f, 0.f, 0.f}; acc[nt] = z; }

    const int aOff = (nq * 16 + (lane & 15)) * 40 + (lane >> 4) * 8;
    const int bK = (lane >> 4) * 8, bL = lane & 15;

    for (int kc = 0; kc < 8; ++kc) {
        const int c0 = kc * 32;
        __syncthreads();
        for (int s = t; s < 512; s += 256) {
            int co = s >> 3, q = s & 7;
            float4 v = *(const float4*)&wa[(size_t)(co0 + co) * 256 + c0 + q * 4];
            ushort4 b = {f2bf(v.x), f2bf(v.y), f2bf(v.z), f2bf(v.w)};
            *(ushort4*)&pA[co * 40 + q * 4] = b;
        }
        for (int s = t; s < 512; s += 256) {
            int c = s >> 4, l4 = s & 15;
            float4 v = *(const float4*)&x[((size_t)n * 256 + c0 + c) * L_ + l0 + l4 * 4];
            ushort4 b = {f2bf(v.x), f2bf(v.y), f2bf(v.z), f2bf(v.w)};
            *(ushort4*)&pB[c * 68 + l4 * 4] = b;
        }
        __syncthreads();
        u16x8 au = *(const u16x8*)&pA[aOff];
        bf16x8 af = __builtin_bit_cast(bf16x8, au);
#pragma unroll
        for (int nt = 0; nt < 4; ++nt) {
            u16x8 bu;
#pragma unroll
            for (int j = 0; j < 8; ++j) bu[j] = pB[(bK + j) * 68 + nt * 16 + bL];
            bf16x8 bf = __builtin_bit_cast(bf16x8, bu);
            acc[nt] = __builtin_amdgcn_mfma_f32_16x16x32_bf16(af, bf, acc[nt], 0, 0, 0);
        }
    }
    __syncthreads();
#pragma unroll
    for (int nt = 0; nt < 4; ++nt)
#pragma unroll
        for (int r = 0; r < 4; ++r)
            det[(nq * 16 + (lane >> 4) * 4 + r) * 67 + nt * 16 + (lane & 15)] = acc[nt][r];
    __syncthreads();
    for (int s = t; s < 512; s += 256) {
        int l = s >> 3, c8 = s & 7;       // 8 co per slot
        u16x8 o;
#pragma unroll
        for (int e = 0; e < 8; ++e) {
            int co = c8 * 8 + e;
            o[e] = f2bf(det[co * 67 + l] + ba[co0 + co]);
        }
        *(u16x8*)&yeb[((size_t)n * L_ + l0 + l) * 256 + co0 + c8 * 8] = o;
    }
}

// ---------------- kmeans assign (fp64 dot; norm is argmax-invariant) ----------------
__global__ __launch_bounds__(256) void k_assign(const float* __restrict__ xe,
                                                const float* __restrict__ means,
                                                int* __restrict__ codes_i,
                                                float* __restrict__ codes_f) {
    __shared__ float sm[128 * 64];
    for (int s = threadIdx.x; s < 8192; s += 256) sm[s] = means[s];
    __syncthreads();
    const int g = blockIdx.x * 256 + threadIdx.x;
    const float* row = xe + (size_t)g * 64;
    float v[64];
#pragma unroll
    for (int c4 = 0; c4 < 16; c4++) {
        float4 t4 = *(const float4*)(row + c4 * 4);
        v[c4 * 4 + 0] = t4.x; v[c4 * 4 + 1] = t4.y; v[c4 * 4 + 2] = t4.z; v[c4 * 4 + 3] = t4.w;
    }
    int best = 0;
    double bd = -1e300;
    for (int cl = 0; cl < 128; cl++) {
        double d = 0.0;
#pragma unroll
        for (int c4 = 0; c4 < 16; c4++) {
            float4 m4 = *(const float4*)(sm + cl * 64 + c4 * 4);
            d += (double)v[c4 * 4 + 0] * (double)m4.x + (double)v[c4 * 4 + 1] * (double)m4.y +
                 (double)v[c4 * 4 + 2] * (double)m4.z + (double)v[c4 * 4 + 3] * (double)m4.w;
        }
        if (d > bd) { bd = d; best = cl; }
    }
    codes_i[g] = best;
    codes_f[g] = (float)best;
}

// ---------------- stable counting sort ----------------
__global__ void k_hist(const int* __restrict__ codes_i, int* __restrict__ hist) {
    __shared__ int h[128];
    if (threadIdx.x < 128) h[threadIdx.x] = 0;
    __syncthreads();
    int n = blockIdx.x / 36, ch = blockIdx.x % 36;
    int c = codes_i[n * L_ + ch * 256 + threadIdx.x];
    atomicAdd(&h[c], 1);
    __syncthreads();
    if (threadIdx.x < 128) hist[(n * 36 + ch) * 128 + threadIdx.x] = h[threadIdx.x];
}

__global__ void k_scan(const int* __restrict__ hist, int* __restrict__ basebuf) {
    __shared__ int tot[128];
    __shared__ int binstart[128];
    int n = blockIdx.x, c = threadIdx.x;
    int run = 0;
    int local[36];
    for (int ch = 0; ch < 36; ch++) { local[ch] = run; run += hist[(n * 36 + ch) * 128 + c]; }
    tot[c] = run;
    __syncthreads();
    if (c == 0) {
        int s = 0;
        for (int b = 0; b < 128; b++) { binstart[b] = s; s += tot[b]; }
    }
    __syncthreads();
    int bs0 = binstart[c];
    for (int ch = 0; ch < 36; ch++) basebuf[(n * 36 + ch) * 128 + c] = bs0 + local[ch];
}

__global__ void k_rank(const int* __restrict__ codes_i, const int* __restrict__ basebuf,
                       int* __restrict__ idxb) {
    __shared__ int sc[256];
    __shared__ int sb[128];
    int n = blockIdx.x / 36, ch = blockIdx.x % 36;
    int i = threadIdx.x;
    int l = ch * 256 + i;
    int c = codes_i[n * L_ + l];
    sc[i] = c;
    if (i < 128) sb[i] = basebuf[(n * 36 + ch) * 128 + i];
    __syncthreads();
    int r = 0;
    for (int j = 0; j < i; j++) r += (sc[j] == c);
    int pos = sb[c] + r;
    idxb[n * L_ + pos] = l;
}

// ---------------- QK via bf16 MFMA + online softmax stats ----------------
// Writes raw scaled logits to score; computes per-row (max, sum) online in
// registers (72 VGPR), combines across 16 lanes (shfl) and 4 waves (LDS),
// writes bs and side buffers smaxb/sinvb so pv needs no stats pass.
__global__ __launch_bounds__(256) void k_qk_mfma(const float* __restrict__ xe,
                                                 const int* __restrict__ idxb,
                                                 float* __restrict__ raw,
                                                 float* __restrict__ bs,
                                                 float* __restrict__ smaxb,
                                                 float* __restrict__ sinvb) {
    __shared__ __align__(16) unsigned short kb[432 * 72];
    __shared__ float snorm[144];
    __shared__ int sidx[432];
    __shared__ float pm[4][144], ps[4][144];
    const int bid = blockIdx.x;
    const int n = bid >> 6, k = bid & 63;
    const int t = threadIdx.x, lane = t & 63, nq = t >> 6;

    for (int s = t; s < 432; s += 256) {
        int wb = s / 144, jj = s % 144;
        int wk = (wb == 0) ? k : (wb == 1) ? ((k + 63) & 63) : ((k + 1) & 63);
        sidx[s] = idxb[n * L_ + wk * WIN + jj];
    }
    __syncthreads();
    for (int s = t; s < 6912; s += 256) {
        int row = s >> 4, q4 = s & 15;
        float4 v = *(const float4*)(xe + ((size_t)n * L_ + sidx[row]) * 64 + q4 * 4);
        float ss = v.x * v.x + v.y * v.y + v.z * v.z + v.w * v.w;
        ss += __shfl_xor(ss, 1); ss += __shfl_xor(ss, 2);
        ss += __shfl_xor(ss, 4); ss += __shfl_xor(ss, 8);
        float nr = fmaxf(sqrtf(ss), 5e-5f);
        float inv = 1.0f / nr;
        ushort4 b = {f2bf(v.x * inv), f2bf(v.y * inv), f2bf(v.z * inv), f2bf(v.w * inv)};
        *(ushort4*)&kb[row * 72 + q4 * 4] = b;
        if (q4 == 0 && row < 144) snorm[row] = nr;
    }
    __syncthreads();
    const int arow = lane & 15, aks = (lane >> 4) * 8;
    bf16x8 af[9][2];
#pragma unroll
    for (int mt = 0; mt < 9; ++mt) {
        af[mt][0] = *(const bf16x8*)&kb[(mt * 16 + arow) * 72 + aks];
        af[mt][1] = *(const bf16x8*)&kb[(mt * 16 + arow) * 72 + 32 + aks];
    }
    float sc[9][4];
#pragma unroll
    for (int mt = 0; mt < 9; ++mt)
#pragma unroll
        for (int r = 0; r < 4; ++r)
            sc[mt][r] = snorm[mt * 16 + (lane >> 4) * 4 + r];

    float rm[9][4], rs[9][4];
#pragma unroll
    for (int mt = 0; mt < 9; ++mt)
#pragma unroll
        for (int r = 0; r < 4; ++r) { rm[mt][r] = -1e30f; rs[mt][r] = 0.f; }

    float* rbase = raw + (size_t)(n * NWIN + k) * WIN * KJ;
    for (int nt = nq; nt < 27; nt += 4) {
        const int col = nt * 16 + (lane & 15);
        bf16x8 b0 = *(const bf16x8*)&kb[col * 72 + aks];
        bf16x8 b1 = *(const bf16x8*)&kb[col * 72 + 32 + aks];
#pragma unroll
        for (int mt = 0; mt < 9; ++mt) {
            f32x4 acc = {0.f, 0.f, 0.f, 0.f};
            acc = __builtin_amdgcn_mfma_f32_16x16x32_bf16(af[mt][0], b0, acc, 0, 0, 0);
            acc = __builtin_amdgcn_mfma_f32_16x16x32_bf16(af[mt][1], b1, acc, 0, 0, 0);
#pragma unroll
            for (int r = 0; r < 4; ++r) {
                float v = acc[r] * sc[mt][r];
                rbase[(size_t)(mt * 16 + (lane >> 4) * 4 + r) * KJ + col] = v;
                float mo = rm[mt][r];
                float mn = fmaxf(mo, v);
                rs[mt][r] = rs[mt][r] * __expf(mo - mn) + __expf(v - mn);
                rm[mt][r] = mn;
            }
        }
    }
    // combine across the 16 lanes covering different columns of the same rows
#pragma unroll
    for (int mt = 0; mt < 9; ++mt)
#pragma unroll
        for (int r = 0; r < 4; ++r) {
            float m = rm[mt][r], s = rs[mt][r];
#pragma unroll
            for (int off = 1; off < 16; off <<= 1) {
                float om = __shfl_xor(m, off);
                float os = __shfl_xor(s, off);
                float M = fmaxf(m, om);
                s = s * __expf(m - M) + os * __expf(om - M);
                m = M;
            }
            rm[mt][r] = m; rs[mt][r] = s;
        }
    if ((lane & 15) == 0) {
#pragma unroll
        for (int mt = 0; mt < 9; ++mt)
#pragma unroll
            for (int r = 0; r < 4; ++r) {
                int row = mt * 16 + (lane >> 4) * 4 + r;
                pm[nq][row] = rm[mt][r];
                ps[nq][row] = rs[mt][r];
            }
    }
    __syncthreads();
    if (t < 144) {
        float M = pm[0][t], S = ps[0][t];
#pragma unroll
        for (int w = 1; w < 4; ++w) {
            float m2 = pm[w][t], s2 = ps[w][t];
            float Mn = fmaxf(M, m2);
            S = S * __expf(M - Mn) + s2 * __expf(m2 - Mn);
            M = Mn;
        }
        size_t o = (size_t)(n * NWIN + k) * WIN + t;
        bs[o] = M + logf(S);
        smaxb[o] = M;
        sinvb[o] = 1.f / S;
    }
}

// ---------------- PV + softmax-apply: probs->score, retb (token order, bf16) ----
__global__ __launch_bounds__(256) void k_pv_sm(const unsigned short* __restrict__ yeb,
                                               const int* __restrict__ idxb,
                                               float* __restrict__ score,
                                               const float* __restrict__ smaxb,
                                               const float* __restrict__ sinvb,
                                               unsigned short* __restrict__ retb) {
    __shared__ __align__(16) unsigned short pA[144 * 72];   // P[i][kk], stride 72
    __shared__ __align__(16) unsigned short pB[64 * 264];   // Y[kk][co], stride 264
    __shared__ int sidx[432];
    __shared__ float smax[144], sinv[144];
    const int bid = blockIdx.x;
    const int n = bid >> 6, k = bid & 63;
    const int t = threadIdx.x, lane = t & 63, nq = t >> 6;

    for (int s = t; s < 432; s += 256) {
        int wb = s / 144, jj = s % 144;
        int wk = (wb == 0) ? k : (wb == 1) ? ((k + 63) & 63) : ((k + 1) & 63);
        sidx[s] = idxb[n * L_ + wk * WIN + jj];
    }
    if (t < 144) {
        size_t o = (size_t)(n * NWIN + k) * WIN + t;
        smax[t] = smaxb[o];
        sinv[t] = sinvb[o];
    }

    f32x4 acc[9][4];
#pragma unroll
    for (int mt = 0; mt < 9; ++mt)
#pragma unroll
        for (int nt = 0; nt < 4; ++nt) {
            f32x4 z = {0.f, 0.f, 0.f, 0.f};
            acc[mt][nt] = z;
        }

    float* srow = score + (size_t)(n * NWIN + k) * WIN * KJ;
    const int aBase = (lane & 15) * 72 + (lane >> 4) * 8;
    const int bBase = (lane >> 4) * 8 * 264 + nq * 64 + (lane & 15);

    for (int kc = 0; kc < 7; ++kc) {
        __syncthreads();
        for (int s = t; s < 2304; s += 256) {
            int i = s >> 4, c4 = s & 15;
            int kcol = kc * 64 + c4 * 4;
            ushort4 b = {0, 0, 0, 0};
            if (kcol < KJ) {
                float4 v = *(const float4*)(srow + (size_t)i * KJ + kcol);
                float m = smax[i], iv = sinv[i];
                float4 p = {__expf(v.x - m) * iv, __expf(v.y - m) * iv,
                            __expf(v.z - m) * iv, __expf(v.w - m) * iv};
                *(float4*)(srow + (size_t)i * KJ + kcol) = p;
                b.x = f2bf(p.x); b.y = f2bf(p.y); b.z = f2bf(p.z); b.w = f2bf(p.w);
            }
            *(ushort4*)&pA[i * 72 + c4 * 4] = b;
        }
        for (int s = t; s < 2048; s += 256) {
            int j = s >> 5, c8 = s & 31;
            int kk = kc * 64 + j;
            u16x8 u = {0, 0, 0, 0, 0, 0, 0, 0};
            if (kk < KJ) u = *(const u16x8*)&yeb[(size_t)sidx[kk] * 256 +
                                                (size_t)n * L_ * 256 + c8 * 8];
            *(u16x8*)&pB[j * 264 + c8 * 8] = u;
        }
        __syncthreads();
#pragma unroll
        for (int ks = 0; ks < 2; ++ks) {
            bf16x8 af[9];
#pragma unroll
            for (int mt = 0; mt < 9; ++mt)
                af[mt] = *(const bf16x8*)&pA[aBase + mt * 1152 + ks * 32];
#pragma unroll
            for (int nt = 0; nt < 4; ++nt) {
                const int e = bBase + ks * 32 * 264 + nt * 16;
                u16x8 bu;
#pragma unroll
                for (int j = 0; j < 8; ++j) bu[j] = pB[e + j * 264];
                bf16x8 bf = __builtin_bit_cast(bf16x8, bu);
#pragma unroll
                for (int mt = 0; mt < 9; ++mt)
                    acc[mt][nt] = __builtin_amdgcn_mfma_f32_16x16x32_bf16(af[mt], bf, acc[mt][nt], 0, 0, 0);
            }
        }
    }
    const int rowb = (lane >> 4) * 4;
    const int colb = nq * 64 + (lane & 15);
#pragma unroll
    for (int mt = 0; mt < 9; ++mt)
#pragma unroll
        for (int nt = 0; nt < 4; ++nt)
#pragma unroll
            for (int r = 0; r < 4; ++r) {
                int row = mt * 16 + rowb + r;
                int tok = sidx[row];
                retb[((size_t)n * L_ + tok) * 256 + colb + nt * 16] = f2bf(acc[mt][nt][r]);
            }
}

// ---------------- final: out = x + 0.1 * retb (token order, bf16) ----------------
__global__ __launch_bounds__(256) void k_out(const float* __restrict__ x,
                                             const unsigned short* __restrict__ retb,
                                             float* __restrict__ out) {
    __shared__ float sr[32 * 257];
    const int n = blockIdx.x / 288, lt = blockIdx.x % 288;
    const int lbase = lt * 32;
    const int t = threadIdx.x;
    for (int s = t; s < 1024; s += 256) {
        int lr = s >> 5, c8 = s & 31;
        u16x8 u = *(const u16x8*)&retb[((size_t)n * L_ + lbase + lr) * 256 + c8 * 8];
#pragma unroll
        for (int e = 0; e < 8; ++e) sr[lr * 257 + c8 * 8 + e] = bf2f(u[e]);
    }
    __syncthreads();
    const int lr = t & 31, cog = t >> 5;
    for (int cc = 0; cc < 32; cc++) {
        int co = cog * 32 + cc;
        size_t gi = ((size_t)(n * 256 + co)) * L_ + lbase + lr;
        out[gi] = x[gi] + 0.1f * sr[lr * 257 + co];
    }
}

extern "C" void kernel_launch(void* const* d_in, const int* in_sizes, int n_in,
                              void* d_out, int out_size, void* d_ws, size_t ws_size,
                              hipStream_t stream) {
    (void)in_sizes; (void)n_in; (void)out_size; (void)ws_size;
    const float* x     = (const float*)d_in[0];
    const float* means = (const float*)d_in[1];
    const float* wm    = (const float*)d_in[2];
    const float* bm    = (const float*)d_in[3];
    const float* wa    = (const float*)d_in[4];
    const float* ba    = (const float*)d_in[5];

    float* out   = (float*)d_out;
    float* score = out + (size_t)8 * 256 * L_;
    float* bs    = score + (size_t)8 * NWIN * WIN * KJ;
    float* codesf = bs + (size_t)8 * L_;

    float* xe  = (float*)d_ws;
    float* ye  = xe + (size_t)8 * L_ * 64;                  // region reused as bf16 yeb
    float* ret = ye + (size_t)8 * L_ * 256;                 // parts (f32) then retb (bf16)
    float* wtr = ret + (size_t)8 * L_ * 256;
    int* codes_i = (int*)(wtr + 147456);
    int* idxb    = codes_i + 8 * L_;
    int* undo    = idxb + 8 * L_;                           // unused, keeps layout
    int* hist    = undo + 8 * L_;
    int* basebuf = hist + 8 * 36 * 128;
    float* zeros = (float*)(basebuf + 8 * 36 * 128);
    float* smaxb = zeros + 64;                              // 512*144 f32
    float* sinvb = smaxb + 73728;                           // 512*144 f32

    float* parts = ret;
    unsigned short* yeb  = (unsigned short*)ye;
    unsigned short* retb = (unsigned short*)ret;

    k_wprep  <<<576, 256, 0, stream>>>(wm, wtr, zeros);
    k_conv3x3<<<768, 256, 0, stream>>>(x, wtr, zeros, parts);
    k_c3sum  <<<4608, 256, 0, stream>>>(parts, bm, xe);
    k_conv1x1<<<4608, 256, 0, stream>>>(x, wa, ba, yeb);
    k_assign <<<288, 256, 0, stream>>>(xe, means, codes_i, codesf);
    k_hist   <<<288, 256, 0, stream>>>(codes_i, hist);
    k_scan   <<<8, 128, 0, stream>>>(hist, basebuf);
    k_rank   <<<288, 256, 0, stream>>>(codes_i, basebuf, idxb);
    k_qk_mfma<<<512, 256, 0, stream>>>(xe, idxb, score, bs, smaxb, sinvb);
    k_pv_sm  <<<512, 256, 0, stream>>>(yeb, idxb, score, smaxb, sinvb, retb);
    k_out    <<<2304, 256, 0, stream>>>(x, retb, out);
}